// Round 1
// baseline (663.191 us; speedup 1.0000x reference)
//
#include <hip/hip_runtime.h>

#define NN   50000
#define NE   1000000
#define FIN  128
#define HID  64
#define HEADS 4
#define C1   256          // HEADS*HID
#define NG   512
#define ETOT (NE + NN)    // edges + self-loops
#define NBLK_SCAN 49      // ceil((NN+1)/1024)

__device__ __forceinline__ float lrelu(float v) { return v > 0.f ? v : 0.2f * v; }
__device__ __forceinline__ float eluf(float v)  { return v > 0.f ? v : __expf(v) - 1.f; }

// ---------------- CSR build ----------------
__global__ __launch_bounds__(256) void k_deg(const int* __restrict__ dst, int* __restrict__ deg) {
    int e = blockIdx.x * 256 + threadIdx.x;
    if (e < NE) atomicAdd(&deg[dst[e]], 1);
}

// scan NN+1 values: val[i] = deg[i]+1 (self-loop) for i<NN, 0 at i==NN. exclusive scan.
__global__ __launch_bounds__(1024) void k_scan_blk(const int* __restrict__ deg,
                                                   int* __restrict__ offs,
                                                   int* __restrict__ bsum) {
    int tid = threadIdx.x;
    int gid = blockIdx.x * 1024 + tid;
    int v = (gid < NN) ? deg[gid] + 1 : 0;
    int lane = tid & 63, wv = tid >> 6;
    int x = v;
    #pragma unroll
    for (int off = 1; off < 64; off <<= 1) {
        int t = __shfl_up(x, off);
        if (lane >= off) x += t;
    }
    __shared__ int ws[16];
    if (lane == 63) ws[wv] = x;
    __syncthreads();
    if (tid < 16) {
        int y = ws[tid];
        #pragma unroll
        for (int off = 1; off < 16; off <<= 1) {
            int t = __shfl_up(y, off);
            if (tid >= off) y += t;
        }
        ws[tid] = y;
    }
    __syncthreads();
    int base = wv ? ws[wv - 1] : 0;
    if (gid < NN + 1) offs[gid] = base + x - v;   // exclusive
    if (tid == 1023) bsum[blockIdx.x] = ws[15];
}

__global__ void k_scan_top(int* __restrict__ bsum, int nb) {
    int tid = threadIdx.x;  // 64 threads, 1 block
    int v = (tid < nb) ? bsum[tid] : 0;
    #pragma unroll
    for (int off = 1; off < 64; off <<= 1) {
        int t = __shfl_up(v, off);
        if (tid >= off) v += t;
    }
    if (tid < nb) bsum[tid] = v;  // inclusive
}

__global__ __launch_bounds__(256) void k_scan_add(int* __restrict__ offs,
                                                  const int* __restrict__ bsum,
                                                  int* __restrict__ cursor) {
    int i = blockIdx.x * 256 + threadIdx.x;
    if (i < NN + 1) {
        int blk = i >> 10;
        int o = offs[i] + (blk ? bsum[blk - 1] : 0);
        offs[i] = o;
        if (i < NN) cursor[i] = o;
    }
}

__global__ __launch_bounds__(256) void k_fill(const int* __restrict__ src,
                                              const int* __restrict__ dst,
                                              int* __restrict__ cursor,
                                              int* __restrict__ colsrc) {
    int i = blockIdx.x * 256 + threadIdx.x;
    if (i < NE) {
        int d = dst[i];
        int p = atomicAdd(&cursor[d], 1);
        colsrc[p] = src[i];
    } else if (i < ETOT) {
        int n = i - NE;
        int p = atomicAdd(&cursor[n], 1);
        colsrc[p] = n;      // self-loop
    }
}

// ---------------- Layer 1 GEMM: h1 = x @ W1, fused es1/ed1 ----------------
__global__ __launch_bounds__(256) void k_gemm1(const float* __restrict__ x,
                                               const float* __restrict__ W1,
                                               const float* __restrict__ asrc,
                                               const float* __restrict__ adst,
                                               float* __restrict__ h1,
                                               float* __restrict__ es1,
                                               float* __restrict__ ed1) {
    int lane = threadIdx.x & 63, wv = threadIdx.x >> 6;
    int r0 = (blockIdx.x * 4 + wv) * 8;
    if (r0 >= NN) return;
    int col = 4 * lane;

    const float* xr[8];
    int rows[8];
    #pragma unroll
    for (int r = 0; r < 8; ++r) {
        rows[r] = min(r0 + r, NN - 1);
        xr[r] = x + (size_t)rows[r] * FIN;
    }
    float4 acc[8];
    #pragma unroll
    for (int r = 0; r < 8; ++r) acc[r] = make_float4(0.f, 0.f, 0.f, 0.f);

    for (int k = 0; k < FIN; k += 4) {
        float4 w0 = *(const float4*)(W1 + (size_t)(k + 0) * C1 + col);
        float4 w1 = *(const float4*)(W1 + (size_t)(k + 1) * C1 + col);
        float4 w2 = *(const float4*)(W1 + (size_t)(k + 2) * C1 + col);
        float4 w3 = *(const float4*)(W1 + (size_t)(k + 3) * C1 + col);
        #pragma unroll
        for (int r = 0; r < 8; ++r) {
            float4 xv = *(const float4*)(xr[r] + k);
            acc[r].x += xv.x * w0.x + xv.y * w1.x + xv.z * w2.x + xv.w * w3.x;
            acc[r].y += xv.x * w0.y + xv.y * w1.y + xv.z * w2.y + xv.w * w3.y;
            acc[r].z += xv.x * w0.z + xv.y * w1.z + xv.z * w2.z + xv.w * w3.z;
            acc[r].w += xv.x * w0.w + xv.y * w1.w + xv.z * w2.w + xv.w * w3.w;
        }
    }

    int head = lane >> 4;
    float4 av = *(const float4*)(asrc + head * HID + (lane & 15) * 4);
    float4 bv = *(const float4*)(adst + head * HID + (lane & 15) * 4);
    #pragma unroll
    for (int r = 0; r < 8; ++r) {
        int row = rows[r];
        *(float4*)(h1 + (size_t)row * C1 + col) = acc[r];
        float ps = acc[r].x * av.x + acc[r].y * av.y + acc[r].z * av.z + acc[r].w * av.w;
        float pd = acc[r].x * bv.x + acc[r].y * bv.y + acc[r].z * bv.z + acc[r].w * bv.w;
        #pragma unroll
        for (int off = 1; off < 16; off <<= 1) {
            ps += __shfl_xor(ps, off);
            pd += __shfl_xor(pd, off);
        }
        if ((lane & 15) == 0) {
            es1[row * 4 + head] = ps;
            ed1[row * 4 + head] = pd;
        }
    }
}

// ---------------- Layer 1 aggregation (segment softmax + weighted sum) ----------------
__global__ __launch_bounds__(256) void k_agg1(const int* __restrict__ offs,
                                              const int* __restrict__ colsrc,
                                              const float* __restrict__ h1,
                                              const float* __restrict__ es1,
                                              const float* __restrict__ ed1,
                                              const float* __restrict__ b1,
                                              float* __restrict__ h1p) {
    int lane = threadIdx.x & 63, wv = threadIdx.x >> 6;
    int n = blockIdx.x * 4 + wv;
    if (n >= NN) return;
    int beg = offs[n], end = offs[n + 1], deg = end - beg;
    float4 edv = *(const float4*)(ed1 + n * 4);
    float4 acc = make_float4(0.f, 0.f, 0.f, 0.f);

    if (deg <= 64) {
        int msrc = 0;
        float m0 = 0.f, m1 = 0.f, m2 = 0.f, m3 = 0.f;
        if (lane < deg) {
            msrc = colsrc[beg + lane];
            float4 ev = *(const float4*)(es1 + msrc * 4);
            m0 = __expf(lrelu(ev.x + edv.x));
            m1 = __expf(lrelu(ev.y + edv.y));
            m2 = __expf(lrelu(ev.z + edv.z));
            m3 = __expf(lrelu(ev.w + edv.w));
        }
        float s0 = m0, s1 = m1, s2 = m2, s3 = m3;
        #pragma unroll
        for (int off = 1; off < 64; off <<= 1) {
            s0 += __shfl_xor(s0, off);
            s1 += __shfl_xor(s1, off);
            s2 += __shfl_xor(s2, off);
            s3 += __shfl_xor(s3, off);
        }
        float r0 = 1.f / s0, r1 = 1.f / s1, r2 = 1.f / s2, r3 = 1.f / s3;
        for (int i = 0; i < deg; ++i) {
            int s = __shfl(msrc, i);
            float a0 = __shfl(m0, i) * r0;
            float a1 = __shfl(m1, i) * r1;
            float a2 = __shfl(m2, i) * r2;
            float a3 = __shfl(m3, i) * r3;
            const float* hr = h1 + (size_t)s * C1;
            acc.x += hr[lane] * a0;
            acc.y += hr[64 + lane] * a1;
            acc.z += hr[128 + lane] * a2;
            acc.w += hr[192 + lane] * a3;
        }
    } else {
        float s0 = 0.f, s1 = 0.f, s2 = 0.f, s3 = 0.f;
        for (int i = beg + lane; i < end; i += 64) {
            int s = colsrc[i];
            float4 ev = *(const float4*)(es1 + s * 4);
            s0 += __expf(lrelu(ev.x + edv.x));
            s1 += __expf(lrelu(ev.y + edv.y));
            s2 += __expf(lrelu(ev.z + edv.z));
            s3 += __expf(lrelu(ev.w + edv.w));
        }
        #pragma unroll
        for (int off = 1; off < 64; off <<= 1) {
            s0 += __shfl_xor(s0, off);
            s1 += __shfl_xor(s1, off);
            s2 += __shfl_xor(s2, off);
            s3 += __shfl_xor(s3, off);
        }
        float r0 = 1.f / s0, r1 = 1.f / s1, r2 = 1.f / s2, r3 = 1.f / s3;
        for (int i = beg; i < end; ++i) {
            int s = colsrc[i];
            float4 ev = *(const float4*)(es1 + s * 4);
            float a0 = __expf(lrelu(ev.x + edv.x)) * r0;
            float a1 = __expf(lrelu(ev.y + edv.y)) * r1;
            float a2 = __expf(lrelu(ev.z + edv.z)) * r2;
            float a3 = __expf(lrelu(ev.w + edv.w)) * r3;
            const float* hr = h1 + (size_t)s * C1;
            acc.x += hr[lane] * a0;
            acc.y += hr[64 + lane] * a1;
            acc.z += hr[128 + lane] * a2;
            acc.w += hr[192 + lane] * a3;
        }
    }

    float* op = h1p + (size_t)n * C1;
    op[lane]       = eluf(acc.x + b1[lane]);
    op[64 + lane]  = eluf(acc.y + b1[64 + lane]);
    op[128 + lane] = eluf(acc.z + b1[128 + lane]);
    op[192 + lane] = eluf(acc.w + b1[192 + lane]);
}

// ---------------- Layer 2 GEMM: h2 = h1p @ W2, fused es2/ed2 ----------------
__global__ __launch_bounds__(256) void k_gemm2(const float* __restrict__ h1p,
                                               const float* __restrict__ W2,
                                               const float* __restrict__ as2,
                                               const float* __restrict__ ad2,
                                               float* __restrict__ h2,
                                               float* __restrict__ es2,
                                               float* __restrict__ ed2) {
    int lane = threadIdx.x & 63, wv = threadIdx.x >> 6;
    int r0 = (blockIdx.x * 4 + wv) * 8;
    if (r0 >= NN) return;

    const float* xr[8];
    int rows[8];
    #pragma unroll
    for (int r = 0; r < 8; ++r) {
        rows[r] = min(r0 + r, NN - 1);
        xr[r] = h1p + (size_t)rows[r] * C1;
    }
    float acc[8];
    #pragma unroll
    for (int r = 0; r < 8; ++r) acc[r] = 0.f;

    for (int k = 0; k < C1; k += 4) {
        float w0 = W2[(size_t)(k + 0) * HID + lane];
        float w1 = W2[(size_t)(k + 1) * HID + lane];
        float w2 = W2[(size_t)(k + 2) * HID + lane];
        float w3 = W2[(size_t)(k + 3) * HID + lane];
        #pragma unroll
        for (int r = 0; r < 8; ++r) {
            float4 xv = *(const float4*)(xr[r] + k);
            acc[r] += xv.x * w0 + xv.y * w1 + xv.z * w2 + xv.w * w3;
        }
    }

    float a_s = as2[lane], a_d = ad2[lane];
    #pragma unroll
    for (int r = 0; r < 8; ++r) {
        int row = rows[r];
        h2[(size_t)row * HID + lane] = acc[r];
        float ps = acc[r] * a_s;
        float pd = acc[r] * a_d;
        #pragma unroll
        for (int off = 1; off < 64; off <<= 1) {
            ps += __shfl_xor(ps, off);
            pd += __shfl_xor(pd, off);
        }
        if (lane == 0) {
            es2[row] = ps;
            ed2[row] = pd;
        }
    }
}

// ---------------- Layer 2 aggregation + fused mean-pool atomics ----------------
__global__ __launch_bounds__(256) void k_agg2(const int* __restrict__ offs,
                                              const int* __restrict__ colsrc,
                                              const float* __restrict__ h2,
                                              const float* __restrict__ es2,
                                              const float* __restrict__ ed2,
                                              const float* __restrict__ b2,
                                              const int* __restrict__ batch,
                                              float* __restrict__ pool,
                                              int* __restrict__ cnt) {
    int lane = threadIdx.x & 63, wv = threadIdx.x >> 6;
    int n = blockIdx.x * 4 + wv;
    if (n >= NN) return;
    int beg = offs[n], end = offs[n + 1], deg = end - beg;
    float edv = ed2[n];
    float acc = 0.f;

    if (deg <= 64) {
        int msrc = 0;
        float mex = 0.f;
        if (lane < deg) {
            msrc = colsrc[beg + lane];
            mex = __expf(lrelu(es2[msrc] + edv));
        }
        float ss = mex;
        #pragma unroll
        for (int off = 1; off < 64; off <<= 1) ss += __shfl_xor(ss, off);
        float rs = 1.f / ss;
        for (int i = 0; i < deg; ++i) {
            int s = __shfl(msrc, i);
            float a = __shfl(mex, i) * rs;
            acc += h2[(size_t)s * HID + lane] * a;
        }
    } else {
        float ss = 0.f;
        for (int i = beg + lane; i < end; i += 64) {
            int s = colsrc[i];
            ss += __expf(lrelu(es2[s] + edv));
        }
        #pragma unroll
        for (int off = 1; off < 64; off <<= 1) ss += __shfl_xor(ss, off);
        float rs = 1.f / ss;
        for (int i = beg; i < end; ++i) {
            int s = colsrc[i];
            float a = __expf(lrelu(es2[s] + edv)) * rs;
            acc += h2[(size_t)s * HID + lane] * a;
        }
    }

    float o = eluf(acc + b2[lane]);
    int g = batch[n];
    atomicAdd(&pool[(size_t)g * HID + lane], o);
    if (lane == 0) atomicAdd(&cnt[g], 1);
}

// ---------------- classifier ----------------
__global__ __launch_bounds__(256) void k_cls(const float* __restrict__ pool,
                                             const int* __restrict__ cnt,
                                             const float* __restrict__ Wc,
                                             const float* __restrict__ bc,
                                             float* __restrict__ out) {
    int lane = threadIdx.x & 63, wv = threadIdx.x >> 6;
    int g = blockIdx.x * 4 + wv;
    if (g >= NG) return;
    float c = fmaxf((float)cnt[g], 1.f);
    float p = pool[(size_t)g * HID + lane] / c;
    float s0 = p * Wc[lane * 2 + 0];
    float s1 = p * Wc[lane * 2 + 1];
    #pragma unroll
    for (int off = 1; off < 64; off <<= 1) {
        s0 += __shfl_xor(s0, off);
        s1 += __shfl_xor(s1, off);
    }
    if (lane == 0) {
        out[g * 2 + 0] = s0 + bc[0];
        out[g * 2 + 1] = s1 + bc[1];
    }
}

extern "C" void kernel_launch(void* const* d_in, const int* in_sizes, int n_in,
                              void* d_out, int out_size, void* d_ws, size_t ws_size,
                              hipStream_t stream) {
    const float* x   = (const float*)d_in[0];
    const int* ei    = (const int*)d_in[1];
    const int* batch = (const int*)d_in[2];
    // d_in[3] = num_graphs scalar (NG hardcoded = 512)
    const float* W1  = (const float*)d_in[4];
    const float* as1 = (const float*)d_in[5];
    const float* ad1 = (const float*)d_in[6];
    const float* b1  = (const float*)d_in[7];
    const float* W2  = (const float*)d_in[8];
    const float* as2 = (const float*)d_in[9];
    const float* ad2 = (const float*)d_in[10];
    const float* b2  = (const float*)d_in[11];
    const float* Wc  = (const float*)d_in[12];
    const float* bc  = (const float*)d_in[13];
    float* out = (float*)d_out;

    char* p = (char*)d_ws;
    auto alloc = [&](size_t bytes) -> char* {
        char* r = p;
        p += (bytes + 255) & ~(size_t)255;
        return r;
    };
    int* offs    = (int*)alloc((NN + 1) * sizeof(int));
    int* cursor  = (int*)alloc(NN * sizeof(int));
    int* deg     = (int*)alloc(NN * sizeof(int));
    int* colsrc  = (int*)alloc((size_t)ETOT * sizeof(int));
    int* bsum    = (int*)alloc(64 * sizeof(int));
    float* h1    = (float*)alloc((size_t)NN * C1 * sizeof(float));
    float* es1   = (float*)alloc((size_t)NN * 4 * sizeof(float));
    float* ed1   = (float*)alloc((size_t)NN * 4 * sizeof(float));
    float* h1p   = (float*)alloc((size_t)NN * C1 * sizeof(float));
    float* h2    = (float*)alloc((size_t)NN * HID * sizeof(float));
    float* es2v  = (float*)alloc((size_t)NN * sizeof(float));
    float* ed2v  = (float*)alloc((size_t)NN * sizeof(float));
    float* pool  = (float*)alloc((size_t)NG * HID * sizeof(float));
    int* cnt     = (int*)alloc(NG * sizeof(int));

    hipMemsetAsync(deg, 0, NN * sizeof(int), stream);
    hipMemsetAsync(pool, 0, (size_t)NG * HID * sizeof(float), stream);
    hipMemsetAsync(cnt, 0, NG * sizeof(int), stream);

    const int* srcA = ei;       // edge_index[0]
    const int* dstA = ei + NE;  // edge_index[1]

    k_deg<<<(NE + 255) / 256, 256, 0, stream>>>(dstA, deg);
    k_scan_blk<<<NBLK_SCAN, 1024, 0, stream>>>(deg, offs, bsum);
    k_scan_top<<<1, 64, 0, stream>>>(bsum, NBLK_SCAN);
    k_scan_add<<<(NN + 1 + 255) / 256, 256, 0, stream>>>(offs, bsum, cursor);
    k_fill<<<(ETOT + 255) / 256, 256, 0, stream>>>(srcA, dstA, cursor, colsrc);

    k_gemm1<<<(NN + 31) / 32, 256, 0, stream>>>(x, W1, as1, ad1, h1, es1, ed1);
    k_agg1<<<(NN + 3) / 4, 256, 0, stream>>>(offs, colsrc, h1, es1, ed1, b1, h1p);
    k_gemm2<<<(NN + 31) / 32, 256, 0, stream>>>(h1p, W2, as2, ad2, h2, es2v, ed2v);
    k_agg2<<<(NN + 3) / 4, 256, 0, stream>>>(offs, colsrc, h2, es2v, ed2v, b2, batch, pool, cnt);
    k_cls<<<(NG + 3) / 4, 256, 0, stream>>>(pool, cnt, Wc, bc, out);
}

// Round 2
// 424.654 us; speedup vs baseline: 1.5617x; 1.5617x over previous
//
#include <hip/hip_runtime.h>

#define NN   50000
#define NE   1000000
#define FIN  128
#define HID  64
#define HEADS 4
#define C1   256          // HEADS*HID
#define NG   512
#define ETOT (NE + NN)    // edges + self-loops
#define NBLK_SCAN 49      // ceil((NN+1)/1024)

typedef __attribute__((ext_vector_type(8))) short bf16x8;
typedef __attribute__((ext_vector_type(4))) float f32x4;

__device__ __forceinline__ float lrelu(float v) { return v > 0.f ? v : 0.2f * v; }
__device__ __forceinline__ float eluf(float v)  { return v > 0.f ? v : __expf(v) - 1.f; }

__device__ __forceinline__ unsigned short f2bf(float f) {
    unsigned u = __float_as_uint(f);
    unsigned r = (u + 0x7FFFu + ((u >> 16) & 1u)) >> 16;
    return (unsigned short)r;
}
__device__ __forceinline__ float bf2f(unsigned short b) {
    return __uint_as_float(((unsigned)b) << 16);
}

// ---------------- weight prep: transpose + bf16 cast ----------------
__global__ __launch_bounds__(256) void k_prep(const float* __restrict__ W1,
                                              const float* __restrict__ W2,
                                              unsigned short* __restrict__ W1t,
                                              unsigned short* __restrict__ W2t) {
    int i = blockIdx.x * 256 + threadIdx.x;
    if (i < FIN * C1) {
        int k = i / C1, c = i % C1;
        W1t[c * FIN + k] = f2bf(W1[i]);
    } else {
        int j = i - FIN * C1;
        if (j < C1 * HID) {
            int k = j / HID, c = j % HID;
            W2t[c * C1 + k] = f2bf(W2[j]);
        }
    }
}

// ---------------- CSR build ----------------
__global__ __launch_bounds__(256) void k_deg(const int* __restrict__ dst, int* __restrict__ deg) {
    int e = blockIdx.x * 256 + threadIdx.x;
    if (e < NE) atomicAdd(&deg[dst[e]], 1);
}

__global__ __launch_bounds__(1024) void k_scan_blk(const int* __restrict__ deg,
                                                   int* __restrict__ offs,
                                                   int* __restrict__ bsum) {
    int tid = threadIdx.x;
    int gid = blockIdx.x * 1024 + tid;
    int v = (gid < NN) ? deg[gid] + 1 : 0;
    int lane = tid & 63, wv = tid >> 6;
    int x = v;
    #pragma unroll
    for (int off = 1; off < 64; off <<= 1) {
        int t = __shfl_up(x, off);
        if (lane >= off) x += t;
    }
    __shared__ int ws[16];
    if (lane == 63) ws[wv] = x;
    __syncthreads();
    if (tid < 16) {
        int y = ws[tid];
        #pragma unroll
        for (int off = 1; off < 16; off <<= 1) {
            int t = __shfl_up(y, off);
            if (tid >= off) y += t;
        }
        ws[tid] = y;
    }
    __syncthreads();
    int base = wv ? ws[wv - 1] : 0;
    if (gid < NN + 1) offs[gid] = base + x - v;   // exclusive
    if (tid == 1023) bsum[blockIdx.x] = ws[15];
}

__global__ void k_scan_top(int* __restrict__ bsum, int nb) {
    int tid = threadIdx.x;
    int v = (tid < nb) ? bsum[tid] : 0;
    #pragma unroll
    for (int off = 1; off < 64; off <<= 1) {
        int t = __shfl_up(v, off);
        if (tid >= off) v += t;
    }
    if (tid < nb) bsum[tid] = v;  // inclusive
}

__global__ __launch_bounds__(256) void k_scan_add(int* __restrict__ offs,
                                                  const int* __restrict__ bsum,
                                                  int* __restrict__ cursor) {
    int i = blockIdx.x * 256 + threadIdx.x;
    if (i < NN + 1) {
        int blk = i >> 10;
        int o = offs[i] + (blk ? bsum[blk - 1] : 0);
        offs[i] = o;
        if (i < NN) cursor[i] = o;
    }
}

__global__ __launch_bounds__(256) void k_fill(const int* __restrict__ src,
                                              const int* __restrict__ dst,
                                              int* __restrict__ cursor,
                                              int* __restrict__ colsrc) {
    int i = blockIdx.x * 256 + threadIdx.x;
    if (i < NE) {
        int d = dst[i];
        int p = atomicAdd(&cursor[d], 1);
        colsrc[p] = src[i];
    } else if (i < ETOT) {
        int n = i - NE;
        int p = atomicAdd(&cursor[n], 1);
        colsrc[p] = n;      // self-loop
    }
}

// ---------------- Layer 1 GEMM (MFMA bf16): h1b = bf16(x @ W1), fused es1/ed1 ----------------
// wave computes 16 rows x 256 cols. A: row=lane&15, k=(lane>>4)*8+j. B: col=lane&15.
// C: col=lane&15, row=(lane>>4)*4+reg  (guide §3, m89-verified)
__global__ __launch_bounds__(256) void k_gemm1(const float* __restrict__ x,
                                               const unsigned short* __restrict__ W1t,
                                               const float* __restrict__ asrc,
                                               const float* __restrict__ adst,
                                               unsigned short* __restrict__ h1b,
                                               float* __restrict__ es1,
                                               float* __restrict__ ed1) {
    int lane = threadIdx.x & 63, wv = threadIdx.x >> 6;
    int r0 = (blockIdx.x * 4 + wv) * 16;
    if (r0 >= NN) return;
    int g = lane >> 4, q = lane & 15;

    // load + convert A fragments (4 k-steps of 32)
    const float* xr = x + (size_t)(r0 + q) * FIN;
    bf16x8 afr[4];
    #pragma unroll
    for (int kt = 0; kt < 4; ++kt) {
        float4 u0 = *(const float4*)(xr + kt * 32 + g * 8);
        float4 u1 = *(const float4*)(xr + kt * 32 + g * 8 + 4);
        bf16x8 a;
        a[0] = (short)f2bf(u0.x); a[1] = (short)f2bf(u0.y);
        a[2] = (short)f2bf(u0.z); a[3] = (short)f2bf(u0.w);
        a[4] = (short)f2bf(u1.x); a[5] = (short)f2bf(u1.y);
        a[6] = (short)f2bf(u1.z); a[7] = (short)f2bf(u1.w);
        afr[kt] = a;
    }

    #pragma unroll
    for (int h = 0; h < 4; ++h) {
        float ps[4] = {0.f, 0.f, 0.f, 0.f};
        float pd[4] = {0.f, 0.f, 0.f, 0.f};
        #pragma unroll
        for (int tl = 0; tl < 4; ++tl) {
            int t = h * 4 + tl;
            int col = t * 16 + q;
            const unsigned short* wb = W1t + (size_t)col * FIN;
            f32x4 acc = {0.f, 0.f, 0.f, 0.f};
            #pragma unroll
            for (int kt = 0; kt < 4; ++kt) {
                bf16x8 b = *(const bf16x8*)(wb + kt * 32 + g * 8);
                acc = __builtin_amdgcn_mfma_f32_16x16x32_bf16(afr[kt], b, acc, 0, 0, 0);
            }
            float av = asrc[col], bv = adst[col];
            #pragma unroll
            for (int j = 0; j < 4; ++j) {
                int rr = r0 + g * 4 + j;
                h1b[(size_t)rr * C1 + col] = f2bf(acc[j]);
                ps[j] += acc[j] * av;
                pd[j] += acc[j] * bv;
            }
        }
        #pragma unroll
        for (int j = 0; j < 4; ++j) {
            #pragma unroll
            for (int off = 1; off < 16; off <<= 1) {
                ps[j] += __shfl_xor(ps[j], off);
                pd[j] += __shfl_xor(pd[j], off);
            }
            if (q == 0) {
                int rr = r0 + g * 4 + j;
                es1[rr * 4 + h] = ps[j];
                ed1[rr * 4 + h] = pd[j];
            }
        }
    }
}

// ---------------- Layer 1 aggregation (bf16 gathers) ----------------
__global__ __launch_bounds__(256) void k_agg1(const int* __restrict__ offs,
                                              const int* __restrict__ colsrc,
                                              const unsigned short* __restrict__ h1b,
                                              const float* __restrict__ es1,
                                              const float* __restrict__ ed1,
                                              const float* __restrict__ b1,
                                              unsigned short* __restrict__ h1p) {
    int lane = threadIdx.x & 63, wv = threadIdx.x >> 6;
    int n = blockIdx.x * 4 + wv;
    if (n >= NN) return;
    int beg = offs[n], end = offs[n + 1], deg = end - beg;
    float4 edv = *(const float4*)(ed1 + n * 4);
    int head = lane >> 4;
    float4 acc = make_float4(0.f, 0.f, 0.f, 0.f);

    if (deg <= 64) {
        int msrc = 0;
        float m0 = 0.f, m1 = 0.f, m2 = 0.f, m3 = 0.f;
        if (lane < deg) {
            msrc = colsrc[beg + lane];
            float4 ev = *(const float4*)(es1 + msrc * 4);
            m0 = __expf(lrelu(ev.x + edv.x));
            m1 = __expf(lrelu(ev.y + edv.y));
            m2 = __expf(lrelu(ev.z + edv.z));
            m3 = __expf(lrelu(ev.w + edv.w));
        }
        float s0 = m0, s1 = m1, s2 = m2, s3 = m3;
        #pragma unroll
        for (int off = 1; off < 64; off <<= 1) {
            s0 += __shfl_xor(s0, off);
            s1 += __shfl_xor(s1, off);
            s2 += __shfl_xor(s2, off);
            s3 += __shfl_xor(s3, off);
        }
        float r0 = 1.f / s0, r1 = 1.f / s1, r2 = 1.f / s2, r3 = 1.f / s3;
        for (int i = 0; i < deg; ++i) {
            int s = __shfl(msrc, i);
            float a0 = __shfl(m0, i) * r0;
            float a1 = __shfl(m1, i) * r1;
            float a2 = __shfl(m2, i) * r2;
            float a3 = __shfl(m3, i) * r3;
            float aa = head == 0 ? a0 : head == 1 ? a1 : head == 2 ? a2 : a3;
            ushort4 hv = *(const ushort4*)(h1b + (size_t)s * C1 + 4 * lane);
            acc.x += bf2f(hv.x) * aa;
            acc.y += bf2f(hv.y) * aa;
            acc.z += bf2f(hv.z) * aa;
            acc.w += bf2f(hv.w) * aa;
        }
    } else {
        float s0 = 0.f, s1 = 0.f, s2 = 0.f, s3 = 0.f;
        for (int i = beg + lane; i < end; i += 64) {
            int s = colsrc[i];
            float4 ev = *(const float4*)(es1 + s * 4);
            s0 += __expf(lrelu(ev.x + edv.x));
            s1 += __expf(lrelu(ev.y + edv.y));
            s2 += __expf(lrelu(ev.z + edv.z));
            s3 += __expf(lrelu(ev.w + edv.w));
        }
        #pragma unroll
        for (int off = 1; off < 64; off <<= 1) {
            s0 += __shfl_xor(s0, off);
            s1 += __shfl_xor(s1, off);
            s2 += __shfl_xor(s2, off);
            s3 += __shfl_xor(s3, off);
        }
        float r0 = 1.f / s0, r1 = 1.f / s1, r2 = 1.f / s2, r3 = 1.f / s3;
        for (int i = beg; i < end; ++i) {
            int s = colsrc[i];
            float4 ev = *(const float4*)(es1 + s * 4);
            float a0 = __expf(lrelu(ev.x + edv.x)) * r0;
            float a1 = __expf(lrelu(ev.y + edv.y)) * r1;
            float a2 = __expf(lrelu(ev.z + edv.z)) * r2;
            float a3 = __expf(lrelu(ev.w + edv.w)) * r3;
            float aa = head == 0 ? a0 : head == 1 ? a1 : head == 2 ? a2 : a3;
            ushort4 hv = *(const ushort4*)(h1b + (size_t)s * C1 + 4 * lane);
            acc.x += bf2f(hv.x) * aa;
            acc.y += bf2f(hv.y) * aa;
            acc.z += bf2f(hv.z) * aa;
            acc.w += bf2f(hv.w) * aa;
        }
    }

    float4 bv = *(const float4*)(b1 + 4 * lane);
    ushort4 o;
    o.x = f2bf(eluf(acc.x + bv.x));
    o.y = f2bf(eluf(acc.y + bv.y));
    o.z = f2bf(eluf(acc.z + bv.z));
    o.w = f2bf(eluf(acc.w + bv.w));
    *(ushort4*)(h1p + (size_t)n * C1 + 4 * lane) = o;
}

// ---------------- Layer 2 GEMM (MFMA bf16): h2b = bf16(h1p @ W2), fused es2/ed2 ----------------
__global__ __launch_bounds__(256) void k_gemm2(const unsigned short* __restrict__ h1p,
                                               const unsigned short* __restrict__ W2t,
                                               const float* __restrict__ as2,
                                               const float* __restrict__ ad2,
                                               unsigned short* __restrict__ h2b,
                                               float* __restrict__ es2,
                                               float* __restrict__ ed2) {
    int lane = threadIdx.x & 63, wv = threadIdx.x >> 6;
    int r0 = (blockIdx.x * 4 + wv) * 16;
    if (r0 >= NN) return;
    int g = lane >> 4, q = lane & 15;

    const unsigned short* ar = h1p + (size_t)(r0 + q) * C1;
    bf16x8 afr[8];
    #pragma unroll
    for (int kt = 0; kt < 8; ++kt)
        afr[kt] = *(const bf16x8*)(ar + kt * 32 + g * 8);

    float ps[4] = {0.f, 0.f, 0.f, 0.f};
    float pd[4] = {0.f, 0.f, 0.f, 0.f};
    #pragma unroll
    for (int t = 0; t < 4; ++t) {
        int col = t * 16 + q;
        const unsigned short* wb = W2t + (size_t)col * C1;
        f32x4 acc = {0.f, 0.f, 0.f, 0.f};
        #pragma unroll
        for (int kt = 0; kt < 8; ++kt) {
            bf16x8 b = *(const bf16x8*)(wb + kt * 32 + g * 8);
            acc = __builtin_amdgcn_mfma_f32_16x16x32_bf16(afr[kt], b, acc, 0, 0, 0);
        }
        float av = as2[col], bv = ad2[col];
        #pragma unroll
        for (int j = 0; j < 4; ++j) {
            int rr = r0 + g * 4 + j;
            h2b[(size_t)rr * HID + col] = f2bf(acc[j]);
            ps[j] += acc[j] * av;
            pd[j] += acc[j] * bv;
        }
    }
    #pragma unroll
    for (int j = 0; j < 4; ++j) {
        #pragma unroll
        for (int off = 1; off < 16; off <<= 1) {
            ps[j] += __shfl_xor(ps[j], off);
            pd[j] += __shfl_xor(pd[j], off);
        }
        if (q == 0) {
            int rr = r0 + g * 4 + j;
            es2[rr] = ps[j];
            ed2[rr] = pd[j];
        }
    }
}

// ---------------- Layer 2 aggregation + fused mean-pool atomics ----------------
__global__ __launch_bounds__(256) void k_agg2(const int* __restrict__ offs,
                                              const int* __restrict__ colsrc,
                                              const unsigned short* __restrict__ h2b,
                                              const float* __restrict__ es2,
                                              const float* __restrict__ ed2,
                                              const float* __restrict__ b2,
                                              const int* __restrict__ batch,
                                              float* __restrict__ pool,
                                              int* __restrict__ cnt) {
    int lane = threadIdx.x & 63, wv = threadIdx.x >> 6;
    int n = blockIdx.x * 4 + wv;
    if (n >= NN) return;
    int beg = offs[n], end = offs[n + 1], deg = end - beg;
    float edv = ed2[n];
    float acc = 0.f;

    if (deg <= 64) {
        int msrc = 0;
        float mex = 0.f;
        if (lane < deg) {
            msrc = colsrc[beg + lane];
            mex = __expf(lrelu(es2[msrc] + edv));
        }
        float ss = mex;
        #pragma unroll
        for (int off = 1; off < 64; off <<= 1) ss += __shfl_xor(ss, off);
        float rs = 1.f / ss;
        for (int i = 0; i < deg; ++i) {
            int s = __shfl(msrc, i);
            float a = __shfl(mex, i) * rs;
            acc += bf2f(h2b[(size_t)s * HID + lane]) * a;
        }
    } else {
        float ss = 0.f;
        for (int i = beg + lane; i < end; i += 64) {
            int s = colsrc[i];
            ss += __expf(lrelu(es2[s] + edv));
        }
        #pragma unroll
        for (int off = 1; off < 64; off <<= 1) ss += __shfl_xor(ss, off);
        float rs = 1.f / ss;
        for (int i = beg; i < end; ++i) {
            int s = colsrc[i];
            float a = __expf(lrelu(es2[s] + edv)) * rs;
            acc += bf2f(h2b[(size_t)s * HID + lane]) * a;
        }
    }

    float o = eluf(acc + b2[lane]);
    int g = batch[n];
    atomicAdd(&pool[(size_t)g * HID + lane], o);
    if (lane == 0) atomicAdd(&cnt[g], 1);
}

// ---------------- classifier ----------------
__global__ __launch_bounds__(256) void k_cls(const float* __restrict__ pool,
                                             const int* __restrict__ cnt,
                                             const float* __restrict__ Wc,
                                             const float* __restrict__ bc,
                                             float* __restrict__ out) {
    int lane = threadIdx.x & 63, wv = threadIdx.x >> 6;
    int g = blockIdx.x * 4 + wv;
    if (g >= NG) return;
    float c = fmaxf((float)cnt[g], 1.f);
    float p = pool[(size_t)g * HID + lane] / c;
    float s0 = p * Wc[lane * 2 + 0];
    float s1 = p * Wc[lane * 2 + 1];
    #pragma unroll
    for (int off = 1; off < 64; off <<= 1) {
        s0 += __shfl_xor(s0, off);
        s1 += __shfl_xor(s1, off);
    }
    if (lane == 0) {
        out[g * 2 + 0] = s0 + bc[0];
        out[g * 2 + 1] = s1 + bc[1];
    }
}

extern "C" void kernel_launch(void* const* d_in, const int* in_sizes, int n_in,
                              void* d_out, int out_size, void* d_ws, size_t ws_size,
                              hipStream_t stream) {
    const float* x   = (const float*)d_in[0];
    const int* ei    = (const int*)d_in[1];
    const int* batch = (const int*)d_in[2];
    const float* W1  = (const float*)d_in[4];
    const float* as1 = (const float*)d_in[5];
    const float* ad1 = (const float*)d_in[6];
    const float* b1  = (const float*)d_in[7];
    const float* W2  = (const float*)d_in[8];
    const float* as2 = (const float*)d_in[9];
    const float* ad2 = (const float*)d_in[10];
    const float* b2  = (const float*)d_in[11];
    const float* Wc  = (const float*)d_in[12];
    const float* bc  = (const float*)d_in[13];
    float* out = (float*)d_out;

    char* p = (char*)d_ws;
    auto alloc = [&](size_t bytes) -> char* {
        char* r = p;
        p += (bytes + 255) & ~(size_t)255;
        return r;
    };
    int* offs    = (int*)alloc((NN + 1) * sizeof(int));
    int* cursor  = (int*)alloc(NN * sizeof(int));
    int* deg     = (int*)alloc(NN * sizeof(int));
    int* colsrc  = (int*)alloc((size_t)ETOT * sizeof(int));
    int* bsum    = (int*)alloc(64 * sizeof(int));
    unsigned short* W1t = (unsigned short*)alloc((size_t)FIN * C1 * sizeof(short));
    unsigned short* W2t = (unsigned short*)alloc((size_t)C1 * HID * sizeof(short));
    unsigned short* h1b = (unsigned short*)alloc((size_t)NN * C1 * sizeof(short));
    unsigned short* h1p = (unsigned short*)alloc((size_t)NN * C1 * sizeof(short));
    unsigned short* h2b = (unsigned short*)alloc((size_t)NN * HID * sizeof(short));
    float* es1   = (float*)alloc((size_t)NN * 4 * sizeof(float));
    float* ed1   = (float*)alloc((size_t)NN * 4 * sizeof(float));
    float* es2v  = (float*)alloc((size_t)NN * sizeof(float));
    float* ed2v  = (float*)alloc((size_t)NN * sizeof(float));
    float* pool  = (float*)alloc((size_t)NG * HID * sizeof(float));
    int* cnt     = (int*)alloc(NG * sizeof(int));

    hipMemsetAsync(deg, 0, NN * sizeof(int), stream);
    hipMemsetAsync(pool, 0, (size_t)NG * HID * sizeof(float), stream);
    hipMemsetAsync(cnt, 0, NG * sizeof(int), stream);

    const int* srcA = ei;       // edge_index[0]
    const int* dstA = ei + NE;  // edge_index[1]

    k_prep<<<(FIN * C1 + C1 * HID + 255) / 256, 256, 0, stream>>>(W1, W2, W1t, W2t);
    k_deg<<<(NE + 255) / 256, 256, 0, stream>>>(dstA, deg);
    k_scan_blk<<<NBLK_SCAN, 1024, 0, stream>>>(deg, offs, bsum);
    k_scan_top<<<1, 64, 0, stream>>>(bsum, NBLK_SCAN);
    k_scan_add<<<(NN + 1 + 255) / 256, 256, 0, stream>>>(offs, bsum, cursor);
    k_fill<<<(ETOT + 255) / 256, 256, 0, stream>>>(srcA, dstA, cursor, colsrc);

    k_gemm1<<<(NN / 16 + 3) / 4, 256, 0, stream>>>(x, W1t, as1, ad1, h1b, es1, ed1);
    k_agg1<<<(NN + 3) / 4, 256, 0, stream>>>(offs, colsrc, h1b, es1, ed1, b1, h1p);
    k_gemm2<<<(NN / 16 + 3) / 4, 256, 0, stream>>>(h1p, W2t, as2, ad2, h2b, es2v, ed2v);
    k_agg2<<<(NN + 3) / 4, 256, 0, stream>>>(offs, colsrc, h2b, es2v, ed2v, b2, batch, pool, cnt);
    k_cls<<<(NG + 3) / 4, 256, 0, stream>>>(pool, cnt, Wc, bc, out);
}

// Round 3
// 377.027 us; speedup vs baseline: 1.7590x; 1.1263x over previous
//
#include <hip/hip_runtime.h>

#define NN   50000
#define NE   1000000
#define FIN  128
#define HID  64
#define HEADS 4
#define C1   256          // HEADS*HID
#define NG   512
#define ETOT (NE + NN)    // edges + self-loops
#define NBLK_SCAN 49      // ceil((NN+1)/1024)

typedef __attribute__((ext_vector_type(8))) short bf16x8;
typedef __attribute__((ext_vector_type(4))) short bf16x4;
typedef __attribute__((ext_vector_type(4))) float f32x4;

__device__ __forceinline__ float lrelu(float v) { return v > 0.f ? v : 0.2f * v; }
__device__ __forceinline__ float eluf(float v)  { return v > 0.f ? v : __expf(v) - 1.f; }

__device__ __forceinline__ unsigned short f2bf(float f) {
    unsigned u = __float_as_uint(f);
    unsigned r = (u + 0x7FFFu + ((u >> 16) & 1u)) >> 16;
    return (unsigned short)r;
}
__device__ __forceinline__ float bf2f(unsigned short b) {
    return __uint_as_float(((unsigned)b) << 16);
}

// ---------------- weight prep: transpose + bf16 cast ----------------
__global__ __launch_bounds__(256) void k_prep(const float* __restrict__ W1,
                                              const float* __restrict__ W2,
                                              unsigned short* __restrict__ W1t,
                                              unsigned short* __restrict__ W2t) {
    int i = blockIdx.x * 256 + threadIdx.x;
    if (i < FIN * C1) {
        int k = i / C1, c = i % C1;
        W1t[c * FIN + k] = f2bf(W1[i]);
    } else {
        int j = i - FIN * C1;
        if (j < C1 * HID) {
            int k = j / HID, c = j % HID;
            W2t[c * C1 + k] = f2bf(W2[j]);
        }
    }
}

// ---------------- CSR build ----------------
__global__ __launch_bounds__(256) void k_deg(const int* __restrict__ dst, int* __restrict__ deg) {
    int e = blockIdx.x * 256 + threadIdx.x;
    if (e < NE) atomicAdd(&deg[dst[e]], 1);
}

__global__ __launch_bounds__(1024) void k_scan_blk(const int* __restrict__ deg,
                                                   int* __restrict__ offs,
                                                   int* __restrict__ bsum) {
    int tid = threadIdx.x;
    int gid = blockIdx.x * 1024 + tid;
    int v = (gid < NN) ? deg[gid] + 1 : 0;
    int lane = tid & 63, wv = tid >> 6;
    int x = v;
    #pragma unroll
    for (int off = 1; off < 64; off <<= 1) {
        int t = __shfl_up(x, off);
        if (lane >= off) x += t;
    }
    __shared__ int ws[16];
    if (lane == 63) ws[wv] = x;
    __syncthreads();
    if (tid < 16) {
        int y = ws[tid];
        #pragma unroll
        for (int off = 1; off < 16; off <<= 1) {
            int t = __shfl_up(y, off);
            if (tid >= off) y += t;
        }
        ws[tid] = y;
    }
    __syncthreads();
    int base = wv ? ws[wv - 1] : 0;
    if (gid < NN + 1) offs[gid] = base + x - v;   // exclusive
    if (tid == 1023) bsum[blockIdx.x] = ws[15];
}

__global__ void k_scan_top(int* __restrict__ bsum, int nb) {
    int tid = threadIdx.x;
    int v = (tid < nb) ? bsum[tid] : 0;
    #pragma unroll
    for (int off = 1; off < 64; off <<= 1) {
        int t = __shfl_up(v, off);
        if (tid >= off) v += t;
    }
    if (tid < nb) bsum[tid] = v;  // inclusive
}

__global__ __launch_bounds__(256) void k_scan_add(int* __restrict__ offs,
                                                  const int* __restrict__ bsum,
                                                  int* __restrict__ cursor) {
    int i = blockIdx.x * 256 + threadIdx.x;
    if (i < NN + 1) {
        int blk = i >> 10;
        int o = offs[i] + (blk ? bsum[blk - 1] : 0);
        offs[i] = o;
        if (i < NN) cursor[i] = o;
    }
}

__global__ __launch_bounds__(256) void k_fill(const int* __restrict__ src,
                                              const int* __restrict__ dst,
                                              int* __restrict__ cursor,
                                              int* __restrict__ colsrc) {
    int i = blockIdx.x * 256 + threadIdx.x;
    if (i < NE) {
        int d = dst[i];
        int p = atomicAdd(&cursor[d], 1);
        colsrc[p] = src[i];
    } else if (i < ETOT) {
        int n = i - NE;
        int p = atomicAdd(&cursor[n], 1);
        colsrc[p] = n;      // self-loop
    }
}

// ---------------- Layer 1 GEMM (MFMA bf16, LDS-staged W) ----------------
// wave computes 16 rows x 256 cols. A: row=lane&15, k=(lane>>4)*8+j. B: col=lane&15.
// C: col=lane&15, row=(lane>>4)*4+reg  (guide §3, m89-verified)
__global__ __launch_bounds__(256) void k_gemm1(const float* __restrict__ x,
                                               const unsigned short* __restrict__ W1t,
                                               const float* __restrict__ asrc,
                                               const float* __restrict__ adst,
                                               unsigned short* __restrict__ h1b,
                                               float* __restrict__ es1,
                                               float* __restrict__ ed1) {
    __shared__ unsigned short Wl[128 * FIN];   // 32 KB: 128 cols x 128 k, swizzled
    int tid = threadIdx.x;
    int lane = tid & 63, wv = tid >> 6;
    int r0 = (blockIdx.x * 4 + wv) * 16;
    int g = lane >> 4, q = lane & 15;

    // load + convert A fragments (4 k-steps of 32); clamp OOB tiles (dup writes are identical)
    int ar = min(r0 + q, NN - 1);
    const float* xr = x + (size_t)ar * FIN;
    bf16x8 afr[4];
    #pragma unroll
    for (int kt = 0; kt < 4; ++kt) {
        float4 u0 = *(const float4*)(xr + kt * 32 + g * 8);
        float4 u1 = *(const float4*)(xr + kt * 32 + g * 8 + 4);
        bf16x8 a;
        a[0] = (short)f2bf(u0.x); a[1] = (short)f2bf(u0.y);
        a[2] = (short)f2bf(u0.z); a[3] = (short)f2bf(u0.w);
        a[4] = (short)f2bf(u1.x); a[5] = (short)f2bf(u1.y);
        a[6] = (short)f2bf(u1.z); a[7] = (short)f2bf(u1.w);
        afr[kt] = a;
    }

    for (int ch = 0; ch < 2; ++ch) {          // column halves: cols [0,128) then [128,256)
        if (ch) __syncthreads();
        const uint4* src = (const uint4*)(W1t + (size_t)ch * 128 * FIN);
        #pragma unroll
        for (int i = 0; i < 8; ++i) {         // 2048 uint4 = 32KB
            int idx = tid + i * 256;
            uint4 v = src[idx];
            unsigned byte = (unsigned)idx << 4;
            unsigned dst = byte ^ (((byte >> 8) & 7) << 4);
            *(uint4*)((char*)Wl + dst) = v;
        }
        __syncthreads();

        #pragma unroll
        for (int hh = 0; hh < 2; ++hh) {
            int h = ch * 2 + hh;
            float ps[4] = {0.f, 0.f, 0.f, 0.f};
            float pd[4] = {0.f, 0.f, 0.f, 0.f};
            #pragma unroll
            for (int tl = 0; tl < 4; ++tl) {
                int col = (h * 4 + tl) * 16 + q;
                int cl = col - ch * 128;
                f32x4 acc = {0.f, 0.f, 0.f, 0.f};
                #pragma unroll
                for (int kt = 0; kt < 4; ++kt) {
                    unsigned bb = (unsigned)cl * 256 + kt * 64 + g * 16;
                    bf16x8 b = *(const bf16x8*)((const char*)Wl + (bb ^ (((unsigned)cl & 7) << 4)));
                    acc = __builtin_amdgcn_mfma_f32_16x16x32_bf16(afr[kt], b, acc, 0, 0, 0);
                }
                float av = asrc[col], bv = adst[col];
                #pragma unroll
                for (int j = 0; j < 4; ++j) {
                    int rr = min(r0 + g * 4 + j, NN - 1);
                    h1b[(size_t)rr * C1 + col] = f2bf(acc[j]);
                    ps[j] += acc[j] * av;
                    pd[j] += acc[j] * bv;
                }
            }
            #pragma unroll
            for (int j = 0; j < 4; ++j) {
                #pragma unroll
                for (int off = 1; off < 16; off <<= 1) {
                    ps[j] += __shfl_xor(ps[j], off);
                    pd[j] += __shfl_xor(pd[j], off);
                }
                if (q == 0) {
                    int rr = min(r0 + g * 4 + j, NN - 1);
                    es1[rr * 4 + h] = ps[j];
                    ed1[rr * 4 + h] = pd[j];
                }
            }
        }
    }
}

// ---------------- Layer 1 aggregation: 2 edges/iter, 16B gathers ----------------
__global__ __launch_bounds__(256) void k_agg1(const int* __restrict__ offs,
                                              const int* __restrict__ colsrc,
                                              const unsigned short* __restrict__ h1b,
                                              const float* __restrict__ es1,
                                              const float* __restrict__ ed1,
                                              const float* __restrict__ b1,
                                              unsigned short* __restrict__ h1p) {
    int lane = threadIdx.x & 63, wv = threadIdx.x >> 6;
    int n = blockIdx.x * 4 + wv;
    if (n >= NN) return;
    int beg = offs[n], end = offs[n + 1], deg = end - beg;
    float4 edv = *(const float4*)(ed1 + n * 4);
    int half = lane >> 5, q5 = lane & 31;
    int hd = q5 >> 3;                         // head of this lane's 8 features
    float acc[8];
    #pragma unroll
    for (int j = 0; j < 8; ++j) acc[j] = 0.f;

    if (deg <= 64) {
        int msrc = 0;
        float m0 = 0.f, m1 = 0.f, m2 = 0.f, m3 = 0.f;
        if (lane < deg) {
            msrc = colsrc[beg + lane];
            float4 ev = *(const float4*)(es1 + msrc * 4);
            m0 = __expf(lrelu(ev.x + edv.x));
            m1 = __expf(lrelu(ev.y + edv.y));
            m2 = __expf(lrelu(ev.z + edv.z));
            m3 = __expf(lrelu(ev.w + edv.w));
        }
        float s0 = m0, s1 = m1, s2 = m2, s3 = m3;
        #pragma unroll
        for (int off = 1; off < 64; off <<= 1) {
            s0 += __shfl_xor(s0, off);
            s1 += __shfl_xor(s1, off);
            s2 += __shfl_xor(s2, off);
            s3 += __shfl_xor(s3, off);
        }
        m0 *= 1.f / s0; m1 *= 1.f / s1; m2 *= 1.f / s2; m3 *= 1.f / s3;  // pre-scaled alpha
        for (int i = 0; i < deg; i += 2) {
            int e = i + half;
            int s  = __shfl(msrc, e);
            float a0 = __shfl(m0, e), a1 = __shfl(m1, e), a2 = __shfl(m2, e), a3 = __shfl(m3, e);
            float a = hd == 0 ? a0 : hd == 1 ? a1 : hd == 2 ? a2 : a3;
            if (e < deg) {
                bf16x8 hv = *(const bf16x8*)(h1b + (size_t)s * C1 + q5 * 8);
                #pragma unroll
                for (int j = 0; j < 8; ++j) acc[j] += bf2f((unsigned short)hv[j]) * a;
            }
        }
    } else {
        float s0 = 0.f, s1 = 0.f, s2 = 0.f, s3 = 0.f;
        for (int i = beg + lane; i < end; i += 64) {
            int s = colsrc[i];
            float4 ev = *(const float4*)(es1 + s * 4);
            s0 += __expf(lrelu(ev.x + edv.x));
            s1 += __expf(lrelu(ev.y + edv.y));
            s2 += __expf(lrelu(ev.z + edv.z));
            s3 += __expf(lrelu(ev.w + edv.w));
        }
        #pragma unroll
        for (int off = 1; off < 64; off <<= 1) {
            s0 += __shfl_xor(s0, off);
            s1 += __shfl_xor(s1, off);
            s2 += __shfl_xor(s2, off);
            s3 += __shfl_xor(s3, off);
        }
        float rr = hd == 0 ? 1.f / s0 : hd == 1 ? 1.f / s1 : hd == 2 ? 1.f / s2 : 1.f / s3;
        float ed_h = hd == 0 ? edv.x : hd == 1 ? edv.y : hd == 2 ? edv.z : edv.w;
        for (int i = beg; i < end; i += 2) {
            int idx = i + half;
            if (idx < end) {
                int s = colsrc[idx];
                float eh = es1[s * 4 + hd] + ed_h;
                float a = __expf(lrelu(eh)) * rr;
                bf16x8 hv = *(const bf16x8*)(h1b + (size_t)s * C1 + q5 * 8);
                #pragma unroll
                for (int j = 0; j < 8; ++j) acc[j] += bf2f((unsigned short)hv[j]) * a;
            }
        }
    }

    #pragma unroll
    for (int j = 0; j < 8; ++j) acc[j] += __shfl_xor(acc[j], 32);

    if (half == 0) {
        float4 bv0 = *(const float4*)(b1 + q5 * 8);
        float4 bv1 = *(const float4*)(b1 + q5 * 8 + 4);
        bf16x8 o;
        o[0] = (short)f2bf(eluf(acc[0] + bv0.x));
        o[1] = (short)f2bf(eluf(acc[1] + bv0.y));
        o[2] = (short)f2bf(eluf(acc[2] + bv0.z));
        o[3] = (short)f2bf(eluf(acc[3] + bv0.w));
        o[4] = (short)f2bf(eluf(acc[4] + bv1.x));
        o[5] = (short)f2bf(eluf(acc[5] + bv1.y));
        o[6] = (short)f2bf(eluf(acc[6] + bv1.z));
        o[7] = (short)f2bf(eluf(acc[7] + bv1.w));
        *(bf16x8*)(h1p + (size_t)n * C1 + q5 * 8) = o;
    }
}

// ---------------- Layer 2 GEMM (MFMA bf16, LDS-staged W) ----------------
__global__ __launch_bounds__(256) void k_gemm2(const unsigned short* __restrict__ h1p,
                                               const unsigned short* __restrict__ W2t,
                                               const float* __restrict__ as2,
                                               const float* __restrict__ ad2,
                                               unsigned short* __restrict__ h2b,
                                               float* __restrict__ es2,
                                               float* __restrict__ ed2) {
    __shared__ unsigned short Wl[HID * C1];   // 32 KB: 64 cols x 256 k, swizzled (512B/col)
    int tid = threadIdx.x;
    int lane = tid & 63, wv = tid >> 6;
    int r0 = (blockIdx.x * 4 + wv) * 16;
    int g = lane >> 4, q = lane & 15;

    const uint4* src = (const uint4*)W2t;
    #pragma unroll
    for (int i = 0; i < 8; ++i) {             // 2048 uint4 = 32KB
        int idx = tid + i * 256;
        uint4 v = src[idx];
        unsigned byte = (unsigned)idx << 4;
        unsigned dst = byte ^ (((byte >> 9) & 7) << 4);
        *(uint4*)((char*)Wl + dst) = v;
    }

    int ar = min(r0 + q, NN - 1);
    const unsigned short* arp = h1p + (size_t)ar * C1;
    bf16x8 afr[8];
    #pragma unroll
    for (int kt = 0; kt < 8; ++kt)
        afr[kt] = *(const bf16x8*)(arp + kt * 32 + g * 8);

    __syncthreads();

    float ps[4] = {0.f, 0.f, 0.f, 0.f};
    float pd[4] = {0.f, 0.f, 0.f, 0.f};
    #pragma unroll
    for (int t = 0; t < 4; ++t) {
        int col = t * 16 + q;
        f32x4 acc = {0.f, 0.f, 0.f, 0.f};
        #pragma unroll
        for (int kt = 0; kt < 8; ++kt) {
            unsigned bb = (unsigned)col * 512 + kt * 64 + g * 16;
            bf16x8 b = *(const bf16x8*)((const char*)Wl + (bb ^ (((unsigned)col & 7) << 4)));
            acc = __builtin_amdgcn_mfma_f32_16x16x32_bf16(afr[kt], b, acc, 0, 0, 0);
        }
        float av = as2[col], bv = ad2[col];
        #pragma unroll
        for (int j = 0; j < 4; ++j) {
            int rr = min(r0 + g * 4 + j, NN - 1);
            h2b[(size_t)rr * HID + col] = f2bf(acc[j]);
            ps[j] += acc[j] * av;
            pd[j] += acc[j] * bv;
        }
    }
    #pragma unroll
    for (int j = 0; j < 4; ++j) {
        #pragma unroll
        for (int off = 1; off < 16; off <<= 1) {
            ps[j] += __shfl_xor(ps[j], off);
            pd[j] += __shfl_xor(pd[j], off);
        }
        if (q == 0) {
            int rr = min(r0 + g * 4 + j, NN - 1);
            es2[rr] = ps[j];
            ed2[rr] = pd[j];
        }
    }
}

// ---------------- Layer 2 aggregation: 4 edges/iter + fused mean-pool ----------------
__global__ __launch_bounds__(256) void k_agg2(const int* __restrict__ offs,
                                              const int* __restrict__ colsrc,
                                              const unsigned short* __restrict__ h2b,
                                              const float* __restrict__ es2,
                                              const float* __restrict__ ed2,
                                              const float* __restrict__ b2,
                                              const int* __restrict__ batch,
                                              float* __restrict__ pool,
                                              int* __restrict__ cnt) {
    int lane = threadIdx.x & 63, wv = threadIdx.x >> 6;
    int n = blockIdx.x * 4 + wv;
    if (n >= NN) return;
    int beg = offs[n], end = offs[n + 1], deg = end - beg;
    float edv = ed2[n];
    int g = lane >> 4, q = lane & 15;
    float acc[4] = {0.f, 0.f, 0.f, 0.f};

    if (deg <= 64) {
        int msrc = 0;
        float mex = 0.f;
        if (lane < deg) {
            msrc = colsrc[beg + lane];
            mex = __expf(lrelu(es2[msrc] + edv));
        }
        float ss = mex;
        #pragma unroll
        for (int off = 1; off < 64; off <<= 1) ss += __shfl_xor(ss, off);
        mex *= 1.f / ss;                       // pre-scaled alpha
        for (int i = 0; i < deg; i += 4) {
            int e = i + g;
            int s = __shfl(msrc, e);
            float a = __shfl(mex, e);
            if (e < deg) {
                bf16x4 hv = *(const bf16x4*)(h2b + (size_t)s * HID + q * 4);
                #pragma unroll
                for (int j = 0; j < 4; ++j) acc[j] += bf2f((unsigned short)hv[j]) * a;
            }
        }
    } else {
        float ss = 0.f;
        for (int i = beg + lane; i < end; i += 64) {
            int s = colsrc[i];
            ss += __expf(lrelu(es2[s] + edv));
        }
        #pragma unroll
        for (int off = 1; off < 64; off <<= 1) ss += __shfl_xor(ss, off);
        float rs = 1.f / ss;
        for (int i = beg; i < end; i += 4) {
            int idx = i + g;
            if (idx < end) {
                int s = colsrc[idx];
                float a = __expf(lrelu(es2[s] + edv)) * rs;
                bf16x4 hv = *(const bf16x4*)(h2b + (size_t)s * HID + q * 4);
                #pragma unroll
                for (int j = 0; j < 4; ++j) acc[j] += bf2f((unsigned short)hv[j]) * a;
            }
        }
    }

    #pragma unroll
    for (int j = 0; j < 4; ++j) {
        acc[j] += __shfl_xor(acc[j], 16);
        acc[j] += __shfl_xor(acc[j], 32);
    }

    if (g == 0) {
        int gr = batch[n];
        float4 bv = *(const float4*)(b2 + q * 4);
        atomicAdd(&pool[(size_t)gr * HID + q * 4 + 0], eluf(acc[0] + bv.x));
        atomicAdd(&pool[(size_t)gr * HID + q * 4 + 1], eluf(acc[1] + bv.y));
        atomicAdd(&pool[(size_t)gr * HID + q * 4 + 2], eluf(acc[2] + bv.z));
        atomicAdd(&pool[(size_t)gr * HID + q * 4 + 3], eluf(acc[3] + bv.w));
        if (lane == 0) atomicAdd(&cnt[gr], 1);
    }
}

// ---------------- classifier ----------------
__global__ __launch_bounds__(256) void k_cls(const float* __restrict__ pool,
                                             const int* __restrict__ cnt,
                                             const float* __restrict__ Wc,
                                             const float* __restrict__ bc,
                                             float* __restrict__ out) {
    int lane = threadIdx.x & 63, wv = threadIdx.x >> 6;
    int g = blockIdx.x * 4 + wv;
    if (g >= NG) return;
    float c = fmaxf((float)cnt[g], 1.f);
    float p = pool[(size_t)g * HID + lane] / c;
    float s0 = p * Wc[lane * 2 + 0];
    float s1 = p * Wc[lane * 2 + 1];
    #pragma unroll
    for (int off = 1; off < 64; off <<= 1) {
        s0 += __shfl_xor(s0, off);
        s1 += __shfl_xor(s1, off);
    }
    if (lane == 0) {
        out[g * 2 + 0] = s0 + bc[0];
        out[g * 2 + 1] = s1 + bc[1];
    }
}

extern "C" void kernel_launch(void* const* d_in, const int* in_sizes, int n_in,
                              void* d_out, int out_size, void* d_ws, size_t ws_size,
                              hipStream_t stream) {
    const float* x   = (const float*)d_in[0];
    const int* ei    = (const int*)d_in[1];
    const int* batch = (const int*)d_in[2];
    const float* W1  = (const float*)d_in[4];
    const float* as1 = (const float*)d_in[5];
    const float* ad1 = (const float*)d_in[6];
    const float* b1  = (const float*)d_in[7];
    const float* W2  = (const float*)d_in[8];
    const float* as2 = (const float*)d_in[9];
    const float* ad2 = (const float*)d_in[10];
    const float* b2  = (const float*)d_in[11];
    const float* Wc  = (const float*)d_in[12];
    const float* bc  = (const float*)d_in[13];
    float* out = (float*)d_out;

    char* p = (char*)d_ws;
    auto alloc = [&](size_t bytes) -> char* {
        char* r = p;
        p += (bytes + 255) & ~(size_t)255;
        return r;
    };
    int* offs    = (int*)alloc((NN + 1) * sizeof(int));
    int* cursor  = (int*)alloc(NN * sizeof(int));
    int* deg     = (int*)alloc(NN * sizeof(int));
    int* colsrc  = (int*)alloc((size_t)ETOT * sizeof(int));
    int* bsum    = (int*)alloc(64 * sizeof(int));
    unsigned short* W1t = (unsigned short*)alloc((size_t)FIN * C1 * sizeof(short));
    unsigned short* W2t = (unsigned short*)alloc((size_t)C1 * HID * sizeof(short));
    unsigned short* h1b = (unsigned short*)alloc((size_t)NN * C1 * sizeof(short));
    unsigned short* h1p = (unsigned short*)alloc((size_t)NN * C1 * sizeof(short));
    unsigned short* h2b = (unsigned short*)alloc((size_t)NN * HID * sizeof(short));
    float* es1   = (float*)alloc((size_t)NN * 4 * sizeof(float));
    float* ed1   = (float*)alloc((size_t)NN * 4 * sizeof(float));
    float* es2v  = (float*)alloc((size_t)NN * sizeof(float));
    float* ed2v  = (float*)alloc((size_t)NN * sizeof(float));
    float* pool  = (float*)alloc((size_t)NG * HID * sizeof(float));
    int* cnt     = (int*)alloc(NG * sizeof(int));

    hipMemsetAsync(deg, 0, NN * sizeof(int), stream);
    hipMemsetAsync(pool, 0, (size_t)NG * HID * sizeof(float), stream);
    hipMemsetAsync(cnt, 0, NG * sizeof(int), stream);

    const int* srcA = ei;       // edge_index[0]
    const int* dstA = ei + NE;  // edge_index[1]

    k_prep<<<(FIN * C1 + C1 * HID + 255) / 256, 256, 0, stream>>>(W1, W2, W1t, W2t);
    k_deg<<<(NE + 255) / 256, 256, 0, stream>>>(dstA, deg);
    k_scan_blk<<<NBLK_SCAN, 1024, 0, stream>>>(deg, offs, bsum);
    k_scan_top<<<1, 64, 0, stream>>>(bsum, NBLK_SCAN);
    k_scan_add<<<(NN + 1 + 255) / 256, 256, 0, stream>>>(offs, bsum, cursor);
    k_fill<<<(ETOT + 255) / 256, 256, 0, stream>>>(srcA, dstA, cursor, colsrc);

    k_gemm1<<<(NN / 16 + 3) / 4, 256, 0, stream>>>(x, W1t, as1, ad1, h1b, es1, ed1);
    k_agg1<<<(NN + 3) / 4, 256, 0, stream>>>(offs, colsrc, h1b, es1, ed1, b1, h1p);
    k_gemm2<<<(NN / 16 + 3) / 4, 256, 0, stream>>>(h1p, W2t, as2, ad2, h2b, es2v, ed2v);
    k_agg2<<<(NN + 3) / 4, 256, 0, stream>>>(offs, colsrc, h2b, es2v, ed2v, b2, batch, pool, cnt);
    k_cls<<<(NG + 3) / 4, 256, 0, stream>>>(pool, cnt, Wc, bc, out);
}

// Round 4
// 351.559 us; speedup vs baseline: 1.8864x; 1.0724x over previous
//
#include <hip/hip_runtime.h>

#define NN   50000
#define NE   1000000
#define FIN  128
#define HID  64
#define HEADS 4
#define C1   256          // HEADS*HID
#define NG   512
#define ETOT (NE + NN)    // edges + self-loops
#define NBLK_SCAN 49      // ceil((NN+1)/1024)

typedef __attribute__((ext_vector_type(8))) short bf16x8;
typedef __attribute__((ext_vector_type(4))) short bf16x4;
typedef __attribute__((ext_vector_type(4))) float f32x4;

__device__ __forceinline__ float lrelu(float v) { return v > 0.f ? v : 0.2f * v; }
__device__ __forceinline__ float eluf(float v)  { return v > 0.f ? v : __expf(v) - 1.f; }

__device__ __forceinline__ unsigned short f2bf(float f) {
    unsigned u = __float_as_uint(f);
    unsigned r = (u + 0x7FFFu + ((u >> 16) & 1u)) >> 16;
    return (unsigned short)r;
}
__device__ __forceinline__ float bf2f(unsigned short b) {
    return __uint_as_float(((unsigned)b) << 16);
}

// ---------------- weight prep: transpose + bf16 cast ----------------
__global__ __launch_bounds__(256) void k_prep(const float* __restrict__ W1,
                                              const float* __restrict__ W2,
                                              unsigned short* __restrict__ W1t,
                                              unsigned short* __restrict__ W2t) {
    int i = blockIdx.x * 256 + threadIdx.x;
    if (i < FIN * C1) {
        int k = i / C1, c = i % C1;
        W1t[c * FIN + k] = f2bf(W1[i]);
    } else {
        int j = i - FIN * C1;
        if (j < C1 * HID) {
            int k = j / HID, c = j % HID;
            W2t[c * C1 + k] = f2bf(W2[j]);
        }
    }
}

// ---------------- CSR build ----------------
__global__ __launch_bounds__(256) void k_deg(const int* __restrict__ dst, int* __restrict__ deg) {
    int e = blockIdx.x * 256 + threadIdx.x;
    if (e < NE) atomicAdd(&deg[dst[e]], 1);
}

__global__ __launch_bounds__(1024) void k_scan_blk(const int* __restrict__ deg,
                                                   int* __restrict__ offs,
                                                   int* __restrict__ bsum) {
    int tid = threadIdx.x;
    int gid = blockIdx.x * 1024 + tid;
    int v = (gid < NN) ? deg[gid] + 1 : 0;
    int lane = tid & 63, wv = tid >> 6;
    int x = v;
    #pragma unroll
    for (int off = 1; off < 64; off <<= 1) {
        int t = __shfl_up(x, off);
        if (lane >= off) x += t;
    }
    __shared__ int ws[16];
    if (lane == 63) ws[wv] = x;
    __syncthreads();
    if (tid < 16) {
        int y = ws[tid];
        #pragma unroll
        for (int off = 1; off < 16; off <<= 1) {
            int t = __shfl_up(y, off);
            if (tid >= off) y += t;
        }
        ws[tid] = y;
    }
    __syncthreads();
    int base = wv ? ws[wv - 1] : 0;
    if (gid < NN + 1) offs[gid] = base + x - v;   // exclusive
    if (tid == 1023) bsum[blockIdx.x] = ws[15];
}

__global__ void k_scan_top(int* __restrict__ bsum, int nb) {
    int tid = threadIdx.x;
    int v = (tid < nb) ? bsum[tid] : 0;
    #pragma unroll
    for (int off = 1; off < 64; off <<= 1) {
        int t = __shfl_up(v, off);
        if (tid >= off) v += t;
    }
    if (tid < nb) bsum[tid] = v;  // inclusive
}

__global__ __launch_bounds__(256) void k_scan_add(int* __restrict__ offs,
                                                  const int* __restrict__ bsum,
                                                  int* __restrict__ cursor) {
    int i = blockIdx.x * 256 + threadIdx.x;
    if (i < NN + 1) {
        int blk = i >> 10;
        int o = offs[i] + (blk ? bsum[blk - 1] : 0);
        offs[i] = o;
        if (i < NN) cursor[i] = o;
    }
}

__global__ __launch_bounds__(256) void k_fill(const int* __restrict__ src,
                                              const int* __restrict__ dst,
                                              int* __restrict__ cursor,
                                              int* __restrict__ colsrc) {
    int i = blockIdx.x * 256 + threadIdx.x;
    if (i < NE) {
        int d = dst[i];
        int p = atomicAdd(&cursor[d], 1);
        colsrc[p] = src[i];
    } else if (i < ETOT) {
        int n = i - NE;
        int p = atomicAdd(&cursor[n], 1);
        colsrc[p] = n;      // self-loop
    }
}

// ---------------- Layer 1 GEMM (MFMA bf16, LDS-staged W) ----------------
__global__ __launch_bounds__(256) void k_gemm1(const float* __restrict__ x,
                                               const unsigned short* __restrict__ W1t,
                                               const float* __restrict__ asrc,
                                               const float* __restrict__ adst,
                                               unsigned short* __restrict__ h1b,
                                               float* __restrict__ es1,
                                               float* __restrict__ ed1) {
    __shared__ unsigned short Wl[128 * FIN];   // 32 KB: 128 cols x 128 k, swizzled
    int tid = threadIdx.x;
    int lane = tid & 63, wv = tid >> 6;
    int r0 = (blockIdx.x * 4 + wv) * 16;
    int g = lane >> 4, q = lane & 15;

    int ar = min(r0 + q, NN - 1);
    const float* xr = x + (size_t)ar * FIN;
    bf16x8 afr[4];
    #pragma unroll
    for (int kt = 0; kt < 4; ++kt) {
        float4 u0 = *(const float4*)(xr + kt * 32 + g * 8);
        float4 u1 = *(const float4*)(xr + kt * 32 + g * 8 + 4);
        bf16x8 a;
        a[0] = (short)f2bf(u0.x); a[1] = (short)f2bf(u0.y);
        a[2] = (short)f2bf(u0.z); a[3] = (short)f2bf(u0.w);
        a[4] = (short)f2bf(u1.x); a[5] = (short)f2bf(u1.y);
        a[6] = (short)f2bf(u1.z); a[7] = (short)f2bf(u1.w);
        afr[kt] = a;
    }

    for (int ch = 0; ch < 2; ++ch) {          // column halves
        if (ch) __syncthreads();
        const uint4* src = (const uint4*)(W1t + (size_t)ch * 128 * FIN);
        #pragma unroll
        for (int i = 0; i < 8; ++i) {
            int idx = tid + i * 256;
            uint4 v = src[idx];
            unsigned byte = (unsigned)idx << 4;
            unsigned dst = byte ^ (((byte >> 8) & 7) << 4);
            *(uint4*)((char*)Wl + dst) = v;
        }
        __syncthreads();

        #pragma unroll
        for (int hh = 0; hh < 2; ++hh) {
            int h = ch * 2 + hh;
            float ps[4] = {0.f, 0.f, 0.f, 0.f};
            float pd[4] = {0.f, 0.f, 0.f, 0.f};
            #pragma unroll
            for (int tl = 0; tl < 4; ++tl) {
                int col = (h * 4 + tl) * 16 + q;
                int cl = col - ch * 128;
                f32x4 acc = {0.f, 0.f, 0.f, 0.f};
                #pragma unroll
                for (int kt = 0; kt < 4; ++kt) {
                    unsigned bb = (unsigned)cl * 256 + kt * 64 + g * 16;
                    bf16x8 b = *(const bf16x8*)((const char*)Wl + (bb ^ (((unsigned)cl & 7) << 4)));
                    acc = __builtin_amdgcn_mfma_f32_16x16x32_bf16(afr[kt], b, acc, 0, 0, 0);
                }
                float av = asrc[col], bv = adst[col];
                #pragma unroll
                for (int j = 0; j < 4; ++j) {
                    int rr = min(r0 + g * 4 + j, NN - 1);
                    h1b[(size_t)rr * C1 + col] = f2bf(acc[j]);
                    ps[j] += acc[j] * av;
                    pd[j] += acc[j] * bv;
                }
            }
            #pragma unroll
            for (int j = 0; j < 4; ++j) {
                #pragma unroll
                for (int off = 1; off < 16; off <<= 1) {
                    ps[j] += __shfl_xor(ps[j], off);
                    pd[j] += __shfl_xor(pd[j], off);
                }
                if (q == 0) {
                    int rr = min(r0 + g * 4 + j, NN - 1);
                    es1[rr * 4 + h] = ps[j];
                    ed1[rr * 4 + h] = pd[j];
                }
            }
        }
    }
}

// ---------------- Layer 1 aggregation: LDS-staged alpha, 8 edges/iter prefetch ----------------
__global__ __launch_bounds__(256) void k_agg1(const int* __restrict__ offs,
                                              const int* __restrict__ colsrc,
                                              const unsigned short* __restrict__ h1b,
                                              const float* __restrict__ es1,
                                              const float* __restrict__ ed1,
                                              const float* __restrict__ b1,
                                              unsigned short* __restrict__ h1p) {
    __shared__ int   sls[4][64];
    __shared__ float sla[4][64][4];
    int lane = threadIdx.x & 63, wv = threadIdx.x >> 6;
    int n = blockIdx.x * 4 + wv;
    if (n >= NN) return;
    int beg = offs[n], end = offs[n + 1], deg = end - beg;
    float4 edv = *(const float4*)(ed1 + n * 4);
    int half = lane >> 5, q5 = lane & 31;
    int hd = q5 >> 3;                         // head of this lane's 8 features
    float acc[8];
    #pragma unroll
    for (int j = 0; j < 8; ++j) acc[j] = 0.f;

    if (deg <= 64) {
        int msrc = 0;
        float m0 = 0.f, m1 = 0.f, m2 = 0.f, m3 = 0.f;
        if (lane < deg) {
            msrc = colsrc[beg + lane];
            float4 ev = *(const float4*)(es1 + msrc * 4);
            m0 = __expf(lrelu(ev.x + edv.x));
            m1 = __expf(lrelu(ev.y + edv.y));
            m2 = __expf(lrelu(ev.z + edv.z));
            m3 = __expf(lrelu(ev.w + edv.w));
        }
        float s0 = m0, s1 = m1, s2 = m2, s3 = m3;
        #pragma unroll
        for (int off = 1; off < 64; off <<= 1) {
            s0 += __shfl_xor(s0, off);
            s1 += __shfl_xor(s1, off);
            s2 += __shfl_xor(s2, off);
            s3 += __shfl_xor(s3, off);
        }
        sls[wv][lane] = msrc;
        sla[wv][lane][0] = m0 * (1.f / s0);   // zero beyond deg -> predication-free tail
        sla[wv][lane][1] = m1 * (1.f / s1);
        sla[wv][lane][2] = m2 * (1.f / s2);
        sla[wv][lane][3] = m3 * (1.f / s3);

        for (int i = 0; i < deg; i += 8) {
            int e0 = i + half, e1 = i + 2 + half, e2 = i + 4 + half, e3 = i + 6 + half;
            e0 &= 63; e1 &= 63; e2 &= 63; e3 &= 63;
            int   s0i = sls[wv][e0], s1i = sls[wv][e1], s2i = sls[wv][e2], s3i = sls[wv][e3];
            float a0 = sla[wv][e0][hd], a1 = sla[wv][e1][hd], a2 = sla[wv][e2][hd], a3 = sla[wv][e3][hd];
            bf16x8 h0 = *(const bf16x8*)(h1b + (size_t)s0i * C1 + q5 * 8);
            bf16x8 h1 = *(const bf16x8*)(h1b + (size_t)s1i * C1 + q5 * 8);
            bf16x8 h2 = *(const bf16x8*)(h1b + (size_t)s2i * C1 + q5 * 8);
            bf16x8 h3 = *(const bf16x8*)(h1b + (size_t)s3i * C1 + q5 * 8);
            #pragma unroll
            for (int j = 0; j < 8; ++j)
                acc[j] += bf2f((unsigned short)h0[j]) * a0 + bf2f((unsigned short)h1[j]) * a1
                        + bf2f((unsigned short)h2[j]) * a2 + bf2f((unsigned short)h3[j]) * a3;
        }
    } else {
        float s0 = 0.f, s1 = 0.f, s2 = 0.f, s3 = 0.f;
        for (int i = beg + lane; i < end; i += 64) {
            int s = colsrc[i];
            float4 ev = *(const float4*)(es1 + s * 4);
            s0 += __expf(lrelu(ev.x + edv.x));
            s1 += __expf(lrelu(ev.y + edv.y));
            s2 += __expf(lrelu(ev.z + edv.z));
            s3 += __expf(lrelu(ev.w + edv.w));
        }
        #pragma unroll
        for (int off = 1; off < 64; off <<= 1) {
            s0 += __shfl_xor(s0, off);
            s1 += __shfl_xor(s1, off);
            s2 += __shfl_xor(s2, off);
            s3 += __shfl_xor(s3, off);
        }
        float rr = hd == 0 ? 1.f / s0 : hd == 1 ? 1.f / s1 : hd == 2 ? 1.f / s2 : 1.f / s3;
        float ed_h = hd == 0 ? edv.x : hd == 1 ? edv.y : hd == 2 ? edv.z : edv.w;
        for (int i = beg; i < end; i += 2) {
            int idx = i + half;
            if (idx < end) {
                int s = colsrc[idx];
                float eh = es1[s * 4 + hd] + ed_h;
                float a = __expf(lrelu(eh)) * rr;
                bf16x8 hv = *(const bf16x8*)(h1b + (size_t)s * C1 + q5 * 8);
                #pragma unroll
                for (int j = 0; j < 8; ++j) acc[j] += bf2f((unsigned short)hv[j]) * a;
            }
        }
    }

    #pragma unroll
    for (int j = 0; j < 8; ++j) acc[j] += __shfl_xor(acc[j], 32);

    if (half == 0) {
        float4 bv0 = *(const float4*)(b1 + q5 * 8);
        float4 bv1 = *(const float4*)(b1 + q5 * 8 + 4);
        bf16x8 o;
        o[0] = (short)f2bf(eluf(acc[0] + bv0.x));
        o[1] = (short)f2bf(eluf(acc[1] + bv0.y));
        o[2] = (short)f2bf(eluf(acc[2] + bv0.z));
        o[3] = (short)f2bf(eluf(acc[3] + bv0.w));
        o[4] = (short)f2bf(eluf(acc[4] + bv1.x));
        o[5] = (short)f2bf(eluf(acc[5] + bv1.y));
        o[6] = (short)f2bf(eluf(acc[6] + bv1.z));
        o[7] = (short)f2bf(eluf(acc[7] + bv1.w));
        *(bf16x8*)(h1p + (size_t)n * C1 + q5 * 8) = o;
    }
}

// ---------------- Layer 2 GEMM (MFMA bf16, LDS-staged W) ----------------
__global__ __launch_bounds__(256) void k_gemm2(const unsigned short* __restrict__ h1p,
                                               const unsigned short* __restrict__ W2t,
                                               const float* __restrict__ as2,
                                               const float* __restrict__ ad2,
                                               unsigned short* __restrict__ h2b,
                                               float* __restrict__ es2,
                                               float* __restrict__ ed2) {
    __shared__ unsigned short Wl[HID * C1];   // 32 KB
    int tid = threadIdx.x;
    int lane = tid & 63, wv = tid >> 6;
    int r0 = (blockIdx.x * 4 + wv) * 16;
    int g = lane >> 4, q = lane & 15;

    const uint4* src = (const uint4*)W2t;
    #pragma unroll
    for (int i = 0; i < 8; ++i) {
        int idx = tid + i * 256;
        uint4 v = src[idx];
        unsigned byte = (unsigned)idx << 4;
        unsigned dst = byte ^ (((byte >> 9) & 7) << 4);
        *(uint4*)((char*)Wl + dst) = v;
    }

    int ar = min(r0 + q, NN - 1);
    const unsigned short* arp = h1p + (size_t)ar * C1;
    bf16x8 afr[8];
    #pragma unroll
    for (int kt = 0; kt < 8; ++kt)
        afr[kt] = *(const bf16x8*)(arp + kt * 32 + g * 8);

    __syncthreads();

    float ps[4] = {0.f, 0.f, 0.f, 0.f};
    float pd[4] = {0.f, 0.f, 0.f, 0.f};
    #pragma unroll
    for (int t = 0; t < 4; ++t) {
        int col = t * 16 + q;
        f32x4 acc = {0.f, 0.f, 0.f, 0.f};
        #pragma unroll
        for (int kt = 0; kt < 8; ++kt) {
            unsigned bb = (unsigned)col * 512 + kt * 64 + g * 16;
            bf16x8 b = *(const bf16x8*)((const char*)Wl + (bb ^ (((unsigned)col & 7) << 4)));
            acc = __builtin_amdgcn_mfma_f32_16x16x32_bf16(afr[kt], b, acc, 0, 0, 0);
        }
        float av = as2[col], bv = ad2[col];
        #pragma unroll
        for (int j = 0; j < 4; ++j) {
            int rr = min(r0 + g * 4 + j, NN - 1);
            h2b[(size_t)rr * HID + col] = f2bf(acc[j]);
            ps[j] += acc[j] * av;
            pd[j] += acc[j] * bv;
        }
    }
    #pragma unroll
    for (int j = 0; j < 4; ++j) {
        #pragma unroll
        for (int off = 1; off < 16; off <<= 1) {
            ps[j] += __shfl_xor(ps[j], off);
            pd[j] += __shfl_xor(pd[j], off);
        }
        if (q == 0) {
            int rr = min(r0 + g * 4 + j, NN - 1);
            es2[rr] = ps[j];
            ed2[rr] = pd[j];
        }
    }
}

// ---------------- Layer 2 aggregation: LDS-staged alpha, 16 edges/iter + pool ----------------
__global__ __launch_bounds__(256) void k_agg2(const int* __restrict__ offs,
                                              const int* __restrict__ colsrc,
                                              const unsigned short* __restrict__ h2b,
                                              const float* __restrict__ es2,
                                              const float* __restrict__ ed2,
                                              const float* __restrict__ b2,
                                              const int* __restrict__ batch,
                                              float* __restrict__ pool,
                                              int* __restrict__ cnt) {
    __shared__ int   sls[4][64];
    __shared__ float sla[4][64];
    int lane = threadIdx.x & 63, wv = threadIdx.x >> 6;
    int n = blockIdx.x * 4 + wv;
    if (n >= NN) return;
    int beg = offs[n], end = offs[n + 1], deg = end - beg;
    float edv = ed2[n];
    int g = lane >> 4, q = lane & 15;
    float acc[4] = {0.f, 0.f, 0.f, 0.f};

    if (deg <= 64) {
        int msrc = 0;
        float mex = 0.f;
        if (lane < deg) {
            msrc = colsrc[beg + lane];
            mex = __expf(lrelu(es2[msrc] + edv));
        }
        float ss = mex;
        #pragma unroll
        for (int off = 1; off < 64; off <<= 1) ss += __shfl_xor(ss, off);
        sls[wv][lane] = msrc;
        sla[wv][lane] = mex * (1.f / ss);     // zero beyond deg

        for (int i = 0; i < deg; i += 16) {
            int e0 = (i + g) & 63, e1 = (i + 4 + g) & 63, e2 = (i + 8 + g) & 63, e3 = (i + 12 + g) & 63;
            int   s0i = sls[wv][e0], s1i = sls[wv][e1], s2i = sls[wv][e2], s3i = sls[wv][e3];
            float a0 = sla[wv][e0], a1 = sla[wv][e1], a2 = sla[wv][e2], a3 = sla[wv][e3];
            bf16x4 h0 = *(const bf16x4*)(h2b + (size_t)s0i * HID + q * 4);
            bf16x4 h1 = *(const bf16x4*)(h2b + (size_t)s1i * HID + q * 4);
            bf16x4 h2v = *(const bf16x4*)(h2b + (size_t)s2i * HID + q * 4);
            bf16x4 h3 = *(const bf16x4*)(h2b + (size_t)s3i * HID + q * 4);
            #pragma unroll
            for (int j = 0; j < 4; ++j)
                acc[j] += bf2f((unsigned short)h0[j]) * a0 + bf2f((unsigned short)h1[j]) * a1
                        + bf2f((unsigned short)h2v[j]) * a2 + bf2f((unsigned short)h3[j]) * a3;
        }
    } else {
        float ss = 0.f;
        for (int i = beg + lane; i < end; i += 64) {
            int s = colsrc[i];
            ss += __expf(lrelu(es2[s] + edv));
        }
        #pragma unroll
        for (int off = 1; off < 64; off <<= 1) ss += __shfl_xor(ss, off);
        float rs = 1.f / ss;
        for (int i = beg; i < end; i += 4) {
            int idx = i + g;
            if (idx < end) {
                int s = colsrc[idx];
                float a = __expf(lrelu(es2[s] + edv)) * rs;
                bf16x4 hv = *(const bf16x4*)(h2b + (size_t)s * HID + q * 4);
                #pragma unroll
                for (int j = 0; j < 4; ++j) acc[j] += bf2f((unsigned short)hv[j]) * a;
            }
        }
    }

    #pragma unroll
    for (int j = 0; j < 4; ++j) {
        acc[j] += __shfl_xor(acc[j], 16);
        acc[j] += __shfl_xor(acc[j], 32);
    }

    // transpose: lane l takes feature l = q'*4+j' from lane q' = l>>2
    float v0 = __shfl(acc[0], lane >> 2);
    float v1 = __shfl(acc[1], lane >> 2);
    float v2 = __shfl(acc[2], lane >> 2);
    float v3 = __shfl(acc[3], lane >> 2);
    int jj = lane & 3;
    float o = jj == 0 ? v0 : jj == 1 ? v1 : jj == 2 ? v2 : v3;
    o = eluf(o + b2[lane]);
    int gr = batch[n];
    atomicAdd(&pool[(size_t)gr * HID + lane], o);
    if (lane == 0) atomicAdd(&cnt[gr], 1);
}

// ---------------- classifier ----------------
__global__ __launch_bounds__(256) void k_cls(const float* __restrict__ pool,
                                             const int* __restrict__ cnt,
                                             const float* __restrict__ Wc,
                                             const float* __restrict__ bc,
                                             float* __restrict__ out) {
    int lane = threadIdx.x & 63, wv = threadIdx.x >> 6;
    int g = blockIdx.x * 4 + wv;
    if (g >= NG) return;
    float c = fmaxf((float)cnt[g], 1.f);
    float p = pool[(size_t)g * HID + lane] / c;
    float s0 = p * Wc[lane * 2 + 0];
    float s1 = p * Wc[lane * 2 + 1];
    #pragma unroll
    for (int off = 1; off < 64; off <<= 1) {
        s0 += __shfl_xor(s0, off);
        s1 += __shfl_xor(s1, off);
    }
    if (lane == 0) {
        out[g * 2 + 0] = s0 + bc[0];
        out[g * 2 + 1] = s1 + bc[1];
    }
}

extern "C" void kernel_launch(void* const* d_in, const int* in_sizes, int n_in,
                              void* d_out, int out_size, void* d_ws, size_t ws_size,
                              hipStream_t stream) {
    const float* x   = (const float*)d_in[0];
    const int* ei    = (const int*)d_in[1];
    const int* batch = (const int*)d_in[2];
    const float* W1  = (const float*)d_in[4];
    const float* as1 = (const float*)d_in[5];
    const float* ad1 = (const float*)d_in[6];
    const float* b1  = (const float*)d_in[7];
    const float* W2  = (const float*)d_in[8];
    const float* as2 = (const float*)d_in[9];
    const float* ad2 = (const float*)d_in[10];
    const float* b2  = (const float*)d_in[11];
    const float* Wc  = (const float*)d_in[12];
    const float* bc  = (const float*)d_in[13];
    float* out = (float*)d_out;

    char* p = (char*)d_ws;
    auto alloc = [&](size_t bytes) -> char* {
        char* r = p;
        p += (bytes + 255) & ~(size_t)255;
        return r;
    };
    int* offs    = (int*)alloc((NN + 1) * sizeof(int));
    int* cursor  = (int*)alloc(NN * sizeof(int));
    int* deg     = (int*)alloc(NN * sizeof(int));
    int* colsrc  = (int*)alloc((size_t)ETOT * sizeof(int));
    int* bsum    = (int*)alloc(64 * sizeof(int));
    unsigned short* W1t = (unsigned short*)alloc((size_t)FIN * C1 * sizeof(short));
    unsigned short* W2t = (unsigned short*)alloc((size_t)C1 * HID * sizeof(short));
    unsigned short* h1b = (unsigned short*)alloc((size_t)NN * C1 * sizeof(short));
    unsigned short* h1p = (unsigned short*)alloc((size_t)NN * C1 * sizeof(short));
    unsigned short* h2b = (unsigned short*)alloc((size_t)NN * HID * sizeof(short));
    float* es1   = (float*)alloc((size_t)NN * 4 * sizeof(float));
    float* ed1   = (float*)alloc((size_t)NN * 4 * sizeof(float));
    float* es2v  = (float*)alloc((size_t)NN * sizeof(float));
    float* ed2v  = (float*)alloc((size_t)NN * sizeof(float));
    float* pool  = (float*)alloc((size_t)NG * HID * sizeof(float));
    int* cnt     = (int*)alloc(NG * sizeof(int));

    hipMemsetAsync(deg, 0, NN * sizeof(int), stream);
    hipMemsetAsync(pool, 0, (size_t)NG * HID * sizeof(float), stream);
    hipMemsetAsync(cnt, 0, NG * sizeof(int), stream);

    const int* srcA = ei;       // edge_index[0]
    const int* dstA = ei + NE;  // edge_index[1]

    k_prep<<<(FIN * C1 + C1 * HID + 255) / 256, 256, 0, stream>>>(W1, W2, W1t, W2t);
    k_deg<<<(NE + 255) / 256, 256, 0, stream>>>(dstA, deg);
    k_scan_blk<<<NBLK_SCAN, 1024, 0, stream>>>(deg, offs, bsum);
    k_scan_top<<<1, 64, 0, stream>>>(bsum, NBLK_SCAN);
    k_scan_add<<<(NN + 1 + 255) / 256, 256, 0, stream>>>(offs, bsum, cursor);
    k_fill<<<(ETOT + 255) / 256, 256, 0, stream>>>(srcA, dstA, cursor, colsrc);

    k_gemm1<<<(NN / 16 + 3) / 4, 256, 0, stream>>>(x, W1t, as1, ad1, h1b, es1, ed1);
    k_agg1<<<(NN + 3) / 4, 256, 0, stream>>>(offs, colsrc, h1b, es1, ed1, b1, h1p);
    k_gemm2<<<(NN / 16 + 3) / 4, 256, 0, stream>>>(h1p, W2t, as2, ad2, h2b, es2v, ed2v);
    k_agg2<<<(NN + 3) / 4, 256, 0, stream>>>(offs, colsrc, h2b, es2v, ed2v, b2, batch, pool, cnt);
    k_cls<<<(NG + 3) / 4, 256, 0, stream>>>(pool, cnt, Wc, bc, out);
}

// Round 6
// 291.060 us; speedup vs baseline: 2.2785x; 1.2079x over previous
//
#include <hip/hip_runtime.h>

#define NN   50000
#define NE   1000000
#define FIN  128
#define HID  64
#define HEADS 4
#define C1   256          // HEADS*HID
#define NG   512
#define ETOT (NE + NN)    // edges + self-loops
#define NBLK_SCAN 49      // ceil((NN+1)/1024)

typedef __attribute__((ext_vector_type(8))) short bf16x8;
typedef __attribute__((ext_vector_type(4))) short bf16x4;
typedef __attribute__((ext_vector_type(4))) float f32x4;

__device__ __forceinline__ float lrelu(float v) { return v > 0.f ? v : 0.2f * v; }
__device__ __forceinline__ float eluf(float v)  { return v > 0.f ? v : __expf(v) - 1.f; }

__device__ __forceinline__ unsigned short f2bf(float f) {
    unsigned u = __float_as_uint(f);
    unsigned r = (u + 0x7FFFu + ((u >> 16) & 1u)) >> 16;
    return (unsigned short)r;
}
__device__ __forceinline__ float bf2f(unsigned short b) {
    return __uint_as_float(((unsigned)b) << 16);
}

// ---------------- weight prep: transpose + bf16 cast ----------------
__global__ __launch_bounds__(256) void k_prep(const float* __restrict__ W1,
                                              const float* __restrict__ W2,
                                              unsigned short* __restrict__ W1t,
                                              unsigned short* __restrict__ W2t) {
    int i = blockIdx.x * 256 + threadIdx.x;
    if (i < FIN * C1) {
        int k = i / C1, c = i % C1;
        W1t[c * FIN + k] = f2bf(W1[i]);
    } else {
        int j = i - FIN * C1;
        if (j < C1 * HID) {
            int k = j / HID, c = j % HID;
            W2t[c * C1 + k] = f2bf(W2[j]);
        }
    }
}

// ---------------- CSR build ----------------
__global__ __launch_bounds__(256) void k_deg(const int* __restrict__ dst, int* __restrict__ deg) {
    int e = blockIdx.x * 256 + threadIdx.x;
    if (e < NE) atomicAdd(&deg[dst[e]], 1);
}

__global__ __launch_bounds__(1024) void k_scan_blk(const int* __restrict__ deg,
                                                   int* __restrict__ offs,
                                                   int* __restrict__ bsum) {
    int tid = threadIdx.x;
    int gid = blockIdx.x * 1024 + tid;
    int v = (gid < NN) ? deg[gid] + 1 : 0;
    int lane = tid & 63, wv = tid >> 6;
    int x = v;
    #pragma unroll
    for (int off = 1; off < 64; off <<= 1) {
        int t = __shfl_up(x, off);
        if (lane >= off) x += t;
    }
    __shared__ int ws[16];
    if (lane == 63) ws[wv] = x;
    __syncthreads();
    if (tid < 16) {
        int y = ws[tid];
        #pragma unroll
        for (int off = 1; off < 16; off <<= 1) {
            int t = __shfl_up(y, off);
            if (tid >= off) y += t;
        }
        ws[tid] = y;
    }
    __syncthreads();
    int base = wv ? ws[wv - 1] : 0;
    if (gid < NN + 1) offs[gid] = base + x - v;   // exclusive
    if (tid == 1023) bsum[blockIdx.x] = ws[15];
}

__global__ void k_scan_top(int* __restrict__ bsum, int nb) {
    int tid = threadIdx.x;
    int v = (tid < nb) ? bsum[tid] : 0;
    #pragma unroll
    for (int off = 1; off < 64; off <<= 1) {
        int t = __shfl_up(v, off);
        if (tid >= off) v += t;
    }
    if (tid < nb) bsum[tid] = v;  // inclusive
}

__global__ __launch_bounds__(256) void k_scan_add(int* __restrict__ offs,
                                                  const int* __restrict__ bsum,
                                                  int* __restrict__ cursor) {
    int i = blockIdx.x * 256 + threadIdx.x;
    if (i < NN + 1) {
        int blk = i >> 10;
        int o = offs[i] + (blk ? bsum[blk - 1] : 0);
        offs[i] = o;
        if (i < NN) cursor[i] = o;
    }
}

__global__ __launch_bounds__(256) void k_fill(const int* __restrict__ src,
                                              const int* __restrict__ dst,
                                              int* __restrict__ cursor,
                                              int* __restrict__ colsrc) {
    int i = blockIdx.x * 256 + threadIdx.x;
    if (i < NE) {
        int d = dst[i];
        int p = atomicAdd(&cursor[d], 1);
        colsrc[p] = src[i];
    } else if (i < ETOT) {
        int n = i - NE;
        int p = atomicAdd(&cursor[n], 1);
        colsrc[p] = n;      // self-loop
    }
}

// ---------------- graph boundaries: gstart[g] = lower_bound(batch, g), g in [0,NG] ----------------
__global__ __launch_bounds__(512) void k_gstart(const int* __restrict__ batch,
                                                int* __restrict__ gstart) {
    for (int g = threadIdx.x; g <= NG; g += 512) {   // 513 entries (incl. gstart[NG] = NN)
        int lo = 0, hi = NN;
        while (lo < hi) {
            int mid = (lo + hi) >> 1;
            if (batch[mid] < g) lo = mid + 1; else hi = mid;
        }
        gstart[g] = lo;
    }
}

// ---------------- Layer 1 GEMM (MFMA bf16, LDS-staged W) ----------------
__global__ __launch_bounds__(256) void k_gemm1(const float* __restrict__ x,
                                               const unsigned short* __restrict__ W1t,
                                               const float* __restrict__ asrc,
                                               const float* __restrict__ adst,
                                               unsigned short* __restrict__ h1b,
                                               float* __restrict__ es1,
                                               float* __restrict__ ed1) {
    __shared__ unsigned short Wl[128 * FIN];   // 32 KB: 128 cols x 128 k, swizzled
    int tid = threadIdx.x;
    int lane = tid & 63, wv = tid >> 6;
    int r0 = (blockIdx.x * 4 + wv) * 16;
    int g = lane >> 4, q = lane & 15;

    int ar = min(r0 + q, NN - 1);
    const float* xr = x + (size_t)ar * FIN;
    bf16x8 afr[4];
    #pragma unroll
    for (int kt = 0; kt < 4; ++kt) {
        float4 u0 = *(const float4*)(xr + kt * 32 + g * 8);
        float4 u1 = *(const float4*)(xr + kt * 32 + g * 8 + 4);
        bf16x8 a;
        a[0] = (short)f2bf(u0.x); a[1] = (short)f2bf(u0.y);
        a[2] = (short)f2bf(u0.z); a[3] = (short)f2bf(u0.w);
        a[4] = (short)f2bf(u1.x); a[5] = (short)f2bf(u1.y);
        a[6] = (short)f2bf(u1.z); a[7] = (short)f2bf(u1.w);
        afr[kt] = a;
    }

    for (int ch = 0; ch < 2; ++ch) {          // column halves
        if (ch) __syncthreads();
        const uint4* src = (const uint4*)(W1t + (size_t)ch * 128 * FIN);
        #pragma unroll
        for (int i = 0; i < 8; ++i) {
            int idx = tid + i * 256;
            uint4 v = src[idx];
            unsigned byte = (unsigned)idx << 4;
            unsigned dst = byte ^ (((byte >> 8) & 7) << 4);
            *(uint4*)((char*)Wl + dst) = v;
        }
        __syncthreads();

        #pragma unroll
        for (int hh = 0; hh < 2; ++hh) {
            int h = ch * 2 + hh;
            float ps[4] = {0.f, 0.f, 0.f, 0.f};
            float pd[4] = {0.f, 0.f, 0.f, 0.f};
            #pragma unroll
            for (int tl = 0; tl < 4; ++tl) {
                int col = (h * 4 + tl) * 16 + q;
                int cl = col - ch * 128;
                f32x4 acc = {0.f, 0.f, 0.f, 0.f};
                #pragma unroll
                for (int kt = 0; kt < 4; ++kt) {
                    unsigned bb = (unsigned)cl * 256 + kt * 64 + g * 16;
                    bf16x8 b = *(const bf16x8*)((const char*)Wl + (bb ^ (((unsigned)cl & 7) << 4)));
                    acc = __builtin_amdgcn_mfma_f32_16x16x32_bf16(afr[kt], b, acc, 0, 0, 0);
                }
                float av = asrc[col], bv = adst[col];
                #pragma unroll
                for (int j = 0; j < 4; ++j) {
                    int rr = min(r0 + g * 4 + j, NN - 1);
                    h1b[(size_t)rr * C1 + col] = f2bf(acc[j]);
                    ps[j] += acc[j] * av;
                    pd[j] += acc[j] * bv;
                }
            }
            #pragma unroll
            for (int j = 0; j < 4; ++j) {
                #pragma unroll
                for (int off = 1; off < 16; off <<= 1) {
                    ps[j] += __shfl_xor(ps[j], off);
                    pd[j] += __shfl_xor(pd[j], off);
                }
                if (q == 0) {
                    int rr = min(r0 + g * 4 + j, NN - 1);
                    es1[rr * 4 + h] = ps[j];
                    ed1[rr * 4 + h] = pd[j];
                }
            }
        }
    }
}

// ---------------- Layer 1 aggregation: 8 waves/block, LDS alpha, 8 edges/iter ----------------
__global__ __launch_bounds__(512) void k_agg1(const int* __restrict__ offs,
                                              const int* __restrict__ colsrc,
                                              const unsigned short* __restrict__ h1b,
                                              const float* __restrict__ es1,
                                              const float* __restrict__ ed1,
                                              const float* __restrict__ b1,
                                              unsigned short* __restrict__ h1p) {
    __shared__ int   sls[8][64];
    __shared__ float sla[8][64][4];
    int lane = threadIdx.x & 63, wv = threadIdx.x >> 6;
    int n = blockIdx.x * 8 + wv;
    if (n >= NN) return;
    int beg = offs[n], end = offs[n + 1], deg = end - beg;
    float4 edv = *(const float4*)(ed1 + n * 4);
    int half = lane >> 5, q5 = lane & 31;
    int hd = q5 >> 3;                         // head of this lane's 8 features
    float acc[8];
    #pragma unroll
    for (int j = 0; j < 8; ++j) acc[j] = 0.f;

    if (deg <= 64) {
        int msrc = 0;
        float m0 = 0.f, m1 = 0.f, m2 = 0.f, m3 = 0.f;
        if (lane < deg) {
            msrc = colsrc[beg + lane];
            float4 ev = *(const float4*)(es1 + msrc * 4);
            m0 = __expf(lrelu(ev.x + edv.x));
            m1 = __expf(lrelu(ev.y + edv.y));
            m2 = __expf(lrelu(ev.z + edv.z));
            m3 = __expf(lrelu(ev.w + edv.w));
        }
        float s0 = m0, s1 = m1, s2 = m2, s3 = m3;
        #pragma unroll
        for (int off = 1; off < 64; off <<= 1) {
            s0 += __shfl_xor(s0, off);
            s1 += __shfl_xor(s1, off);
            s2 += __shfl_xor(s2, off);
            s3 += __shfl_xor(s3, off);
        }
        sls[wv][lane] = msrc;
        sla[wv][lane][0] = m0 * (1.f / s0);   // zero beyond deg -> predication-free tail
        sla[wv][lane][1] = m1 * (1.f / s1);
        sla[wv][lane][2] = m2 * (1.f / s2);
        sla[wv][lane][3] = m3 * (1.f / s3);

        for (int i = 0; i < deg; i += 8) {
            int e0 = (i + half) & 63, e1 = (i + 2 + half) & 63, e2 = (i + 4 + half) & 63, e3 = (i + 6 + half) & 63;
            int   s0i = sls[wv][e0], s1i = sls[wv][e1], s2i = sls[wv][e2], s3i = sls[wv][e3];
            float a0 = sla[wv][e0][hd], a1 = sla[wv][e1][hd], a2 = sla[wv][e2][hd], a3 = sla[wv][e3][hd];
            bf16x8 h0 = *(const bf16x8*)(h1b + (size_t)s0i * C1 + q5 * 8);
            bf16x8 h1 = *(const bf16x8*)(h1b + (size_t)s1i * C1 + q5 * 8);
            bf16x8 h2 = *(const bf16x8*)(h1b + (size_t)s2i * C1 + q5 * 8);
            bf16x8 h3 = *(const bf16x8*)(h1b + (size_t)s3i * C1 + q5 * 8);
            #pragma unroll
            for (int j = 0; j < 8; ++j)
                acc[j] += bf2f((unsigned short)h0[j]) * a0 + bf2f((unsigned short)h1[j]) * a1
                        + bf2f((unsigned short)h2[j]) * a2 + bf2f((unsigned short)h3[j]) * a3;
        }
    } else {
        float s0 = 0.f, s1 = 0.f, s2 = 0.f, s3 = 0.f;
        for (int i = beg + lane; i < end; i += 64) {
            int s = colsrc[i];
            float4 ev = *(const float4*)(es1 + s * 4);
            s0 += __expf(lrelu(ev.x + edv.x));
            s1 += __expf(lrelu(ev.y + edv.y));
            s2 += __expf(lrelu(ev.z + edv.z));
            s3 += __expf(lrelu(ev.w + edv.w));
        }
        #pragma unroll
        for (int off = 1; off < 64; off <<= 1) {
            s0 += __shfl_xor(s0, off);
            s1 += __shfl_xor(s1, off);
            s2 += __shfl_xor(s2, off);
            s3 += __shfl_xor(s3, off);
        }
        float rr = hd == 0 ? 1.f / s0 : hd == 1 ? 1.f / s1 : hd == 2 ? 1.f / s2 : 1.f / s3;
        float ed_h = hd == 0 ? edv.x : hd == 1 ? edv.y : hd == 2 ? edv.z : edv.w;
        for (int i = beg; i < end; i += 2) {
            int idx = i + half;
            if (idx < end) {
                int s = colsrc[idx];
                float eh = es1[s * 4 + hd] + ed_h;
                float a = __expf(lrelu(eh)) * rr;
                bf16x8 hv = *(const bf16x8*)(h1b + (size_t)s * C1 + q5 * 8);
                #pragma unroll
                for (int j = 0; j < 8; ++j) acc[j] += bf2f((unsigned short)hv[j]) * a;
            }
        }
    }

    #pragma unroll
    for (int j = 0; j < 8; ++j) acc[j] += __shfl_xor(acc[j], 32);

    if (half == 0) {
        float4 bv0 = *(const float4*)(b1 + q5 * 8);
        float4 bv1 = *(const float4*)(b1 + q5 * 8 + 4);
        bf16x8 o;
        o[0] = (short)f2bf(eluf(acc[0] + bv0.x));
        o[1] = (short)f2bf(eluf(acc[1] + bv0.y));
        o[2] = (short)f2bf(eluf(acc[2] + bv0.z));
        o[3] = (short)f2bf(eluf(acc[3] + bv0.w));
        o[4] = (short)f2bf(eluf(acc[4] + bv1.x));
        o[5] = (short)f2bf(eluf(acc[5] + bv1.y));
        o[6] = (short)f2bf(eluf(acc[6] + bv1.z));
        o[7] = (short)f2bf(eluf(acc[7] + bv1.w));
        *(bf16x8*)(h1p + (size_t)n * C1 + q5 * 8) = o;
    }
}

// ---------------- Layer 2 GEMM (MFMA bf16, LDS-staged W) ----------------
__global__ __launch_bounds__(256) void k_gemm2(const unsigned short* __restrict__ h1p,
                                               const unsigned short* __restrict__ W2t,
                                               const float* __restrict__ as2,
                                               const float* __restrict__ ad2,
                                               unsigned short* __restrict__ h2b,
                                               float* __restrict__ es2,
                                               float* __restrict__ ed2) {
    __shared__ unsigned short Wl[HID * C1];   // 32 KB
    int tid = threadIdx.x;
    int lane = tid & 63, wv = tid >> 6;
    int r0 = (blockIdx.x * 4 + wv) * 16;
    int g = lane >> 4, q = lane & 15;

    const uint4* src = (const uint4*)W2t;
    #pragma unroll
    for (int i = 0; i < 8; ++i) {
        int idx = tid + i * 256;
        uint4 v = src[idx];
        unsigned byte = (unsigned)idx << 4;
        unsigned dst = byte ^ (((byte >> 9) & 7) << 4);
        *(uint4*)((char*)Wl + dst) = v;
    }

    int ar = min(r0 + q, NN - 1);
    const unsigned short* arp = h1p + (size_t)ar * C1;
    bf16x8 afr[8];
    #pragma unroll
    for (int kt = 0; kt < 8; ++kt)
        afr[kt] = *(const bf16x8*)(arp + kt * 32 + g * 8);

    __syncthreads();

    float ps[4] = {0.f, 0.f, 0.f, 0.f};
    float pd[4] = {0.f, 0.f, 0.f, 0.f};
    #pragma unroll
    for (int t = 0; t < 4; ++t) {
        int col = t * 16 + q;
        f32x4 acc = {0.f, 0.f, 0.f, 0.f};
        #pragma unroll
        for (int kt = 0; kt < 8; ++kt) {
            unsigned bb = (unsigned)col * 512 + kt * 64 + g * 16;
            bf16x8 b = *(const bf16x8*)((const char*)Wl + (bb ^ (((unsigned)col & 7) << 4)));
            acc = __builtin_amdgcn_mfma_f32_16x16x32_bf16(afr[kt], b, acc, 0, 0, 0);
        }
        float av = as2[col], bv = ad2[col];
        #pragma unroll
        for (int j = 0; j < 4; ++j) {
            int rr = min(r0 + g * 4 + j, NN - 1);
            h2b[(size_t)rr * HID + col] = f2bf(acc[j]);
            ps[j] += acc[j] * av;
            pd[j] += acc[j] * bv;
        }
    }
    #pragma unroll
    for (int j = 0; j < 4; ++j) {
        #pragma unroll
        for (int off = 1; off < 16; off <<= 1) {
            ps[j] += __shfl_xor(ps[j], off);
            pd[j] += __shfl_xor(pd[j], off);
        }
        if (q == 0) {
            int rr = min(r0 + g * 4 + j, NN - 1);
            es2[rr] = ps[j];
            ed2[rr] = pd[j];
        }
    }
}

// ---------------- Layer 2 aggregation: dense h3 output (no atomics) ----------------
__global__ __launch_bounds__(512) void k_agg2(const int* __restrict__ offs,
                                              const int* __restrict__ colsrc,
                                              const unsigned short* __restrict__ h2b,
                                              const float* __restrict__ es2,
                                              const float* __restrict__ ed2,
                                              const float* __restrict__ b2,
                                              float* __restrict__ h3) {
    __shared__ int   sls[8][64];
    __shared__ float sla[8][64];
    int lane = threadIdx.x & 63, wv = threadIdx.x >> 6;
    int n = blockIdx.x * 8 + wv;
    if (n >= NN) return;
    int beg = offs[n], end = offs[n + 1], deg = end - beg;
    float edv = ed2[n];
    int g = lane >> 4, q = lane & 15;
    float acc[4] = {0.f, 0.f, 0.f, 0.f};

    if (deg <= 64) {
        int msrc = 0;
        float mex = 0.f;
        if (lane < deg) {
            msrc = colsrc[beg + lane];
            mex = __expf(lrelu(es2[msrc] + edv));
        }
        float ss = mex;
        #pragma unroll
        for (int off = 1; off < 64; off <<= 1) ss += __shfl_xor(ss, off);
        sls[wv][lane] = msrc;
        sla[wv][lane] = mex * (1.f / ss);     // zero beyond deg

        for (int i = 0; i < deg; i += 16) {
            int e0 = (i + g) & 63, e1 = (i + 4 + g) & 63, e2 = (i + 8 + g) & 63, e3 = (i + 12 + g) & 63;
            int   s0i = sls[wv][e0], s1i = sls[wv][e1], s2i = sls[wv][e2], s3i = sls[wv][e3];
            float a0 = sla[wv][e0], a1 = sla[wv][e1], a2 = sla[wv][e2], a3 = sla[wv][e3];
            bf16x4 h0 = *(const bf16x4*)(h2b + (size_t)s0i * HID + q * 4);
            bf16x4 h1 = *(const bf16x4*)(h2b + (size_t)s1i * HID + q * 4);
            bf16x4 h2v = *(const bf16x4*)(h2b + (size_t)s2i * HID + q * 4);
            bf16x4 h3v = *(const bf16x4*)(h2b + (size_t)s3i * HID + q * 4);
            #pragma unroll
            for (int j = 0; j < 4; ++j)
                acc[j] += bf2f((unsigned short)h0[j]) * a0 + bf2f((unsigned short)h1[j]) * a1
                        + bf2f((unsigned short)h2v[j]) * a2 + bf2f((unsigned short)h3v[j]) * a3;
        }
    } else {
        float ss = 0.f;
        for (int i = beg + lane; i < end; i += 64) {
            int s = colsrc[i];
            ss += __expf(lrelu(es2[s] + edv));
        }
        #pragma unroll
        for (int off = 1; off < 64; off <<= 1) ss += __shfl_xor(ss, off);
        float rs = 1.f / ss;
        for (int i = beg; i < end; i += 4) {
            int idx = i + g;
            if (idx < end) {
                int s = colsrc[idx];
                float a = __expf(lrelu(es2[s] + edv)) * rs;
                bf16x4 hv = *(const bf16x4*)(h2b + (size_t)s * HID + q * 4);
                #pragma unroll
                for (int j = 0; j < 4; ++j) acc[j] += bf2f((unsigned short)hv[j]) * a;
            }
        }
    }

    #pragma unroll
    for (int j = 0; j < 4; ++j) {
        acc[j] += __shfl_xor(acc[j], 16);
        acc[j] += __shfl_xor(acc[j], 32);
    }

    // transpose: lane l takes feature l from lane l>>2
    float v0 = __shfl(acc[0], lane >> 2);
    float v1 = __shfl(acc[1], lane >> 2);
    float v2 = __shfl(acc[2], lane >> 2);
    float v3 = __shfl(acc[3], lane >> 2);
    int jj = lane & 3;
    float o = jj == 0 ? v0 : jj == 1 ? v1 : jj == 2 ? v2 : v3;
    h3[(size_t)n * HID + lane] = eluf(o + b2[lane]);
}

// ---------------- fused mean-pool + classifier ----------------
__global__ __launch_bounds__(256) void k_poolcls(const float* __restrict__ h3,
                                                 const int* __restrict__ gstart,
                                                 const float* __restrict__ Wc,
                                                 const float* __restrict__ bc,
                                                 float* __restrict__ out) {
    __shared__ float red[4][64];
    int g = blockIdx.x;
    int lane = threadIdx.x & 63, wv = threadIdx.x >> 6;
    int gs = gstart[g], ge = gstart[g + 1];
    float acc = 0.f;
    for (int r = gs + wv; r < ge; r += 4)
        acc += h3[(size_t)r * HID + lane];
    red[wv][lane] = acc;
    __syncthreads();
    if (wv == 0) {
        float p = red[0][lane] + red[1][lane] + red[2][lane] + red[3][lane];
        float c = fmaxf((float)(ge - gs), 1.f);
        p /= c;
        float s0 = p * Wc[lane * 2 + 0];
        float s1 = p * Wc[lane * 2 + 1];
        #pragma unroll
        for (int off = 1; off < 64; off <<= 1) {
            s0 += __shfl_xor(s0, off);
            s1 += __shfl_xor(s1, off);
        }
        if (lane == 0) {
            out[g * 2 + 0] = s0 + bc[0];
            out[g * 2 + 1] = s1 + bc[1];
        }
    }
}

extern "C" void kernel_launch(void* const* d_in, const int* in_sizes, int n_in,
                              void* d_out, int out_size, void* d_ws, size_t ws_size,
                              hipStream_t stream) {
    const float* x   = (const float*)d_in[0];
    const int* ei    = (const int*)d_in[1];
    const int* batch = (const int*)d_in[2];
    const float* W1  = (const float*)d_in[4];
    const float* as1 = (const float*)d_in[5];
    const float* ad1 = (const float*)d_in[6];
    const float* b1  = (const float*)d_in[7];
    const float* W2  = (const float*)d_in[8];
    const float* as2 = (const float*)d_in[9];
    const float* ad2 = (const float*)d_in[10];
    const float* b2  = (const float*)d_in[11];
    const float* Wc  = (const float*)d_in[12];
    const float* bc  = (const float*)d_in[13];
    float* out = (float*)d_out;

    char* p = (char*)d_ws;
    auto alloc = [&](size_t bytes) -> char* {
        char* r = p;
        p += (bytes + 255) & ~(size_t)255;
        return r;
    };
    int* offs    = (int*)alloc((NN + 1) * sizeof(int));
    int* cursor  = (int*)alloc(NN * sizeof(int));
    int* deg     = (int*)alloc(NN * sizeof(int));
    int* colsrc  = (int*)alloc((size_t)ETOT * sizeof(int));
    int* bsum    = (int*)alloc(64 * sizeof(int));
    int* gstart  = (int*)alloc((NG + 1) * sizeof(int));
    unsigned short* W1t = (unsigned short*)alloc((size_t)FIN * C1 * sizeof(short));
    unsigned short* W2t = (unsigned short*)alloc((size_t)C1 * HID * sizeof(short));
    unsigned short* h1b = (unsigned short*)alloc((size_t)NN * C1 * sizeof(short));
    unsigned short* h1p = (unsigned short*)alloc((size_t)NN * C1 * sizeof(short));
    unsigned short* h2b = (unsigned short*)alloc((size_t)NN * HID * sizeof(short));
    float* es1   = (float*)alloc((size_t)NN * 4 * sizeof(float));
    float* ed1   = (float*)alloc((size_t)NN * 4 * sizeof(float));
    float* es2v  = (float*)alloc((size_t)NN * sizeof(float));
    float* ed2v  = (float*)alloc((size_t)NN * sizeof(float));
    float* h3    = (float*)h1b;   // alias: h1b dead after k_agg1 (12.8 MB <= 25.6 MB)

    hipMemsetAsync(deg, 0, NN * sizeof(int), stream);

    const int* srcA = ei;       // edge_index[0]
    const int* dstA = ei + NE;  // edge_index[1]

    k_prep<<<(FIN * C1 + C1 * HID + 255) / 256, 256, 0, stream>>>(W1, W2, W1t, W2t);
    k_deg<<<(NE + 255) / 256, 256, 0, stream>>>(dstA, deg);
    k_scan_blk<<<NBLK_SCAN, 1024, 0, stream>>>(deg, offs, bsum);
    k_scan_top<<<1, 64, 0, stream>>>(bsum, NBLK_SCAN);
    k_scan_add<<<(NN + 1 + 255) / 256, 256, 0, stream>>>(offs, bsum, cursor);
    k_fill<<<(ETOT + 255) / 256, 256, 0, stream>>>(srcA, dstA, cursor, colsrc);
    k_gstart<<<1, 512, 0, stream>>>(batch, gstart);

    k_gemm1<<<(NN / 16 + 3) / 4, 256, 0, stream>>>(x, W1t, as1, ad1, h1b, es1, ed1);
    k_agg1<<<(NN + 7) / 8, 512, 0, stream>>>(offs, colsrc, h1b, es1, ed1, b1, h1p);
    k_gemm2<<<(NN / 16 + 3) / 4, 256, 0, stream>>>(h1p, W2t, as2, ad2, h2b, es2v, ed2v);
    k_agg2<<<(NN + 7) / 8, 512, 0, stream>>>(offs, colsrc, h2b, es2v, ed2v, b2, h3);
    k_poolcls<<<NG, 256, 0, stream>>>(h3, gstart, Wc, bc, out);
}

// Round 7
// 226.683 us; speedup vs baseline: 2.9256x; 1.2840x over previous
//
#include <hip/hip_runtime.h>

#define NN   50000
#define NE   1000000
#define FIN  128
#define HID  64
#define HEADS 4
#define C1   256          // HEADS*HID
#define NG   512
#define ETOT (NE + NN)    // edges + self-loops
#define BSH  10           // bucket = dst >> 10 (1024 nodes/bucket)
#define NBUK 49           // ceil(NN/1024)
#define CHUNK 8192
#define NCHUNK 123        // ceil(NE/CHUNK)

typedef __attribute__((ext_vector_type(8))) short bf16x8;
typedef __attribute__((ext_vector_type(4))) short bf16x4;
typedef __attribute__((ext_vector_type(4))) float f32x4;

__device__ __forceinline__ float lrelu(float v) { return v > 0.f ? v : 0.2f * v; }
__device__ __forceinline__ float eluf(float v)  { return v > 0.f ? v : __expf(v) - 1.f; }

__device__ __forceinline__ unsigned short f2bf(float f) {
    unsigned u = __float_as_uint(f);
    unsigned r = (u + 0x7FFFu + ((u >> 16) & 1u)) >> 16;
    return (unsigned short)r;
}
__device__ __forceinline__ float bf2f(unsigned short b) {
    return __uint_as_float(((unsigned)b) << 16);
}

// ---------------- weight prep: transpose + bf16 cast ----------------
__global__ __launch_bounds__(256) void k_prep(const float* __restrict__ W1,
                                              const float* __restrict__ W2,
                                              unsigned short* __restrict__ W1t,
                                              unsigned short* __restrict__ W2t) {
    int i = blockIdx.x * 256 + threadIdx.x;
    if (i < FIN * C1) {
        int k = i / C1, c = i % C1;
        W1t[c * FIN + k] = f2bf(W1[i]);
    } else {
        int j = i - FIN * C1;
        if (j < C1 * HID) {
            int k = j / HID, c = j % HID;
            W2t[c * C1 + k] = f2bf(W2[j]);
        }
    }
}

// ---------------- CSR build via bucket counting-sort ----------------
__global__ __launch_bounds__(256) void k_hist(const int* __restrict__ dst,
                                              int* __restrict__ bhist) {
    __shared__ int lh[NBUK];
    int tid = threadIdx.x;
    if (tid < NBUK) lh[tid] = 0;
    __syncthreads();
    for (int e = blockIdx.x * 256 + tid; e < NE; e += gridDim.x * 256)
        atomicAdd(&lh[dst[e] >> BSH], 1);
    __syncthreads();
    if (tid < NBUK) atomicAdd(&bhist[tid], lh[tid]);
}

__global__ void k_bscan(const int* __restrict__ bhist,
                        int* __restrict__ bbase,
                        int* __restrict__ bcur,
                        int* __restrict__ offs) {
    int tid = threadIdx.x;   // 1 block, 64 threads
    int v = (tid < NBUK) ? bhist[tid] : 0;
    int x = v;
    #pragma unroll
    for (int off = 1; off < 64; off <<= 1) {
        int t = __shfl_up(x, off);
        if (tid >= off) x += t;
    }
    if (tid < NBUK) {
        int excl = x - v;
        bbase[tid] = excl;
        bcur[tid] = excl;
    }
    if (tid == NBUK - 1) bbase[NBUK] = x;   // = NE
    if (tid == 0) offs[NN] = ETOT;
}

// chunk-wise partition: edges -> bucket-contiguous ebuf (src,dst)
__global__ __launch_bounds__(256) void k_part(const int* __restrict__ src,
                                              const int* __restrict__ dst,
                                              int* __restrict__ bcur,
                                              int2* __restrict__ ebuf) {
    __shared__ int lcnt[NBUK];
    __shared__ int gbase[NBUK];
    __shared__ int lrank[NBUK];
    int tid = threadIdx.x;
    int e0 = blockIdx.x * CHUNK;
    int e1 = min(e0 + CHUNK, NE);
    if (tid < NBUK) { lcnt[tid] = 0; lrank[tid] = 0; }
    __syncthreads();
    for (int e = e0 + tid; e < e1; e += 256)
        atomicAdd(&lcnt[dst[e] >> BSH], 1);
    __syncthreads();
    if (tid < NBUK) gbase[tid] = atomicAdd(&bcur[tid], lcnt[tid]);
    __syncthreads();
    for (int e = e0 + tid; e < e1; e += 256) {
        int d = dst[e];
        int b = d >> BSH;
        int r = atomicAdd(&lrank[b], 1);
        ebuf[gbase[b] + r] = make_int2(src[e], d);
    }
}

// per-bucket: local degrees -> scan -> offs + colsrc fill (all XCD-local)
__global__ __launch_bounds__(1024) void k_bfill(const int2* __restrict__ ebuf,
                                                const int* __restrict__ bbase,
                                                int* __restrict__ offs,
                                                int* __restrict__ colsrc) {
    __shared__ int ldeg[1024];
    __shared__ int lcur[1024];
    __shared__ int ws[16];
    int b = blockIdx.x;
    int tid = threadIdx.x;
    int nbase = b << BSH;
    int ncnt = min(1024, NN - nbase);
    int ebeg = bbase[b], eend = bbase[b + 1];
    ldeg[tid] = 0;
    __syncthreads();
    for (int i = ebeg + tid; i < eend; i += 1024)
        atomicAdd(&ldeg[ebuf[i].y - nbase], 1);
    __syncthreads();
    // exclusive scan of (ldeg[i]+1) over ncnt entries
    int v = (tid < ncnt) ? ldeg[tid] + 1 : 0;
    int lane = tid & 63, wv = tid >> 6;
    int x = v;
    #pragma unroll
    for (int off = 1; off < 64; off <<= 1) {
        int t = __shfl_up(x, off);
        if (lane >= off) x += t;
    }
    if (lane == 63) ws[wv] = x;
    __syncthreads();
    if (tid < 16) {
        int y = ws[tid];
        #pragma unroll
        for (int off = 1; off < 16; off <<= 1) {
            int t = __shfl_up(y, off);
            if (tid >= off) y += t;
        }
        ws[tid] = y;
    }
    __syncthreads();
    int base = wv ? ws[wv - 1] : 0;
    int excl = base + x - v;
    int gofs = ebeg + nbase + excl;   // global position: prior edges + prior self-loops + local
    if (tid < ncnt) {
        offs[nbase + tid] = gofs;
        lcur[tid] = gofs;
    }
    __syncthreads();
    for (int i = ebeg + tid; i < eend; i += 1024) {
        int2 ed = ebuf[i];
        int p = atomicAdd(&lcur[ed.y - nbase], 1);
        colsrc[p] = ed.x;
    }
    __syncthreads();
    if (tid < ncnt) colsrc[lcur[tid]] = nbase + tid;   // self-loop at segment end
}

// ---------------- graph boundaries ----------------
__global__ __launch_bounds__(512) void k_gstart(const int* __restrict__ batch,
                                                int* __restrict__ gstart) {
    for (int g = threadIdx.x; g <= NG; g += 512) {
        int lo = 0, hi = NN;
        while (lo < hi) {
            int mid = (lo + hi) >> 1;
            if (batch[mid] < g) lo = mid + 1; else hi = mid;
        }
        gstart[g] = lo;
    }
}

// ---------------- Layer 1 GEMM (MFMA bf16, LDS-staged W) ----------------
__global__ __launch_bounds__(256) void k_gemm1(const float* __restrict__ x,
                                               const unsigned short* __restrict__ W1t,
                                               const float* __restrict__ asrc,
                                               const float* __restrict__ adst,
                                               unsigned short* __restrict__ h1b,
                                               float* __restrict__ es1,
                                               float* __restrict__ ed1) {
    __shared__ unsigned short Wl[128 * FIN];   // 32 KB
    int tid = threadIdx.x;
    int lane = tid & 63, wv = tid >> 6;
    int r0 = (blockIdx.x * 4 + wv) * 16;
    int g = lane >> 4, q = lane & 15;

    int ar = min(r0 + q, NN - 1);
    const float* xr = x + (size_t)ar * FIN;
    bf16x8 afr[4];
    #pragma unroll
    for (int kt = 0; kt < 4; ++kt) {
        float4 u0 = *(const float4*)(xr + kt * 32 + g * 8);
        float4 u1 = *(const float4*)(xr + kt * 32 + g * 8 + 4);
        bf16x8 a;
        a[0] = (short)f2bf(u0.x); a[1] = (short)f2bf(u0.y);
        a[2] = (short)f2bf(u0.z); a[3] = (short)f2bf(u0.w);
        a[4] = (short)f2bf(u1.x); a[5] = (short)f2bf(u1.y);
        a[6] = (short)f2bf(u1.z); a[7] = (short)f2bf(u1.w);
        afr[kt] = a;
    }

    for (int ch = 0; ch < 2; ++ch) {
        if (ch) __syncthreads();
        const uint4* src = (const uint4*)(W1t + (size_t)ch * 128 * FIN);
        #pragma unroll
        for (int i = 0; i < 8; ++i) {
            int idx = tid + i * 256;
            uint4 v = src[idx];
            unsigned byte = (unsigned)idx << 4;
            unsigned dst = byte ^ (((byte >> 8) & 7) << 4);
            *(uint4*)((char*)Wl + dst) = v;
        }
        __syncthreads();

        #pragma unroll
        for (int hh = 0; hh < 2; ++hh) {
            int h = ch * 2 + hh;
            float ps[4] = {0.f, 0.f, 0.f, 0.f};
            float pd[4] = {0.f, 0.f, 0.f, 0.f};
            #pragma unroll
            for (int tl = 0; tl < 4; ++tl) {
                int col = (h * 4 + tl) * 16 + q;
                int cl = col - ch * 128;
                f32x4 acc = {0.f, 0.f, 0.f, 0.f};
                #pragma unroll
                for (int kt = 0; kt < 4; ++kt) {
                    unsigned bb = (unsigned)cl * 256 + kt * 64 + g * 16;
                    bf16x8 b = *(const bf16x8*)((const char*)Wl + (bb ^ (((unsigned)cl & 7) << 4)));
                    acc = __builtin_amdgcn_mfma_f32_16x16x32_bf16(afr[kt], b, acc, 0, 0, 0);
                }
                float av = asrc[col], bv = adst[col];
                #pragma unroll
                for (int j = 0; j < 4; ++j) {
                    int rr = min(r0 + g * 4 + j, NN - 1);
                    h1b[(size_t)rr * C1 + col] = f2bf(acc[j]);
                    ps[j] += acc[j] * av;
                    pd[j] += acc[j] * bv;
                }
            }
            #pragma unroll
            for (int j = 0; j < 4; ++j) {
                #pragma unroll
                for (int off = 1; off < 16; off <<= 1) {
                    ps[j] += __shfl_xor(ps[j], off);
                    pd[j] += __shfl_xor(pd[j], off);
                }
                if (q == 0) {
                    int rr = min(r0 + g * 4 + j, NN - 1);
                    es1[rr * 4 + h] = ps[j];
                    ed1[rr * 4 + h] = pd[j];
                }
            }
        }
    }
}

// ---------------- Layer 1 aggregation ----------------
__global__ __launch_bounds__(512) void k_agg1(const int* __restrict__ offs,
                                              const int* __restrict__ colsrc,
                                              const unsigned short* __restrict__ h1b,
                                              const float* __restrict__ es1,
                                              const float* __restrict__ ed1,
                                              const float* __restrict__ b1,
                                              unsigned short* __restrict__ h1p) {
    __shared__ int   sls[8][64];
    __shared__ float sla[8][64][4];
    int lane = threadIdx.x & 63, wv = threadIdx.x >> 6;
    int n = blockIdx.x * 8 + wv;
    if (n >= NN) return;
    int beg = offs[n], end = offs[n + 1], deg = end - beg;
    float4 edv = *(const float4*)(ed1 + n * 4);
    int half = lane >> 5, q5 = lane & 31;
    int hd = q5 >> 3;
    float acc[8];
    #pragma unroll
    for (int j = 0; j < 8; ++j) acc[j] = 0.f;

    if (deg <= 64) {
        int msrc = 0;
        float m0 = 0.f, m1 = 0.f, m2 = 0.f, m3 = 0.f;
        if (lane < deg) {
            msrc = colsrc[beg + lane];
            float4 ev = *(const float4*)(es1 + msrc * 4);
            m0 = __expf(lrelu(ev.x + edv.x));
            m1 = __expf(lrelu(ev.y + edv.y));
            m2 = __expf(lrelu(ev.z + edv.z));
            m3 = __expf(lrelu(ev.w + edv.w));
        }
        float s0 = m0, s1 = m1, s2 = m2, s3 = m3;
        #pragma unroll
        for (int off = 1; off < 64; off <<= 1) {
            s0 += __shfl_xor(s0, off);
            s1 += __shfl_xor(s1, off);
            s2 += __shfl_xor(s2, off);
            s3 += __shfl_xor(s3, off);
        }
        sls[wv][lane] = msrc;
        sla[wv][lane][0] = m0 * (1.f / s0);
        sla[wv][lane][1] = m1 * (1.f / s1);
        sla[wv][lane][2] = m2 * (1.f / s2);
        sla[wv][lane][3] = m3 * (1.f / s3);

        for (int i = 0; i < deg; i += 8) {
            int e0 = (i + half) & 63, e1 = (i + 2 + half) & 63, e2 = (i + 4 + half) & 63, e3 = (i + 6 + half) & 63;
            int   s0i = sls[wv][e0], s1i = sls[wv][e1], s2i = sls[wv][e2], s3i = sls[wv][e3];
            float a0 = sla[wv][e0][hd], a1 = sla[wv][e1][hd], a2 = sla[wv][e2][hd], a3 = sla[wv][e3][hd];
            bf16x8 h0 = *(const bf16x8*)(h1b + (size_t)s0i * C1 + q5 * 8);
            bf16x8 h1 = *(const bf16x8*)(h1b + (size_t)s1i * C1 + q5 * 8);
            bf16x8 h2 = *(const bf16x8*)(h1b + (size_t)s2i * C1 + q5 * 8);
            bf16x8 h3 = *(const bf16x8*)(h1b + (size_t)s3i * C1 + q5 * 8);
            #pragma unroll
            for (int j = 0; j < 8; ++j)
                acc[j] += bf2f((unsigned short)h0[j]) * a0 + bf2f((unsigned short)h1[j]) * a1
                        + bf2f((unsigned short)h2[j]) * a2 + bf2f((unsigned short)h3[j]) * a3;
        }
    } else {
        float s0 = 0.f, s1 = 0.f, s2 = 0.f, s3 = 0.f;
        for (int i = beg + lane; i < end; i += 64) {
            int s = colsrc[i];
            float4 ev = *(const float4*)(es1 + s * 4);
            s0 += __expf(lrelu(ev.x + edv.x));
            s1 += __expf(lrelu(ev.y + edv.y));
            s2 += __expf(lrelu(ev.z + edv.z));
            s3 += __expf(lrelu(ev.w + edv.w));
        }
        #pragma unroll
        for (int off = 1; off < 64; off <<= 1) {
            s0 += __shfl_xor(s0, off);
            s1 += __shfl_xor(s1, off);
            s2 += __shfl_xor(s2, off);
            s3 += __shfl_xor(s3, off);
        }
        float rr = hd == 0 ? 1.f / s0 : hd == 1 ? 1.f / s1 : hd == 2 ? 1.f / s2 : 1.f / s3;
        float ed_h = hd == 0 ? edv.x : hd == 1 ? edv.y : hd == 2 ? edv.z : edv.w;
        for (int i = beg; i < end; i += 2) {
            int idx = i + half;
            if (idx < end) {
                int s = colsrc[idx];
                float eh = es1[s * 4 + hd] + ed_h;
                float a = __expf(lrelu(eh)) * rr;
                bf16x8 hv = *(const bf16x8*)(h1b + (size_t)s * C1 + q5 * 8);
                #pragma unroll
                for (int j = 0; j < 8; ++j) acc[j] += bf2f((unsigned short)hv[j]) * a;
            }
        }
    }

    #pragma unroll
    for (int j = 0; j < 8; ++j) acc[j] += __shfl_xor(acc[j], 32);

    if (half == 0) {
        float4 bv0 = *(const float4*)(b1 + q5 * 8);
        float4 bv1 = *(const float4*)(b1 + q5 * 8 + 4);
        bf16x8 o;
        o[0] = (short)f2bf(eluf(acc[0] + bv0.x));
        o[1] = (short)f2bf(eluf(acc[1] + bv0.y));
        o[2] = (short)f2bf(eluf(acc[2] + bv0.z));
        o[3] = (short)f2bf(eluf(acc[3] + bv0.w));
        o[4] = (short)f2bf(eluf(acc[4] + bv1.x));
        o[5] = (short)f2bf(eluf(acc[5] + bv1.y));
        o[6] = (short)f2bf(eluf(acc[6] + bv1.z));
        o[7] = (short)f2bf(eluf(acc[7] + bv1.w));
        *(bf16x8*)(h1p + (size_t)n * C1 + q5 * 8) = o;
    }
}

// ---------------- Layer 2 GEMM (MFMA bf16, LDS-staged W) ----------------
__global__ __launch_bounds__(256) void k_gemm2(const unsigned short* __restrict__ h1p,
                                               const unsigned short* __restrict__ W2t,
                                               const float* __restrict__ as2,
                                               const float* __restrict__ ad2,
                                               unsigned short* __restrict__ h2b,
                                               float* __restrict__ es2,
                                               float* __restrict__ ed2) {
    __shared__ unsigned short Wl[HID * C1];   // 32 KB
    int tid = threadIdx.x;
    int lane = tid & 63, wv = tid >> 6;
    int r0 = (blockIdx.x * 4 + wv) * 16;
    int g = lane >> 4, q = lane & 15;

    const uint4* src = (const uint4*)W2t;
    #pragma unroll
    for (int i = 0; i < 8; ++i) {
        int idx = tid + i * 256;
        uint4 v = src[idx];
        unsigned byte = (unsigned)idx << 4;
        unsigned dst = byte ^ (((byte >> 9) & 7) << 4);
        *(uint4*)((char*)Wl + dst) = v;
    }

    int ar = min(r0 + q, NN - 1);
    const unsigned short* arp = h1p + (size_t)ar * C1;
    bf16x8 afr[8];
    #pragma unroll
    for (int kt = 0; kt < 8; ++kt)
        afr[kt] = *(const bf16x8*)(arp + kt * 32 + g * 8);

    __syncthreads();

    float ps[4] = {0.f, 0.f, 0.f, 0.f};
    float pd[4] = {0.f, 0.f, 0.f, 0.f};
    #pragma unroll
    for (int t = 0; t < 4; ++t) {
        int col = t * 16 + q;
        f32x4 acc = {0.f, 0.f, 0.f, 0.f};
        #pragma unroll
        for (int kt = 0; kt < 8; ++kt) {
            unsigned bb = (unsigned)col * 512 + kt * 64 + g * 16;
            bf16x8 b = *(const bf16x8*)((const char*)Wl + (bb ^ (((unsigned)col & 7) << 4)));
            acc = __builtin_amdgcn_mfma_f32_16x16x32_bf16(afr[kt], b, acc, 0, 0, 0);
        }
        float av = as2[col], bv = ad2[col];
        #pragma unroll
        for (int j = 0; j < 4; ++j) {
            int rr = min(r0 + g * 4 + j, NN - 1);
            h2b[(size_t)rr * HID + col] = f2bf(acc[j]);
            ps[j] += acc[j] * av;
            pd[j] += acc[j] * bv;
        }
    }
    #pragma unroll
    for (int j = 0; j < 4; ++j) {
        #pragma unroll
        for (int off = 1; off < 16; off <<= 1) {
            ps[j] += __shfl_xor(ps[j], off);
            pd[j] += __shfl_xor(pd[j], off);
        }
        if (q == 0) {
            int rr = min(r0 + g * 4 + j, NN - 1);
            es2[rr] = ps[j];
            ed2[rr] = pd[j];
        }
    }
}

// ---------------- Layer 2 aggregation: dense h3 output ----------------
__global__ __launch_bounds__(512) void k_agg2(const int* __restrict__ offs,
                                              const int* __restrict__ colsrc,
                                              const unsigned short* __restrict__ h2b,
                                              const float* __restrict__ es2,
                                              const float* __restrict__ ed2,
                                              const float* __restrict__ b2,
                                              float* __restrict__ h3) {
    __shared__ int   sls[8][64];
    __shared__ float sla[8][64];
    int lane = threadIdx.x & 63, wv = threadIdx.x >> 6;
    int n = blockIdx.x * 8 + wv;
    if (n >= NN) return;
    int beg = offs[n], end = offs[n + 1], deg = end - beg;
    float edv = ed2[n];
    int g = lane >> 4, q = lane & 15;
    float acc[4] = {0.f, 0.f, 0.f, 0.f};

    if (deg <= 64) {
        int msrc = 0;
        float mex = 0.f;
        if (lane < deg) {
            msrc = colsrc[beg + lane];
            mex = __expf(lrelu(es2[msrc] + edv));
        }
        float ss = mex;
        #pragma unroll
        for (int off = 1; off < 64; off <<= 1) ss += __shfl_xor(ss, off);
        sls[wv][lane] = msrc;
        sla[wv][lane] = mex * (1.f / ss);

        for (int i = 0; i < deg; i += 16) {
            int e0 = (i + g) & 63, e1 = (i + 4 + g) & 63, e2 = (i + 8 + g) & 63, e3 = (i + 12 + g) & 63;
            int   s0i = sls[wv][e0], s1i = sls[wv][e1], s2i = sls[wv][e2], s3i = sls[wv][e3];
            float a0 = sla[wv][e0], a1 = sla[wv][e1], a2 = sla[wv][e2], a3 = sla[wv][e3];
            bf16x4 h0 = *(const bf16x4*)(h2b + (size_t)s0i * HID + q * 4);
            bf16x4 h1 = *(const bf16x4*)(h2b + (size_t)s1i * HID + q * 4);
            bf16x4 h2v = *(const bf16x4*)(h2b + (size_t)s2i * HID + q * 4);
            bf16x4 h3v = *(const bf16x4*)(h2b + (size_t)s3i * HID + q * 4);
            #pragma unroll
            for (int j = 0; j < 4; ++j)
                acc[j] += bf2f((unsigned short)h0[j]) * a0 + bf2f((unsigned short)h1[j]) * a1
                        + bf2f((unsigned short)h2v[j]) * a2 + bf2f((unsigned short)h3v[j]) * a3;
        }
    } else {
        float ss = 0.f;
        for (int i = beg + lane; i < end; i += 64) {
            int s = colsrc[i];
            ss += __expf(lrelu(es2[s] + edv));
        }
        #pragma unroll
        for (int off = 1; off < 64; off <<= 1) ss += __shfl_xor(ss, off);
        float rs = 1.f / ss;
        for (int i = beg; i < end; i += 4) {
            int idx = i + g;
            if (idx < end) {
                int s = colsrc[idx];
                float a = __expf(lrelu(es2[s] + edv)) * rs;
                bf16x4 hv = *(const bf16x4*)(h2b + (size_t)s * HID + q * 4);
                #pragma unroll
                for (int j = 0; j < 4; ++j) acc[j] += bf2f((unsigned short)hv[j]) * a;
            }
        }
    }

    #pragma unroll
    for (int j = 0; j < 4; ++j) {
        acc[j] += __shfl_xor(acc[j], 16);
        acc[j] += __shfl_xor(acc[j], 32);
    }

    float v0 = __shfl(acc[0], lane >> 2);
    float v1 = __shfl(acc[1], lane >> 2);
    float v2 = __shfl(acc[2], lane >> 2);
    float v3 = __shfl(acc[3], lane >> 2);
    int jj = lane & 3;
    float o = jj == 0 ? v0 : jj == 1 ? v1 : jj == 2 ? v2 : v3;
    h3[(size_t)n * HID + lane] = eluf(o + b2[lane]);
}

// ---------------- fused mean-pool + classifier ----------------
__global__ __launch_bounds__(256) void k_poolcls(const float* __restrict__ h3,
                                                 const int* __restrict__ gstart,
                                                 const float* __restrict__ Wc,
                                                 const float* __restrict__ bc,
                                                 float* __restrict__ out) {
    __shared__ float red[4][64];
    int g = blockIdx.x;
    int lane = threadIdx.x & 63, wv = threadIdx.x >> 6;
    int gs = gstart[g], ge = gstart[g + 1];
    float acc = 0.f;
    for (int r = gs + wv; r < ge; r += 4)
        acc += h3[(size_t)r * HID + lane];
    red[wv][lane] = acc;
    __syncthreads();
    if (wv == 0) {
        float p = red[0][lane] + red[1][lane] + red[2][lane] + red[3][lane];
        float c = fmaxf((float)(ge - gs), 1.f);
        p /= c;
        float s0 = p * Wc[lane * 2 + 0];
        float s1 = p * Wc[lane * 2 + 1];
        #pragma unroll
        for (int off = 1; off < 64; off <<= 1) {
            s0 += __shfl_xor(s0, off);
            s1 += __shfl_xor(s1, off);
        }
        if (lane == 0) {
            out[g * 2 + 0] = s0 + bc[0];
            out[g * 2 + 1] = s1 + bc[1];
        }
    }
}

extern "C" void kernel_launch(void* const* d_in, const int* in_sizes, int n_in,
                              void* d_out, int out_size, void* d_ws, size_t ws_size,
                              hipStream_t stream) {
    const float* x   = (const float*)d_in[0];
    const int* ei    = (const int*)d_in[1];
    const int* batch = (const int*)d_in[2];
    const float* W1  = (const float*)d_in[4];
    const float* as1 = (const float*)d_in[5];
    const float* ad1 = (const float*)d_in[6];
    const float* b1  = (const float*)d_in[7];
    const float* W2  = (const float*)d_in[8];
    const float* as2 = (const float*)d_in[9];
    const float* ad2 = (const float*)d_in[10];
    const float* b2  = (const float*)d_in[11];
    const float* Wc  = (const float*)d_in[12];
    const float* bc  = (const float*)d_in[13];
    float* out = (float*)d_out;

    char* p = (char*)d_ws;
    auto alloc = [&](size_t bytes) -> char* {
        char* r = p;
        p += (bytes + 255) & ~(size_t)255;
        return r;
    };
    int* offs    = (int*)alloc((NN + 1) * sizeof(int));
    int* colsrc  = (int*)alloc((size_t)ETOT * sizeof(int));
    int2* ebuf   = (int2*)alloc((size_t)NE * sizeof(int2));
    int* bhist   = (int*)alloc(NBUK * sizeof(int));
    int* bbase   = (int*)alloc((NBUK + 1) * sizeof(int));
    int* bcur    = (int*)alloc(NBUK * sizeof(int));
    int* gstart  = (int*)alloc((NG + 1) * sizeof(int));
    unsigned short* W1t = (unsigned short*)alloc((size_t)FIN * C1 * sizeof(short));
    unsigned short* W2t = (unsigned short*)alloc((size_t)C1 * HID * sizeof(short));
    unsigned short* h1b = (unsigned short*)alloc((size_t)NN * C1 * sizeof(short));
    unsigned short* h1p = (unsigned short*)alloc((size_t)NN * C1 * sizeof(short));
    unsigned short* h2b = (unsigned short*)alloc((size_t)NN * HID * sizeof(short));
    float* es1   = (float*)alloc((size_t)NN * 4 * sizeof(float));
    float* ed1   = (float*)alloc((size_t)NN * 4 * sizeof(float));
    float* es2v  = (float*)alloc((size_t)NN * sizeof(float));
    float* ed2v  = (float*)alloc((size_t)NN * sizeof(float));
    float* h3    = (float*)h1b;   // alias: h1b dead after k_agg1

    hipMemsetAsync(bhist, 0, NBUK * sizeof(int), stream);

    const int* srcA = ei;       // edge_index[0]
    const int* dstA = ei + NE;  // edge_index[1]

    k_prep<<<(FIN * C1 + C1 * HID + 255) / 256, 256, 0, stream>>>(W1, W2, W1t, W2t);
    k_hist<<<256, 256, 0, stream>>>(dstA, bhist);
    k_bscan<<<1, 64, 0, stream>>>(bhist, bbase, bcur, offs);
    k_part<<<NCHUNK, 256, 0, stream>>>(srcA, dstA, bcur, ebuf);
    k_bfill<<<NBUK, 1024, 0, stream>>>(ebuf, bbase, offs, colsrc);
    k_gstart<<<1, 512, 0, stream>>>(batch, gstart);

    k_gemm1<<<(NN / 16 + 3) / 4, 256, 0, stream>>>(x, W1t, as1, ad1, h1b, es1, ed1);
    k_agg1<<<(NN + 7) / 8, 512, 0, stream>>>(offs, colsrc, h1b, es1, ed1, b1, h1p);
    k_gemm2<<<(NN / 16 + 3) / 4, 256, 0, stream>>>(h1p, W2t, as2, ad2, h2b, es2v, ed2v);
    k_agg2<<<(NN + 7) / 8, 512, 0, stream>>>(offs, colsrc, h2b, es2v, ed2v, b2, h3);
    k_poolcls<<<NG, 256, 0, stream>>>(h3, gstart, Wc, bc, out);
}

// Round 8
// 195.010 us; speedup vs baseline: 3.4008x; 1.1624x over previous
//
#include <hip/hip_runtime.h>

#define NN   50000
#define NE   1000000
#define FIN  128
#define HID  64
#define HEADS 4
#define C1   256          // HEADS*HID
#define NG   512
#define ETOT (NE + NN)    // edges + self-loops
#define BSH  10           // bucket = dst >> 10 (1024 nodes/bucket)
#define NBUK 49           // ceil(NN/1024)
#define CHUNK 8192
#define NCHUNK 123        // ceil(NE/CHUNK)

typedef __attribute__((ext_vector_type(8))) short bf16x8;
typedef __attribute__((ext_vector_type(4))) short bf16x4;
typedef __attribute__((ext_vector_type(4))) float f32x4;
typedef __attribute__((ext_vector_type(2))) float f32x2;

__device__ __forceinline__ float lrelu(float v) { return v > 0.f ? v : 0.2f * v; }
__device__ __forceinline__ float eluf(float v)  { return v > 0.f ? v : __expf(v) - 1.f; }

__device__ __forceinline__ unsigned short f2bf(float f) {
    unsigned u = __float_as_uint(f);
    unsigned r = (u + 0x7FFFu + ((u >> 16) & 1u)) >> 16;
    return (unsigned short)r;
}
__device__ __forceinline__ float bf2f(unsigned short b) {
    return __uint_as_float(((unsigned)b) << 16);
}
__device__ __forceinline__ unsigned char f2fp8(float f) {
    int w = __builtin_amdgcn_cvt_pk_fp8_f32(f, f, 0, false);
    return (unsigned char)(w & 0xFF);
}

// ---------------- weight prep: transpose + bf16 cast ----------------
__global__ __launch_bounds__(256) void k_prep(const float* __restrict__ W1,
                                              const float* __restrict__ W2,
                                              unsigned short* __restrict__ W1t,
                                              unsigned short* __restrict__ W2t) {
    int i = blockIdx.x * 256 + threadIdx.x;
    if (i < FIN * C1) {
        int k = i / C1, c = i % C1;
        W1t[c * FIN + k] = f2bf(W1[i]);
    } else {
        int j = i - FIN * C1;
        if (j < C1 * HID) {
            int k = j / HID, c = j % HID;
            W2t[c * C1 + k] = f2bf(W2[j]);
        }
    }
}

// ---------------- CSR build via bucket counting-sort ----------------
__global__ __launch_bounds__(256) void k_hist(const int* __restrict__ dst,
                                              int* __restrict__ bhist) {
    __shared__ int lh[NBUK];
    int tid = threadIdx.x;
    if (tid < NBUK) lh[tid] = 0;
    __syncthreads();
    for (int e = blockIdx.x * 256 + tid; e < NE; e += gridDim.x * 256)
        atomicAdd(&lh[dst[e] >> BSH], 1);
    __syncthreads();
    if (tid < NBUK) atomicAdd(&bhist[tid], lh[tid]);
}

__global__ void k_bscan(const int* __restrict__ bhist,
                        int* __restrict__ bbase,
                        int* __restrict__ bcur,
                        int* __restrict__ offs) {
    int tid = threadIdx.x;   // 1 block, 64 threads
    int v = (tid < NBUK) ? bhist[tid] : 0;
    int x = v;
    #pragma unroll
    for (int off = 1; off < 64; off <<= 1) {
        int t = __shfl_up(x, off);
        if (tid >= off) x += t;
    }
    if (tid < NBUK) {
        int excl = x - v;
        bbase[tid] = excl;
        bcur[tid] = excl;
    }
    if (tid == NBUK - 1) bbase[NBUK] = x;   // = NE
    if (tid == 0) offs[NN] = ETOT;
}

// chunk-wise partition: edges -> bucket-contiguous ebuf (src,dst)
__global__ __launch_bounds__(256) void k_part(const int* __restrict__ src,
                                              const int* __restrict__ dst,
                                              int* __restrict__ bcur,
                                              int2* __restrict__ ebuf) {
    __shared__ int lcnt[NBUK];
    __shared__ int gbase[NBUK];
    __shared__ int lrank[NBUK];
    int tid = threadIdx.x;
    int e0 = blockIdx.x * CHUNK;
    int e1 = min(e0 + CHUNK, NE);
    if (tid < NBUK) { lcnt[tid] = 0; lrank[tid] = 0; }
    __syncthreads();
    for (int e = e0 + tid; e < e1; e += 256)
        atomicAdd(&lcnt[dst[e] >> BSH], 1);
    __syncthreads();
    if (tid < NBUK) gbase[tid] = atomicAdd(&bcur[tid], lcnt[tid]);
    __syncthreads();
    for (int e = e0 + tid; e < e1; e += 256) {
        int d = dst[e];
        int b = d >> BSH;
        int r = atomicAdd(&lrank[b], 1);
        ebuf[gbase[b] + r] = make_int2(src[e], d);
    }
}

// per-bucket: local degrees -> scan -> offs + colsrc fill (all XCD-local)
__global__ __launch_bounds__(1024) void k_bfill(const int2* __restrict__ ebuf,
                                                const int* __restrict__ bbase,
                                                int* __restrict__ offs,
                                                int* __restrict__ colsrc) {
    __shared__ int ldeg[1024];
    __shared__ int lcur[1024];
    __shared__ int ws[16];
    int b = blockIdx.x;
    int tid = threadIdx.x;
    int nbase = b << BSH;
    int ncnt = min(1024, NN - nbase);
    int ebeg = bbase[b], eend = bbase[b + 1];
    ldeg[tid] = 0;
    __syncthreads();
    for (int i = ebeg + tid; i < eend; i += 1024)
        atomicAdd(&ldeg[ebuf[i].y - nbase], 1);
    __syncthreads();
    int v = (tid < ncnt) ? ldeg[tid] + 1 : 0;
    int lane = tid & 63, wv = tid >> 6;
    int x = v;
    #pragma unroll
    for (int off = 1; off < 64; off <<= 1) {
        int t = __shfl_up(x, off);
        if (lane >= off) x += t;
    }
    if (lane == 63) ws[wv] = x;
    __syncthreads();
    if (tid < 16) {
        int y = ws[tid];
        #pragma unroll
        for (int off = 1; off < 16; off <<= 1) {
            int t = __shfl_up(y, off);
            if (tid >= off) y += t;
        }
        ws[tid] = y;
    }
    __syncthreads();
    int base = wv ? ws[wv - 1] : 0;
    int excl = base + x - v;
    int gofs = ebeg + nbase + excl;
    if (tid < ncnt) {
        offs[nbase + tid] = gofs;
        lcur[tid] = gofs;
    }
    __syncthreads();
    for (int i = ebeg + tid; i < eend; i += 1024) {
        int2 ed = ebuf[i];
        int p = atomicAdd(&lcur[ed.y - nbase], 1);
        colsrc[p] = ed.x;
    }
    __syncthreads();
    if (tid < ncnt) colsrc[lcur[tid]] = nbase + tid;   // self-loop at segment end
}

// ---------------- graph boundaries ----------------
__global__ __launch_bounds__(512) void k_gstart(const int* __restrict__ batch,
                                                int* __restrict__ gstart) {
    for (int g = threadIdx.x; g <= NG; g += 512) {
        int lo = 0, hi = NN;
        while (lo < hi) {
            int mid = (lo + hi) >> 1;
            if (batch[mid] < g) lo = mid + 1; else hi = mid;
        }
        gstart[g] = lo;
    }
}

// ---------------- Layer 1 GEMM (MFMA bf16, LDS-staged W, fp8 h1 output) ----------------
__global__ __launch_bounds__(256) void k_gemm1(const float* __restrict__ x,
                                               const unsigned short* __restrict__ W1t,
                                               const float* __restrict__ asrc,
                                               const float* __restrict__ adst,
                                               unsigned char* __restrict__ h1f,
                                               float* __restrict__ es1,
                                               float* __restrict__ ed1) {
    __shared__ unsigned short Wl[128 * FIN];   // 32 KB
    int tid = threadIdx.x;
    int lane = tid & 63, wv = tid >> 6;
    int r0 = (blockIdx.x * 4 + wv) * 16;
    int g = lane >> 4, q = lane & 15;

    int ar = min(r0 + q, NN - 1);
    const float* xr = x + (size_t)ar * FIN;
    bf16x8 afr[4];
    #pragma unroll
    for (int kt = 0; kt < 4; ++kt) {
        float4 u0 = *(const float4*)(xr + kt * 32 + g * 8);
        float4 u1 = *(const float4*)(xr + kt * 32 + g * 8 + 4);
        bf16x8 a;
        a[0] = (short)f2bf(u0.x); a[1] = (short)f2bf(u0.y);
        a[2] = (short)f2bf(u0.z); a[3] = (short)f2bf(u0.w);
        a[4] = (short)f2bf(u1.x); a[5] = (short)f2bf(u1.y);
        a[6] = (short)f2bf(u1.z); a[7] = (short)f2bf(u1.w);
        afr[kt] = a;
    }

    for (int ch = 0; ch < 2; ++ch) {
        if (ch) __syncthreads();
        const uint4* src = (const uint4*)(W1t + (size_t)ch * 128 * FIN);
        #pragma unroll
        for (int i = 0; i < 8; ++i) {
            int idx = tid + i * 256;
            uint4 v = src[idx];
            unsigned byte = (unsigned)idx << 4;
            unsigned dst = byte ^ (((byte >> 8) & 7) << 4);
            *(uint4*)((char*)Wl + dst) = v;
        }
        __syncthreads();

        #pragma unroll
        for (int hh = 0; hh < 2; ++hh) {
            int h = ch * 2 + hh;
            float ps[4] = {0.f, 0.f, 0.f, 0.f};
            float pd[4] = {0.f, 0.f, 0.f, 0.f};
            #pragma unroll
            for (int tl = 0; tl < 4; ++tl) {
                int col = (h * 4 + tl) * 16 + q;
                int cl = col - ch * 128;
                f32x4 acc = {0.f, 0.f, 0.f, 0.f};
                #pragma unroll
                for (int kt = 0; kt < 4; ++kt) {
                    unsigned bb = (unsigned)cl * 256 + kt * 64 + g * 16;
                    bf16x8 b = *(const bf16x8*)((const char*)Wl + (bb ^ (((unsigned)cl & 7) << 4)));
                    acc = __builtin_amdgcn_mfma_f32_16x16x32_bf16(afr[kt], b, acc, 0, 0, 0);
                }
                float av = asrc[col], bv = adst[col];
                #pragma unroll
                for (int j = 0; j < 4; ++j) {
                    int rr = min(r0 + g * 4 + j, NN - 1);
                    h1f[(size_t)rr * C1 + col] = f2fp8(acc[j]);
                    ps[j] += acc[j] * av;
                    pd[j] += acc[j] * bv;
                }
            }
            #pragma unroll
            for (int j = 0; j < 4; ++j) {
                #pragma unroll
                for (int off = 1; off < 16; off <<= 1) {
                    ps[j] += __shfl_xor(ps[j], off);
                    pd[j] += __shfl_xor(pd[j], off);
                }
                if (q == 0) {
                    int rr = min(r0 + g * 4 + j, NN - 1);
                    es1[rr * 4 + h] = ps[j];
                    ed1[rr * 4 + h] = pd[j];
                }
            }
        }
    }
}

// ---------------- Layer 1 aggregation: fp8 gathers (8 B/lane/edge) ----------------
__global__ __launch_bounds__(512) void k_agg1(const int* __restrict__ offs,
                                              const int* __restrict__ colsrc,
                                              const unsigned char* __restrict__ h1f,
                                              const float* __restrict__ es1,
                                              const float* __restrict__ ed1,
                                              const float* __restrict__ b1,
                                              unsigned short* __restrict__ h1p) {
    __shared__ int   sls[8][64];
    __shared__ float sla[8][64][4];
    int lane = threadIdx.x & 63, wv = threadIdx.x >> 6;
    int n = blockIdx.x * 8 + wv;
    if (n >= NN) return;
    int beg = offs[n], end = offs[n + 1], deg = end - beg;
    float4 edv = *(const float4*)(ed1 + n * 4);
    int half = lane >> 5, q5 = lane & 31;
    int hd = q5 >> 3;
    float acc[8];
    #pragma unroll
    for (int j = 0; j < 8; ++j) acc[j] = 0.f;

    if (deg <= 64) {
        int msrc = 0;
        float m0 = 0.f, m1 = 0.f, m2 = 0.f, m3 = 0.f;
        if (lane < deg) {
            msrc = colsrc[beg + lane];
            float4 ev = *(const float4*)(es1 + msrc * 4);
            m0 = __expf(lrelu(ev.x + edv.x));
            m1 = __expf(lrelu(ev.y + edv.y));
            m2 = __expf(lrelu(ev.z + edv.z));
            m3 = __expf(lrelu(ev.w + edv.w));
        }
        float s0 = m0, s1 = m1, s2 = m2, s3 = m3;
        #pragma unroll
        for (int off = 1; off < 64; off <<= 1) {
            s0 += __shfl_xor(s0, off);
            s1 += __shfl_xor(s1, off);
            s2 += __shfl_xor(s2, off);
            s3 += __shfl_xor(s3, off);
        }
        sls[wv][lane] = msrc;
        sla[wv][lane][0] = m0 * (1.f / s0);
        sla[wv][lane][1] = m1 * (1.f / s1);
        sla[wv][lane][2] = m2 * (1.f / s2);
        sla[wv][lane][3] = m3 * (1.f / s3);

        for (int i = 0; i < deg; i += 8) {
            int e0 = (i + half) & 63, e1 = (i + 2 + half) & 63, e2 = (i + 4 + half) & 63, e3 = (i + 6 + half) & 63;
            int   s0i = sls[wv][e0], s1i = sls[wv][e1], s2i = sls[wv][e2], s3i = sls[wv][e3];
            float a0 = sla[wv][e0][hd], a1 = sla[wv][e1][hd], a2 = sla[wv][e2][hd], a3 = sla[wv][e3][hd];
            uint2 h0 = *(const uint2*)(h1f + (size_t)s0i * C1 + q5 * 8);
            uint2 h1 = *(const uint2*)(h1f + (size_t)s1i * C1 + q5 * 8);
            uint2 h2 = *(const uint2*)(h1f + (size_t)s2i * C1 + q5 * 8);
            uint2 h3 = *(const uint2*)(h1f + (size_t)s3i * C1 + q5 * 8);
            #pragma unroll
            for (int w = 0; w < 2; ++w) {
                unsigned w0 = w ? h0.y : h0.x, w1 = w ? h1.y : h1.x;
                unsigned w2 = w ? h2.y : h2.x, w3 = w ? h3.y : h3.x;
                f32x2 p;
                p = __builtin_amdgcn_cvt_pk_f32_fp8(w0, false); acc[w*4+0] += p[0]*a0; acc[w*4+1] += p[1]*a0;
                p = __builtin_amdgcn_cvt_pk_f32_fp8(w0, true);  acc[w*4+2] += p[0]*a0; acc[w*4+3] += p[1]*a0;
                p = __builtin_amdgcn_cvt_pk_f32_fp8(w1, false); acc[w*4+0] += p[0]*a1; acc[w*4+1] += p[1]*a1;
                p = __builtin_amdgcn_cvt_pk_f32_fp8(w1, true);  acc[w*4+2] += p[0]*a1; acc[w*4+3] += p[1]*a1;
                p = __builtin_amdgcn_cvt_pk_f32_fp8(w2, false); acc[w*4+0] += p[0]*a2; acc[w*4+1] += p[1]*a2;
                p = __builtin_amdgcn_cvt_pk_f32_fp8(w2, true);  acc[w*4+2] += p[0]*a2; acc[w*4+3] += p[1]*a2;
                p = __builtin_amdgcn_cvt_pk_f32_fp8(w3, false); acc[w*4+0] += p[0]*a3; acc[w*4+1] += p[1]*a3;
                p = __builtin_amdgcn_cvt_pk_f32_fp8(w3, true);  acc[w*4+2] += p[0]*a3; acc[w*4+3] += p[1]*a3;
            }
        }
    } else {
        float s0 = 0.f, s1 = 0.f, s2 = 0.f, s3 = 0.f;
        for (int i = beg + lane; i < end; i += 64) {
            int s = colsrc[i];
            float4 ev = *(const float4*)(es1 + s * 4);
            s0 += __expf(lrelu(ev.x + edv.x));
            s1 += __expf(lrelu(ev.y + edv.y));
            s2 += __expf(lrelu(ev.z + edv.z));
            s3 += __expf(lrelu(ev.w + edv.w));
        }
        #pragma unroll
        for (int off = 1; off < 64; off <<= 1) {
            s0 += __shfl_xor(s0, off);
            s1 += __shfl_xor(s1, off);
            s2 += __shfl_xor(s2, off);
            s3 += __shfl_xor(s3, off);
        }
        float rr = hd == 0 ? 1.f / s0 : hd == 1 ? 1.f / s1 : hd == 2 ? 1.f / s2 : 1.f / s3;
        float ed_h = hd == 0 ? edv.x : hd == 1 ? edv.y : hd == 2 ? edv.z : edv.w;
        for (int i = beg; i < end; i += 2) {
            int idx = i + half;
            if (idx < end) {
                int s = colsrc[idx];
                float eh = es1[s * 4 + hd] + ed_h;
                float a = __expf(lrelu(eh)) * rr;
                uint2 hv = *(const uint2*)(h1f + (size_t)s * C1 + q5 * 8);
                f32x2 p;
                p = __builtin_amdgcn_cvt_pk_f32_fp8(hv.x, false); acc[0] += p[0]*a; acc[1] += p[1]*a;
                p = __builtin_amdgcn_cvt_pk_f32_fp8(hv.x, true);  acc[2] += p[0]*a; acc[3] += p[1]*a;
                p = __builtin_amdgcn_cvt_pk_f32_fp8(hv.y, false); acc[4] += p[0]*a; acc[5] += p[1]*a;
                p = __builtin_amdgcn_cvt_pk_f32_fp8(hv.y, true);  acc[6] += p[0]*a; acc[7] += p[1]*a;
            }
        }
    }

    #pragma unroll
    for (int j = 0; j < 8; ++j) acc[j] += __shfl_xor(acc[j], 32);

    if (half == 0) {
        float4 bv0 = *(const float4*)(b1 + q5 * 8);
        float4 bv1 = *(const float4*)(b1 + q5 * 8 + 4);
        bf16x8 o;
        o[0] = (short)f2bf(eluf(acc[0] + bv0.x));
        o[1] = (short)f2bf(eluf(acc[1] + bv0.y));
        o[2] = (short)f2bf(eluf(acc[2] + bv0.z));
        o[3] = (short)f2bf(eluf(acc[3] + bv0.w));
        o[4] = (short)f2bf(eluf(acc[4] + bv1.x));
        o[5] = (short)f2bf(eluf(acc[5] + bv1.y));
        o[6] = (short)f2bf(eluf(acc[6] + bv1.z));
        o[7] = (short)f2bf(eluf(acc[7] + bv1.w));
        *(bf16x8*)(h1p + (size_t)n * C1 + q5 * 8) = o;
    }
}

// ---------------- Layer 2 GEMM (MFMA bf16, LDS-staged W) ----------------
__global__ __launch_bounds__(256) void k_gemm2(const unsigned short* __restrict__ h1p,
                                               const unsigned short* __restrict__ W2t,
                                               const float* __restrict__ as2,
                                               const float* __restrict__ ad2,
                                               unsigned short* __restrict__ h2b,
                                               float* __restrict__ es2,
                                               float* __restrict__ ed2) {
    __shared__ unsigned short Wl[HID * C1];   // 32 KB
    int tid = threadIdx.x;
    int lane = tid & 63, wv = tid >> 6;
    int r0 = (blockIdx.x * 4 + wv) * 16;
    int g = lane >> 4, q = lane & 15;

    const uint4* src = (const uint4*)W2t;
    #pragma unroll
    for (int i = 0; i < 8; ++i) {
        int idx = tid + i * 256;
        uint4 v = src[idx];
        unsigned byte = (unsigned)idx << 4;
        unsigned dst = byte ^ (((byte >> 9) & 7) << 4);
        *(uint4*)((char*)Wl + dst) = v;
    }

    int ar = min(r0 + q, NN - 1);
    const unsigned short* arp = h1p + (size_t)ar * C1;
    bf16x8 afr[8];
    #pragma unroll
    for (int kt = 0; kt < 8; ++kt)
        afr[kt] = *(const bf16x8*)(arp + kt * 32 + g * 8);

    __syncthreads();

    float ps[4] = {0.f, 0.f, 0.f, 0.f};
    float pd[4] = {0.f, 0.f, 0.f, 0.f};
    #pragma unroll
    for (int t = 0; t < 4; ++t) {
        int col = t * 16 + q;
        f32x4 acc = {0.f, 0.f, 0.f, 0.f};
        #pragma unroll
        for (int kt = 0; kt < 8; ++kt) {
            unsigned bb = (unsigned)col * 512 + kt * 64 + g * 16;
            bf16x8 b = *(const bf16x8*)((const char*)Wl + (bb ^ (((unsigned)col & 7) << 4)));
            acc = __builtin_amdgcn_mfma_f32_16x16x32_bf16(afr[kt], b, acc, 0, 0, 0);
        }
        float av = as2[col], bv = ad2[col];
        #pragma unroll
        for (int j = 0; j < 4; ++j) {
            int rr = min(r0 + g * 4 + j, NN - 1);
            h2b[(size_t)rr * HID + col] = f2bf(acc[j]);
            ps[j] += acc[j] * av;
            pd[j] += acc[j] * bv;
        }
    }
    #pragma unroll
    for (int j = 0; j < 4; ++j) {
        #pragma unroll
        for (int off = 1; off < 16; off <<= 1) {
            ps[j] += __shfl_xor(ps[j], off);
            pd[j] += __shfl_xor(pd[j], off);
        }
        if (q == 0) {
            int rr = min(r0 + g * 4 + j, NN - 1);
            es2[rr] = ps[j];
            ed2[rr] = pd[j];
        }
    }
}

// ---------------- Layer 2 aggregation: dense h3 output ----------------
__global__ __launch_bounds__(512) void k_agg2(const int* __restrict__ offs,
                                              const int* __restrict__ colsrc,
                                              const unsigned short* __restrict__ h2b,
                                              const float* __restrict__ es2,
                                              const float* __restrict__ ed2,
                                              const float* __restrict__ b2,
                                              float* __restrict__ h3) {
    __shared__ int   sls[8][64];
    __shared__ float sla[8][64];
    int lane = threadIdx.x & 63, wv = threadIdx.x >> 6;
    int n = blockIdx.x * 8 + wv;
    if (n >= NN) return;
    int beg = offs[n], end = offs[n + 1], deg = end - beg;
    float edv = ed2[n];
    int g = lane >> 4, q = lane & 15;
    float acc[4] = {0.f, 0.f, 0.f, 0.f};

    if (deg <= 64) {
        int msrc = 0;
        float mex = 0.f;
        if (lane < deg) {
            msrc = colsrc[beg + lane];
            mex = __expf(lrelu(es2[msrc] + edv));
        }
        float ss = mex;
        #pragma unroll
        for (int off = 1; off < 64; off <<= 1) ss += __shfl_xor(ss, off);
        sls[wv][lane] = msrc;
        sla[wv][lane] = mex * (1.f / ss);

        for (int i = 0; i < deg; i += 16) {
            int e0 = (i + g) & 63, e1 = (i + 4 + g) & 63, e2 = (i + 8 + g) & 63, e3 = (i + 12 + g) & 63;
            int   s0i = sls[wv][e0], s1i = sls[wv][e1], s2i = sls[wv][e2], s3i = sls[wv][e3];
            float a0 = sla[wv][e0], a1 = sla[wv][e1], a2 = sla[wv][e2], a3 = sla[wv][e3];
            bf16x4 h0 = *(const bf16x4*)(h2b + (size_t)s0i * HID + q * 4);
            bf16x4 h1 = *(const bf16x4*)(h2b + (size_t)s1i * HID + q * 4);
            bf16x4 h2v = *(const bf16x4*)(h2b + (size_t)s2i * HID + q * 4);
            bf16x4 h3v = *(const bf16x4*)(h2b + (size_t)s3i * HID + q * 4);
            #pragma unroll
            for (int j = 0; j < 4; ++j)
                acc[j] += bf2f((unsigned short)h0[j]) * a0 + bf2f((unsigned short)h1[j]) * a1
                        + bf2f((unsigned short)h2v[j]) * a2 + bf2f((unsigned short)h3v[j]) * a3;
        }
    } else {
        float ss = 0.f;
        for (int i = beg + lane; i < end; i += 64) {
            int s = colsrc[i];
            ss += __expf(lrelu(es2[s] + edv));
        }
        #pragma unroll
        for (int off = 1; off < 64; off <<= 1) ss += __shfl_xor(ss, off);
        float rs = 1.f / ss;
        for (int i = beg; i < end; i += 4) {
            int idx = i + g;
            if (idx < end) {
                int s = colsrc[idx];
                float a = __expf(lrelu(es2[s] + edv)) * rs;
                bf16x4 hv = *(const bf16x4*)(h2b + (size_t)s * HID + q * 4);
                #pragma unroll
                for (int j = 0; j < 4; ++j) acc[j] += bf2f((unsigned short)hv[j]) * a;
            }
        }
    }

    #pragma unroll
    for (int j = 0; j < 4; ++j) {
        acc[j] += __shfl_xor(acc[j], 16);
        acc[j] += __shfl_xor(acc[j], 32);
    }

    float v0 = __shfl(acc[0], lane >> 2);
    float v1 = __shfl(acc[1], lane >> 2);
    float v2 = __shfl(acc[2], lane >> 2);
    float v3 = __shfl(acc[3], lane >> 2);
    int jj = lane & 3;
    float o = jj == 0 ? v0 : jj == 1 ? v1 : jj == 2 ? v2 : v3;
    h3[(size_t)n * HID + lane] = eluf(o + b2[lane]);
}

// ---------------- fused mean-pool + classifier ----------------
__global__ __launch_bounds__(256) void k_poolcls(const float* __restrict__ h3,
                                                 const int* __restrict__ gstart,
                                                 const float* __restrict__ Wc,
                                                 const float* __restrict__ bc,
                                                 float* __restrict__ out) {
    __shared__ float red[4][64];
    int g = blockIdx.x;
    int lane = threadIdx.x & 63, wv = threadIdx.x >> 6;
    int gs = gstart[g], ge = gstart[g + 1];
    float acc = 0.f;
    for (int r = gs + wv; r < ge; r += 4)
        acc += h3[(size_t)r * HID + lane];
    red[wv][lane] = acc;
    __syncthreads();
    if (wv == 0) {
        float p = red[0][lane] + red[1][lane] + red[2][lane] + red[3][lane];
        float c = fmaxf((float)(ge - gs), 1.f);
        p /= c;
        float s0 = p * Wc[lane * 2 + 0];
        float s1 = p * Wc[lane * 2 + 1];
        #pragma unroll
        for (int off = 1; off < 64; off <<= 1) {
            s0 += __shfl_xor(s0, off);
            s1 += __shfl_xor(s1, off);
        }
        if (lane == 0) {
            out[g * 2 + 0] = s0 + bc[0];
            out[g * 2 + 1] = s1 + bc[1];
        }
    }
}

extern "C" void kernel_launch(void* const* d_in, const int* in_sizes, int n_in,
                              void* d_out, int out_size, void* d_ws, size_t ws_size,
                              hipStream_t stream) {
    const float* x   = (const float*)d_in[0];
    const int* ei    = (const int*)d_in[1];
    const int* batch = (const int*)d_in[2];
    const float* W1  = (const float*)d_in[4];
    const float* as1 = (const float*)d_in[5];
    const float* ad1 = (const float*)d_in[6];
    const float* b1  = (const float*)d_in[7];
    const float* W2  = (const float*)d_in[8];
    const float* as2 = (const float*)d_in[9];
    const float* ad2 = (const float*)d_in[10];
    const float* b2  = (const float*)d_in[11];
    const float* Wc  = (const float*)d_in[12];
    const float* bc  = (const float*)d_in[13];
    float* out = (float*)d_out;

    char* p = (char*)d_ws;
    auto alloc = [&](size_t bytes) -> char* {
        char* r = p;
        p += (bytes + 255) & ~(size_t)255;
        return r;
    };
    int* offs    = (int*)alloc((NN + 1) * sizeof(int));
    int* colsrc  = (int*)alloc((size_t)ETOT * sizeof(int));
    int2* ebuf   = (int2*)alloc((size_t)NE * sizeof(int2));
    int* bhist   = (int*)alloc(NBUK * sizeof(int));
    int* bbase   = (int*)alloc((NBUK + 1) * sizeof(int));
    int* bcur    = (int*)alloc(NBUK * sizeof(int));
    int* gstart  = (int*)alloc((NG + 1) * sizeof(int));
    unsigned short* W1t = (unsigned short*)alloc((size_t)FIN * C1 * sizeof(short));
    unsigned short* W2t = (unsigned short*)alloc((size_t)C1 * HID * sizeof(short));
    unsigned char* h1f  = (unsigned char*)alloc((size_t)NN * C1);          // fp8 h1
    unsigned short* h1p = (unsigned short*)alloc((size_t)NN * C1 * sizeof(short));
    unsigned short* h2b = (unsigned short*)alloc((size_t)NN * HID * sizeof(short));
    float* es1   = (float*)alloc((size_t)NN * 4 * sizeof(float));
    float* ed1   = (float*)alloc((size_t)NN * 4 * sizeof(float));
    float* es2v  = (float*)alloc((size_t)NN * sizeof(float));
    float* ed2v  = (float*)alloc((size_t)NN * sizeof(float));
    float* h3    = (float*)alloc((size_t)NN * HID * sizeof(float));

    hipMemsetAsync(bhist, 0, NBUK * sizeof(int), stream);

    const int* srcA = ei;       // edge_index[0]
    const int* dstA = ei + NE;  // edge_index[1]

    k_prep<<<(FIN * C1 + C1 * HID + 255) / 256, 256, 0, stream>>>(W1, W2, W1t, W2t);
    k_hist<<<256, 256, 0, stream>>>(dstA, bhist);
    k_bscan<<<1, 64, 0, stream>>>(bhist, bbase, bcur, offs);
    k_part<<<NCHUNK, 256, 0, stream>>>(srcA, dstA, bcur, ebuf);
    k_bfill<<<NBUK, 1024, 0, stream>>>(ebuf, bbase, offs, colsrc);
    k_gstart<<<1, 512, 0, stream>>>(batch, gstart);

    k_gemm1<<<(NN / 16 + 3) / 4, 256, 0, stream>>>(x, W1t, as1, ad1, h1f, es1, ed1);
    k_agg1<<<(NN + 7) / 8, 512, 0, stream>>>(offs, colsrc, h1f, es1, ed1, b1, h1p);
    k_gemm2<<<(NN / 16 + 3) / 4, 256, 0, stream>>>(h1p, W2t, as2, ad2, h2b, es2v, ed2v);
    k_agg2<<<(NN + 7) / 8, 512, 0, stream>>>(offs, colsrc, h2b, es2v, ed2v, b2, h3);
    k_poolcls<<<NG, 256, 0, stream>>>(h3, gstart, Wc, bc, out);
}

// Round 9
// 191.411 us; speedup vs baseline: 3.4648x; 1.0188x over previous
//
#include <hip/hip_runtime.h>

#define NN   50000
#define NE   1000000
#define FIN  128
#define HID  64
#define HEADS 4
#define C1   256          // HEADS*HID
#define NG   512
#define ETOT (NE + NN)    // edges + self-loops
#define BSH  10           // bucket = dst >> 10 (1024 nodes/bucket)
#define NBUK 49           // ceil(NN/1024)
#define CHUNK 8192
#define NCHUNK 123        // ceil(NE/CHUNK)

typedef __attribute__((ext_vector_type(8))) short bf16x8;
typedef __attribute__((ext_vector_type(4))) short bf16x4;
typedef __attribute__((ext_vector_type(4))) float f32x4;
typedef __attribute__((ext_vector_type(2))) float f32x2;

__device__ __forceinline__ float lrelu(float v) { return v > 0.f ? v : 0.2f * v; }
__device__ __forceinline__ float eluf(float v)  { return v > 0.f ? v : __expf(v) - 1.f; }

__device__ __forceinline__ unsigned short f2bf(float f) {
    unsigned u = __float_as_uint(f);
    unsigned r = (u + 0x7FFFu + ((u >> 16) & 1u)) >> 16;
    return (unsigned short)r;
}
__device__ __forceinline__ float bf2f(unsigned short b) {
    return __uint_as_float(((unsigned)b) << 16);
}
__device__ __forceinline__ unsigned char f2fp8(float f) {
    int w = __builtin_amdgcn_cvt_pk_fp8_f32(f, f, 0, false);
    return (unsigned char)(w & 0xFF);
}

// ---------------- weight prep: transpose + bf16 cast ----------------
__global__ __launch_bounds__(256) void k_prep(const float* __restrict__ W1,
                                              const float* __restrict__ W2,
                                              unsigned short* __restrict__ W1t,
                                              unsigned short* __restrict__ W2t) {
    int i = blockIdx.x * 256 + threadIdx.x;
    if (i < FIN * C1) {
        int k = i / C1, c = i % C1;
        W1t[c * FIN + k] = f2bf(W1[i]);
    } else {
        int j = i - FIN * C1;
        if (j < C1 * HID) {
            int k = j / HID, c = j % HID;
            W2t[c * C1 + k] = f2bf(W2[j]);
        }
    }
}

// ---------------- CSR build via bucket counting-sort ----------------
__global__ __launch_bounds__(256) void k_hist(const int* __restrict__ dst,
                                              int* __restrict__ bhist) {
    __shared__ int lh[NBUK];
    int tid = threadIdx.x;
    if (tid < NBUK) lh[tid] = 0;
    __syncthreads();
    for (int e = blockIdx.x * 256 + tid; e < NE; e += gridDim.x * 256)
        atomicAdd(&lh[dst[e] >> BSH], 1);
    __syncthreads();
    if (tid < NBUK) atomicAdd(&bhist[tid], lh[tid]);
}

__global__ void k_bscan(const int* __restrict__ bhist,
                        int* __restrict__ bbase,
                        int* __restrict__ bcur,
                        int* __restrict__ offs) {
    int tid = threadIdx.x;   // 1 block, 64 threads
    int v = (tid < NBUK) ? bhist[tid] : 0;
    int x = v;
    #pragma unroll
    for (int off = 1; off < 64; off <<= 1) {
        int t = __shfl_up(x, off);
        if (tid >= off) x += t;
    }
    if (tid < NBUK) {
        int excl = x - v;
        bbase[tid] = excl;
        bcur[tid] = excl;
    }
    if (tid == NBUK - 1) bbase[NBUK] = x;   // = NE
    if (tid == 0) offs[NN] = ETOT;
}

// chunk-wise partition: edges -> bucket-contiguous ebuf (src,dst)
__global__ __launch_bounds__(256) void k_part(const int* __restrict__ src,
                                              const int* __restrict__ dst,
                                              int* __restrict__ bcur,
                                              int2* __restrict__ ebuf) {
    __shared__ int lcnt[NBUK];
    __shared__ int gbase[NBUK];
    __shared__ int lrank[NBUK];
    int tid = threadIdx.x;
    int e0 = blockIdx.x * CHUNK;
    int e1 = min(e0 + CHUNK, NE);
    if (tid < NBUK) { lcnt[tid] = 0; lrank[tid] = 0; }
    __syncthreads();
    for (int e = e0 + tid; e < e1; e += 256)
        atomicAdd(&lcnt[dst[e] >> BSH], 1);
    __syncthreads();
    if (tid < NBUK) gbase[tid] = atomicAdd(&bcur[tid], lcnt[tid]);
    __syncthreads();
    for (int e = e0 + tid; e < e1; e += 256) {
        int d = dst[e];
        int b = d >> BSH;
        int r = atomicAdd(&lrank[b], 1);
        ebuf[gbase[b] + r] = make_int2(src[e], d);
    }
}

// per-bucket: local degrees -> scan -> offs + colsrc fill (all XCD-local)
__global__ __launch_bounds__(1024) void k_bfill(const int2* __restrict__ ebuf,
                                                const int* __restrict__ bbase,
                                                int* __restrict__ offs,
                                                int* __restrict__ colsrc) {
    __shared__ int ldeg[1024];
    __shared__ int lcur[1024];
    __shared__ int ws[16];
    int b = blockIdx.x;
    int tid = threadIdx.x;
    int nbase = b << BSH;
    int ncnt = min(1024, NN - nbase);
    int ebeg = bbase[b], eend = bbase[b + 1];
    ldeg[tid] = 0;
    __syncthreads();
    for (int i = ebeg + tid; i < eend; i += 1024)
        atomicAdd(&ldeg[ebuf[i].y - nbase], 1);
    __syncthreads();
    int v = (tid < ncnt) ? ldeg[tid] + 1 : 0;
    int lane = tid & 63, wv = tid >> 6;
    int x = v;
    #pragma unroll
    for (int off = 1; off < 64; off <<= 1) {
        int t = __shfl_up(x, off);
        if (lane >= off) x += t;
    }
    if (lane == 63) ws[wv] = x;
    __syncthreads();
    if (tid < 16) {
        int y = ws[tid];
        #pragma unroll
        for (int off = 1; off < 16; off <<= 1) {
            int t = __shfl_up(y, off);
            if (tid >= off) y += t;
        }
        ws[tid] = y;
    }
    __syncthreads();
    int base = wv ? ws[wv - 1] : 0;
    int excl = base + x - v;
    int gofs = ebeg + nbase + excl;
    if (tid < ncnt) {
        offs[nbase + tid] = gofs;
        lcur[tid] = gofs;
    }
    __syncthreads();
    for (int i = ebeg + tid; i < eend; i += 1024) {
        int2 ed = ebuf[i];
        int p = atomicAdd(&lcur[ed.y - nbase], 1);
        colsrc[p] = ed.x;
    }
    __syncthreads();
    if (tid < ncnt) colsrc[lcur[tid]] = nbase + tid;   // self-loop at segment end
}

// ---------------- graph boundaries ----------------
__global__ __launch_bounds__(512) void k_gstart(const int* __restrict__ batch,
                                                int* __restrict__ gstart) {
    for (int g = threadIdx.x; g <= NG; g += 512) {
        int lo = 0, hi = NN;
        while (lo < hi) {
            int mid = (lo + hi) >> 1;
            if (batch[mid] < g) lo = mid + 1; else hi = mid;
        }
        gstart[g] = lo;
    }
}

// ---------------- Layer 1 GEMM (MFMA bf16, LDS-staged W, fp8 h1 output) ----------------
__global__ __launch_bounds__(256) void k_gemm1(const float* __restrict__ x,
                                               const unsigned short* __restrict__ W1t,
                                               const float* __restrict__ asrc,
                                               const float* __restrict__ adst,
                                               unsigned char* __restrict__ h1f,
                                               float* __restrict__ es1,
                                               float* __restrict__ ed1) {
    __shared__ unsigned short Wl[128 * FIN];   // 32 KB
    int tid = threadIdx.x;
    int lane = tid & 63, wv = tid >> 6;
    int r0 = (blockIdx.x * 4 + wv) * 16;
    int g = lane >> 4, q = lane & 15;

    int ar = min(r0 + q, NN - 1);
    const float* xr = x + (size_t)ar * FIN;
    bf16x8 afr[4];
    #pragma unroll
    for (int kt = 0; kt < 4; ++kt) {
        float4 u0 = *(const float4*)(xr + kt * 32 + g * 8);
        float4 u1 = *(const float4*)(xr + kt * 32 + g * 8 + 4);
        bf16x8 a;
        a[0] = (short)f2bf(u0.x); a[1] = (short)f2bf(u0.y);
        a[2] = (short)f2bf(u0.z); a[3] = (short)f2bf(u0.w);
        a[4] = (short)f2bf(u1.x); a[5] = (short)f2bf(u1.y);
        a[6] = (short)f2bf(u1.z); a[7] = (short)f2bf(u1.w);
        afr[kt] = a;
    }

    for (int ch = 0; ch < 2; ++ch) {
        if (ch) __syncthreads();
        const uint4* src = (const uint4*)(W1t + (size_t)ch * 128 * FIN);
        #pragma unroll
        for (int i = 0; i < 8; ++i) {
            int idx = tid + i * 256;
            uint4 v = src[idx];
            unsigned byte = (unsigned)idx << 4;
            unsigned dst = byte ^ (((byte >> 8) & 7) << 4);
            *(uint4*)((char*)Wl + dst) = v;
        }
        __syncthreads();

        #pragma unroll
        for (int hh = 0; hh < 2; ++hh) {
            int h = ch * 2 + hh;
            float ps[4] = {0.f, 0.f, 0.f, 0.f};
            float pd[4] = {0.f, 0.f, 0.f, 0.f};
            #pragma unroll
            for (int tl = 0; tl < 4; ++tl) {
                int col = (h * 4 + tl) * 16 + q;
                int cl = col - ch * 128;
                f32x4 acc = {0.f, 0.f, 0.f, 0.f};
                #pragma unroll
                for (int kt = 0; kt < 4; ++kt) {
                    unsigned bb = (unsigned)cl * 256 + kt * 64 + g * 16;
                    bf16x8 b = *(const bf16x8*)((const char*)Wl + (bb ^ (((unsigned)cl & 7) << 4)));
                    acc = __builtin_amdgcn_mfma_f32_16x16x32_bf16(afr[kt], b, acc, 0, 0, 0);
                }
                float av = asrc[col], bv = adst[col];
                #pragma unroll
                for (int j = 0; j < 4; ++j) {
                    int rr = min(r0 + g * 4 + j, NN - 1);
                    h1f[(size_t)rr * C1 + col] = f2fp8(acc[j]);
                    ps[j] += acc[j] * av;
                    pd[j] += acc[j] * bv;
                }
            }
            #pragma unroll
            for (int j = 0; j < 4; ++j) {
                #pragma unroll
                for (int off = 1; off < 16; off <<= 1) {
                    ps[j] += __shfl_xor(ps[j], off);
                    pd[j] += __shfl_xor(pd[j], off);
                }
                if (q == 0) {
                    int rr = min(r0 + g * 4 + j, NN - 1);
                    es1[rr * 4 + h] = ps[j];
                    ed1[rr * 4 + h] = pd[j];
                }
            }
        }
    }
}

// ---------------- Layer 1 aggregation: fp8 gathers, packed f32x2 accumulate ----------------
__global__ __launch_bounds__(512) void k_agg1(const int* __restrict__ offs,
                                              const int* __restrict__ colsrc,
                                              const unsigned char* __restrict__ h1f,
                                              const float* __restrict__ es1,
                                              const float* __restrict__ ed1,
                                              const float* __restrict__ b1,
                                              unsigned short* __restrict__ h1p) {
    __shared__ int   sls[8][64];
    __shared__ float sla[8][64][4];
    int lane = threadIdx.x & 63, wv = threadIdx.x >> 6;
    int n = blockIdx.x * 8 + wv;
    if (n >= NN) return;
    int beg = offs[n], end = offs[n + 1], deg = end - beg;
    float4 edv = *(const float4*)(ed1 + n * 4);
    int half = lane >> 5, q5 = lane & 31;
    int hd = q5 >> 3;
    f32x2 acc2[4];
    #pragma unroll
    for (int j = 0; j < 4; ++j) acc2[j] = (f32x2){0.f, 0.f};

    if (deg <= 64) {
        int msrc = 0;
        float m0 = 0.f, m1 = 0.f, m2 = 0.f, m3 = 0.f;
        if (lane < deg) {
            msrc = colsrc[beg + lane];
            float4 ev = *(const float4*)(es1 + msrc * 4);
            m0 = __expf(lrelu(ev.x + edv.x));
            m1 = __expf(lrelu(ev.y + edv.y));
            m2 = __expf(lrelu(ev.z + edv.z));
            m3 = __expf(lrelu(ev.w + edv.w));
        }
        float s0 = m0, s1 = m1, s2 = m2, s3 = m3;
        #pragma unroll
        for (int off = 1; off < 64; off <<= 1) {
            s0 += __shfl_xor(s0, off);
            s1 += __shfl_xor(s1, off);
            s2 += __shfl_xor(s2, off);
            s3 += __shfl_xor(s3, off);
        }
        sls[wv][lane] = msrc;
        sla[wv][lane][0] = m0 * (1.f / s0);
        sla[wv][lane][1] = m1 * (1.f / s1);
        sla[wv][lane][2] = m2 * (1.f / s2);
        sla[wv][lane][3] = m3 * (1.f / s3);

        for (int i = 0; i < deg; i += 8) {
            int e0 = (i + half) & 63, e1 = (i + 2 + half) & 63, e2 = (i + 4 + half) & 63, e3 = (i + 6 + half) & 63;
            int   s0i = sls[wv][e0], s1i = sls[wv][e1], s2i = sls[wv][e2], s3i = sls[wv][e3];
            f32x2 a0 = (f32x2){sla[wv][e0][hd], sla[wv][e0][hd]};
            f32x2 a1 = (f32x2){sla[wv][e1][hd], sla[wv][e1][hd]};
            f32x2 a2 = (f32x2){sla[wv][e2][hd], sla[wv][e2][hd]};
            f32x2 a3 = (f32x2){sla[wv][e3][hd], sla[wv][e3][hd]};
            uint2 h0 = *(const uint2*)(h1f + (size_t)s0i * C1 + q5 * 8);
            uint2 h1 = *(const uint2*)(h1f + (size_t)s1i * C1 + q5 * 8);
            uint2 h2 = *(const uint2*)(h1f + (size_t)s2i * C1 + q5 * 8);
            uint2 h3 = *(const uint2*)(h1f + (size_t)s3i * C1 + q5 * 8);
            f32x2 p;
            p = __builtin_amdgcn_cvt_pk_f32_fp8(h0.x, false); acc2[0] += p * a0;
            p = __builtin_amdgcn_cvt_pk_f32_fp8(h0.x, true);  acc2[1] += p * a0;
            p = __builtin_amdgcn_cvt_pk_f32_fp8(h0.y, false); acc2[2] += p * a0;
            p = __builtin_amdgcn_cvt_pk_f32_fp8(h0.y, true);  acc2[3] += p * a0;
            p = __builtin_amdgcn_cvt_pk_f32_fp8(h1.x, false); acc2[0] += p * a1;
            p = __builtin_amdgcn_cvt_pk_f32_fp8(h1.x, true);  acc2[1] += p * a1;
            p = __builtin_amdgcn_cvt_pk_f32_fp8(h1.y, false); acc2[2] += p * a1;
            p = __builtin_amdgcn_cvt_pk_f32_fp8(h1.y, true);  acc2[3] += p * a1;
            p = __builtin_amdgcn_cvt_pk_f32_fp8(h2.x, false); acc2[0] += p * a2;
            p = __builtin_amdgcn_cvt_pk_f32_fp8(h2.x, true);  acc2[1] += p * a2;
            p = __builtin_amdgcn_cvt_pk_f32_fp8(h2.y, false); acc2[2] += p * a2;
            p = __builtin_amdgcn_cvt_pk_f32_fp8(h2.y, true);  acc2[3] += p * a2;
            p = __builtin_amdgcn_cvt_pk_f32_fp8(h3.x, false); acc2[0] += p * a3;
            p = __builtin_amdgcn_cvt_pk_f32_fp8(h3.x, true);  acc2[1] += p * a3;
            p = __builtin_amdgcn_cvt_pk_f32_fp8(h3.y, false); acc2[2] += p * a3;
            p = __builtin_amdgcn_cvt_pk_f32_fp8(h3.y, true);  acc2[3] += p * a3;
        }
    } else {
        float s0 = 0.f, s1 = 0.f, s2 = 0.f, s3 = 0.f;
        for (int i = beg + lane; i < end; i += 64) {
            int s = colsrc[i];
            float4 ev = *(const float4*)(es1 + s * 4);
            s0 += __expf(lrelu(ev.x + edv.x));
            s1 += __expf(lrelu(ev.y + edv.y));
            s2 += __expf(lrelu(ev.z + edv.z));
            s3 += __expf(lrelu(ev.w + edv.w));
        }
        #pragma unroll
        for (int off = 1; off < 64; off <<= 1) {
            s0 += __shfl_xor(s0, off);
            s1 += __shfl_xor(s1, off);
            s2 += __shfl_xor(s2, off);
            s3 += __shfl_xor(s3, off);
        }
        float rr = hd == 0 ? 1.f / s0 : hd == 1 ? 1.f / s1 : hd == 2 ? 1.f / s2 : 1.f / s3;
        float ed_h = hd == 0 ? edv.x : hd == 1 ? edv.y : hd == 2 ? edv.z : edv.w;
        for (int i = beg; i < end; i += 2) {
            int idx = i + half;
            if (idx < end) {
                int s = colsrc[idx];
                float eh = es1[s * 4 + hd] + ed_h;
                float av = __expf(lrelu(eh)) * rr;
                f32x2 a = (f32x2){av, av};
                uint2 hv = *(const uint2*)(h1f + (size_t)s * C1 + q5 * 8);
                f32x2 p;
                p = __builtin_amdgcn_cvt_pk_f32_fp8(hv.x, false); acc2[0] += p * a;
                p = __builtin_amdgcn_cvt_pk_f32_fp8(hv.x, true);  acc2[1] += p * a;
                p = __builtin_amdgcn_cvt_pk_f32_fp8(hv.y, false); acc2[2] += p * a;
                p = __builtin_amdgcn_cvt_pk_f32_fp8(hv.y, true);  acc2[3] += p * a;
            }
        }
    }

    float acc[8];
    #pragma unroll
    for (int j = 0; j < 4; ++j) { acc[2*j] = acc2[j][0]; acc[2*j+1] = acc2[j][1]; }
    #pragma unroll
    for (int j = 0; j < 8; ++j) acc[j] += __shfl_xor(acc[j], 32);

    if (half == 0) {
        float4 bv0 = *(const float4*)(b1 + q5 * 8);
        float4 bv1 = *(const float4*)(b1 + q5 * 8 + 4);
        bf16x8 o;
        o[0] = (short)f2bf(eluf(acc[0] + bv0.x));
        o[1] = (short)f2bf(eluf(acc[1] + bv0.y));
        o[2] = (short)f2bf(eluf(acc[2] + bv0.z));
        o[3] = (short)f2bf(eluf(acc[3] + bv0.w));
        o[4] = (short)f2bf(eluf(acc[4] + bv1.x));
        o[5] = (short)f2bf(eluf(acc[5] + bv1.y));
        o[6] = (short)f2bf(eluf(acc[6] + bv1.z));
        o[7] = (short)f2bf(eluf(acc[7] + bv1.w));
        *(bf16x8*)(h1p + (size_t)n * C1 + q5 * 8) = o;
    }
}

// ---------------- Layer 2 GEMM (MFMA bf16, LDS-staged W, fp8 h2 output) ----------------
__global__ __launch_bounds__(256) void k_gemm2(const unsigned short* __restrict__ h1p,
                                               const unsigned short* __restrict__ W2t,
                                               const float* __restrict__ as2,
                                               const float* __restrict__ ad2,
                                               unsigned char* __restrict__ h2f,
                                               float* __restrict__ es2,
                                               float* __restrict__ ed2) {
    __shared__ unsigned short Wl[HID * C1];   // 32 KB
    int tid = threadIdx.x;
    int lane = tid & 63, wv = tid >> 6;
    int r0 = (blockIdx.x * 4 + wv) * 16;
    int g = lane >> 4, q = lane & 15;

    const uint4* src = (const uint4*)W2t;
    #pragma unroll
    for (int i = 0; i < 8; ++i) {
        int idx = tid + i * 256;
        uint4 v = src[idx];
        unsigned byte = (unsigned)idx << 4;
        unsigned dst = byte ^ (((byte >> 9) & 7) << 4);
        *(uint4*)((char*)Wl + dst) = v;
    }

    int ar = min(r0 + q, NN - 1);
    const unsigned short* arp = h1p + (size_t)ar * C1;
    bf16x8 afr[8];
    #pragma unroll
    for (int kt = 0; kt < 8; ++kt)
        afr[kt] = *(const bf16x8*)(arp + kt * 32 + g * 8);

    __syncthreads();

    float ps[4] = {0.f, 0.f, 0.f, 0.f};
    float pd[4] = {0.f, 0.f, 0.f, 0.f};
    #pragma unroll
    for (int t = 0; t < 4; ++t) {
        int col = t * 16 + q;
        f32x4 acc = {0.f, 0.f, 0.f, 0.f};
        #pragma unroll
        for (int kt = 0; kt < 8; ++kt) {
            unsigned bb = (unsigned)col * 512 + kt * 64 + g * 16;
            bf16x8 b = *(const bf16x8*)((const char*)Wl + (bb ^ (((unsigned)col & 7) << 4)));
            acc = __builtin_amdgcn_mfma_f32_16x16x32_bf16(afr[kt], b, acc, 0, 0, 0);
        }
        float av = as2[col], bv = ad2[col];
        #pragma unroll
        for (int j = 0; j < 4; ++j) {
            int rr = min(r0 + g * 4 + j, NN - 1);
            h2f[(size_t)rr * HID + col] = f2fp8(acc[j]);
            ps[j] += acc[j] * av;
            pd[j] += acc[j] * bv;
        }
    }
    #pragma unroll
    for (int j = 0; j < 4; ++j) {
        #pragma unroll
        for (int off = 1; off < 16; off <<= 1) {
            ps[j] += __shfl_xor(ps[j], off);
            pd[j] += __shfl_xor(pd[j], off);
        }
        if (q == 0) {
            int rr = min(r0 + g * 4 + j, NN - 1);
            es2[rr] = ps[j];
            ed2[rr] = pd[j];
        }
    }
}

// ---------------- Layer 2 aggregation: fp8 gathers, packed accumulate ----------------
__global__ __launch_bounds__(512) void k_agg2(const int* __restrict__ offs,
                                              const int* __restrict__ colsrc,
                                              const unsigned char* __restrict__ h2f,
                                              const float* __restrict__ es2,
                                              const float* __restrict__ ed2,
                                              const float* __restrict__ b2,
                                              float* __restrict__ h3) {
    __shared__ int   sls[8][64];
    __shared__ float sla[8][64];
    int lane = threadIdx.x & 63, wv = threadIdx.x >> 6;
    int n = blockIdx.x * 8 + wv;
    if (n >= NN) return;
    int beg = offs[n], end = offs[n + 1], deg = end - beg;
    float edv = ed2[n];
    int g = lane >> 4, q = lane & 15;
    f32x2 acc2[2];
    acc2[0] = (f32x2){0.f, 0.f};
    acc2[1] = (f32x2){0.f, 0.f};

    if (deg <= 64) {
        int msrc = 0;
        float mex = 0.f;
        if (lane < deg) {
            msrc = colsrc[beg + lane];
            mex = __expf(lrelu(es2[msrc] + edv));
        }
        float ss = mex;
        #pragma unroll
        for (int off = 1; off < 64; off <<= 1) ss += __shfl_xor(ss, off);
        sls[wv][lane] = msrc;
        sla[wv][lane] = mex * (1.f / ss);

        for (int i = 0; i < deg; i += 16) {
            int e0 = (i + g) & 63, e1 = (i + 4 + g) & 63, e2 = (i + 8 + g) & 63, e3 = (i + 12 + g) & 63;
            int   s0i = sls[wv][e0], s1i = sls[wv][e1], s2i = sls[wv][e2], s3i = sls[wv][e3];
            f32x2 a0 = (f32x2){sla[wv][e0], sla[wv][e0]};
            f32x2 a1 = (f32x2){sla[wv][e1], sla[wv][e1]};
            f32x2 a2 = (f32x2){sla[wv][e2], sla[wv][e2]};
            f32x2 a3 = (f32x2){sla[wv][e3], sla[wv][e3]};
            unsigned w0 = *(const unsigned*)(h2f + (size_t)s0i * HID + q * 4);
            unsigned w1 = *(const unsigned*)(h2f + (size_t)s1i * HID + q * 4);
            unsigned w2 = *(const unsigned*)(h2f + (size_t)s2i * HID + q * 4);
            unsigned w3 = *(const unsigned*)(h2f + (size_t)s3i * HID + q * 4);
            f32x2 p;
            p = __builtin_amdgcn_cvt_pk_f32_fp8(w0, false); acc2[0] += p * a0;
            p = __builtin_amdgcn_cvt_pk_f32_fp8(w0, true);  acc2[1] += p * a0;
            p = __builtin_amdgcn_cvt_pk_f32_fp8(w1, false); acc2[0] += p * a1;
            p = __builtin_amdgcn_cvt_pk_f32_fp8(w1, true);  acc2[1] += p * a1;
            p = __builtin_amdgcn_cvt_pk_f32_fp8(w2, false); acc2[0] += p * a2;
            p = __builtin_amdgcn_cvt_pk_f32_fp8(w2, true);  acc2[1] += p * a2;
            p = __builtin_amdgcn_cvt_pk_f32_fp8(w3, false); acc2[0] += p * a3;
            p = __builtin_amdgcn_cvt_pk_f32_fp8(w3, true);  acc2[1] += p * a3;
        }
    } else {
        float ss = 0.f;
        for (int i = beg + lane; i < end; i += 64) {
            int s = colsrc[i];
            ss += __expf(lrelu(es2[s] + edv));
        }
        #pragma unroll
        for (int off = 1; off < 64; off <<= 1) ss += __shfl_xor(ss, off);
        float rs = 1.f / ss;
        for (int i = beg; i < end; i += 4) {
            int idx = i + g;
            if (idx < end) {
                int s = colsrc[idx];
                float av = __expf(lrelu(es2[s] + edv)) * rs;
                f32x2 a = (f32x2){av, av};
                unsigned w = *(const unsigned*)(h2f + (size_t)s * HID + q * 4);
                f32x2 p;
                p = __builtin_amdgcn_cvt_pk_f32_fp8(w, false); acc2[0] += p * a;
                p = __builtin_amdgcn_cvt_pk_f32_fp8(w, true);  acc2[1] += p * a;
            }
        }
    }

    float acc[4] = {acc2[0][0], acc2[0][1], acc2[1][0], acc2[1][1]};
    #pragma unroll
    for (int j = 0; j < 4; ++j) {
        acc[j] += __shfl_xor(acc[j], 16);
        acc[j] += __shfl_xor(acc[j], 32);
    }

    float v0 = __shfl(acc[0], lane >> 2);
    float v1 = __shfl(acc[1], lane >> 2);
    float v2 = __shfl(acc[2], lane >> 2);
    float v3 = __shfl(acc[3], lane >> 2);
    int jj = lane & 3;
    float o = jj == 0 ? v0 : jj == 1 ? v1 : jj == 2 ? v2 : v3;
    h3[(size_t)n * HID + lane] = eluf(o + b2[lane]);
}

// ---------------- fused mean-pool + classifier ----------------
__global__ __launch_bounds__(256) void k_poolcls(const float* __restrict__ h3,
                                                 const int* __restrict__ gstart,
                                                 const float* __restrict__ Wc,
                                                 const float* __restrict__ bc,
                                                 float* __restrict__ out) {
    __shared__ float red[4][64];
    int g = blockIdx.x;
    int lane = threadIdx.x & 63, wv = threadIdx.x >> 6;
    int gs = gstart[g], ge = gstart[g + 1];
    float acc = 0.f;
    for (int r = gs + wv; r < ge; r += 4)
        acc += h3[(size_t)r * HID + lane];
    red[wv][lane] = acc;
    __syncthreads();
    if (wv == 0) {
        float p = red[0][lane] + red[1][lane] + red[2][lane] + red[3][lane];
        float c = fmaxf((float)(ge - gs), 1.f);
        p /= c;
        float s0 = p * Wc[lane * 2 + 0];
        float s1 = p * Wc[lane * 2 + 1];
        #pragma unroll
        for (int off = 1; off < 64; off <<= 1) {
            s0 += __shfl_xor(s0, off);
            s1 += __shfl_xor(s1, off);
        }
        if (lane == 0) {
            out[g * 2 + 0] = s0 + bc[0];
            out[g * 2 + 1] = s1 + bc[1];
        }
    }
}

extern "C" void kernel_launch(void* const* d_in, const int* in_sizes, int n_in,
                              void* d_out, int out_size, void* d_ws, size_t ws_size,
                              hipStream_t stream) {
    const float* x   = (const float*)d_in[0];
    const int* ei    = (const int*)d_in[1];
    const int* batch = (const int*)d_in[2];
    const float* W1  = (const float*)d_in[4];
    const float* as1 = (const float*)d_in[5];
    const float* ad1 = (const float*)d_in[6];
    const float* b1  = (const float*)d_in[7];
    const float* W2  = (const float*)d_in[8];
    const float* as2 = (const float*)d_in[9];
    const float* ad2 = (const float*)d_in[10];
    const float* b2  = (const float*)d_in[11];
    const float* Wc  = (const float*)d_in[12];
    const float* bc  = (const float*)d_in[13];
    float* out = (float*)d_out;

    char* p = (char*)d_ws;
    auto alloc = [&](size_t bytes) -> char* {
        char* r = p;
        p += (bytes + 255) & ~(size_t)255;
        return r;
    };
    int* offs    = (int*)alloc((NN + 1) * sizeof(int));
    int* colsrc  = (int*)alloc((size_t)ETOT * sizeof(int));
    int2* ebuf   = (int2*)alloc((size_t)NE * sizeof(int2));
    int* bhist   = (int*)alloc(NBUK * sizeof(int));
    int* bbase   = (int*)alloc((NBUK + 1) * sizeof(int));
    int* bcur    = (int*)alloc(NBUK * sizeof(int));
    int* gstart  = (int*)alloc((NG + 1) * sizeof(int));
    unsigned short* W1t = (unsigned short*)alloc((size_t)FIN * C1 * sizeof(short));
    unsigned short* W2t = (unsigned short*)alloc((size_t)C1 * HID * sizeof(short));
    unsigned char* h1f  = (unsigned char*)alloc((size_t)NN * C1);          // fp8 h1
    unsigned short* h1p = (unsigned short*)alloc((size_t)NN * C1 * sizeof(short));
    unsigned char* h2f  = (unsigned char*)alloc((size_t)NN * HID);         // fp8 h2
    float* es1   = (float*)alloc((size_t)NN * 4 * sizeof(float));
    float* ed1   = (float*)alloc((size_t)NN * 4 * sizeof(float));
    float* es2v  = (float*)alloc((size_t)NN * sizeof(float));
    float* ed2v  = (float*)alloc((size_t)NN * sizeof(float));
    float* h3    = (float*)alloc((size_t)NN * HID * sizeof(float));

    hipMemsetAsync(bhist, 0, NBUK * sizeof(int), stream);

    const int* srcA = ei;       // edge_index[0]
    const int* dstA = ei + NE;  // edge_index[1]

    k_prep<<<(FIN * C1 + C1 * HID + 255) / 256, 256, 0, stream>>>(W1, W2, W1t, W2t);
    k_hist<<<256, 256, 0, stream>>>(dstA, bhist);
    k_bscan<<<1, 64, 0, stream>>>(bhist, bbase, bcur, offs);
    k_part<<<NCHUNK, 256, 0, stream>>>(srcA, dstA, bcur, ebuf);
    k_bfill<<<NBUK, 1024, 0, stream>>>(ebuf, bbase, offs, colsrc);
    k_gstart<<<1, 512, 0, stream>>>(batch, gstart);

    k_gemm1<<<(NN / 16 + 3) / 4, 256, 0, stream>>>(x, W1t, as1, ad1, h1f, es1, ed1);
    k_agg1<<<(NN + 7) / 8, 512, 0, stream>>>(offs, colsrc, h1f, es1, ed1, b1, h1p);
    k_gemm2<<<(NN / 16 + 3) / 4, 256, 0, stream>>>(h1p, W2t, as2, ad2, h2f, es2v, ed2v);
    k_agg2<<<(NN + 7) / 8, 512, 0, stream>>>(offs, colsrc, h2f, es2v, ed2v, b2, h3);
    k_poolcls<<<NG, 256, 0, stream>>>(h3, gstart, Wc, bc, out);
}